// Round 1
// baseline (2090.621 us; speedup 1.0000x reference)
//
#include <hip/hip_runtime.h>
#include <math.h>

namespace {

constexpr int NN = 4096;
constexpr int EE = 131072;
constexpr int E2 = EE + NN;      // 135168 pool edges (orig + self loops)
constexpr int HH = 128;
constexpr int KC = 3277;         // ceil(0.8*4096)
constexpr int KPAD = 3328;

constexpr int NTI = (KC + 63) / 64;    // 52 i-tiles for dense agg
constexpr int NJC = 8;                  // j-chunks for dense agg
constexpr int JCH = (KC + NJC - 1) / NJC;  // 410
constexpr int DIB = (KC + 255) / 256;  // 13 i-blocks for deg
constexpr int DJC = 16;                 // j-chunks for deg
constexpr int DJCH = (KC + DJC - 1) / DJC; // 205

__device__ __forceinline__ float lrelu02(float x){ return x > 0.f ? x : 0.2f * x; }

__device__ __forceinline__ float redSum128(float* red, int t, float v){
  red[t] = v; __syncthreads();
  #pragma unroll
  for (int s = 64; s > 0; s >>= 1){ if (t < s) red[t] += red[t + s]; __syncthreads(); }
  float r = red[0]; __syncthreads();
  return r;
}
__device__ __forceinline__ float redMax128(float* red, int t, float v){
  red[t] = v; __syncthreads();
  #pragma unroll
  for (int s = 64; s > 0; s >>= 1){ if (t < s) red[t] = fmaxf(red[t], red[t + s]); __syncthreads(); }
  float r = red[0]; __syncthreads();
  return r;
}

__global__ void k_zero_init(int* cntD, int* cntS, float* out){
  int i = blockIdx.x * blockDim.x + threadIdx.x;
  if (i < NN){ cntD[i] = 0; cntS[i] = 0; }
  if (i < 512) out[i] = 0.f;
}

__global__ void k_count(const int* __restrict__ ei, int* cntD, int* cntS){
  int e = blockIdx.x * blockDim.x + threadIdx.x;
  if (e >= E2) return;
  int u, v;
  if (e < EE){ u = ei[e]; v = ei[EE + e]; } else { u = e - EE; v = u; }
  atomicAdd(&cntD[v], 1);
  atomicAdd(&cntS[u], 1);
}

__global__ void k_scan(const int* cntD, const int* cntS, int* rowD, int* rowS, int* curD, int* curS){
  __shared__ int sc[1024];
  int t = threadIdx.x;
  for (int pass = 0; pass < 2; ++pass){
    const int* cnt = pass ? cntS : cntD;
    int* row = pass ? rowS : rowD;
    int* cur = pass ? curS : curD;
    int c0 = cnt[t*4+0], c1 = cnt[t*4+1], c2 = cnt[t*4+2], c3 = cnt[t*4+3];
    int tot = c0 + c1 + c2 + c3;
    sc[t] = tot; __syncthreads();
    for (int offs = 1; offs < 1024; offs <<= 1){
      int v = (t >= offs) ? sc[t - offs] : 0;
      __syncthreads();
      sc[t] += v;
      __syncthreads();
    }
    int excl = sc[t] - tot;
    int r0 = excl, r1 = r0 + c0, r2 = r1 + c1, r3 = r2 + c2;
    row[t*4+0] = r0; row[t*4+1] = r1; row[t*4+2] = r2; row[t*4+3] = r3;
    cur[t*4+0] = r0; cur[t*4+1] = r1; cur[t*4+2] = r2; cur[t*4+3] = r3;
    if (t == 1023) row[NN] = r3 + c3;
    __syncthreads();
  }
}

__global__ void k_scatter(const int* __restrict__ ei, int* curD, int* curS, int* colD, int* dstS){
  int e = blockIdx.x * blockDim.x + threadIdx.x;
  if (e >= E2) return;
  int u, v;
  if (e < EE){ u = ei[e]; v = ei[EE + e]; } else { u = e - EE; v = u; }
  int p = atomicAdd(&curD[v], 1); colD[p] = u;
  int q = atomicAdd(&curS[u], 1); dstS[q] = v;
}

// mean over in-neighbors (original edges only -> skip the self loop entry u==v)
__global__ void k_edge_mean(const float* __restrict__ xin, const int* __restrict__ rowD,
                            const int* __restrict__ colD, float* __restrict__ meanb){
  int v = blockIdx.x, t = threadIdx.x;
  int beg = rowD[v], end = rowD[v+1];
  float acc = 0.f;
  for (int p = beg; p < end; ++p){ int u = colD[p]; if (u != v) acc += xin[u*HH + t]; }
  float dg = (float)(end - beg - 1);
  meanb[v*HH + t] = acc / fmaxf(dg, 1.f);
}

// xout = relu(meanb @ Wrel^T + brel + xin @ Wroot^T), 16 rows/block
__global__ void k_lin(const float* __restrict__ meanb, const float* __restrict__ xin,
                      const float* __restrict__ Wrel, const float* __restrict__ brel,
                      const float* __restrict__ Wroot, float* __restrict__ xout, int rows){
  __shared__ float ms[16][HH];
  __shared__ float xs[16][HH];
  int tid = threadIdx.x;
  int r0 = blockIdx.x * 16;
  for (int l = tid; l < 16*HH; l += 256){
    int r = l >> 7, c = l & 127; int gr = r0 + r;
    float mv = 0.f, xv = 0.f;
    if (gr < rows){ mv = meanb[gr*HH + c]; xv = xin[gr*HH + c]; }
    ms[r][c] = mv; xs[r][c] = xv;
  }
  __syncthreads();
  int h = tid & 127, hgrp = tid >> 7;
  float acc[8] = {0.f,0.f,0.f,0.f,0.f,0.f,0.f,0.f};
  for (int c = 0; c < HH; ++c){
    float wr = Wrel[h*HH + c], wo = Wroot[h*HH + c];
    #pragma unroll
    for (int r = 0; r < 8; ++r) acc[r] += ms[hgrp*8 + r][c]*wr + xs[hgrp*8 + r][c]*wo;
  }
  float bb = brel[h];
  #pragma unroll
  for (int r = 0; r < 8; ++r){
    int gr = r0 + hgrp*8 + r;
    if (gr < rows) xout[gr*HH + h] = fmaxf(acc[r] + bb, 0.f);
  }
}

__global__ void k_colmean(const float* __restrict__ x, int rows, float* __restrict__ outp){
  int t = threadIdx.x;
  int r0 = blockIdx.x * 64;
  int rend = min(rows, r0 + 64);
  float acc = 0.f;
  for (int r = r0; r < rend; ++r) acc += x[r*HH + t];
  atomicAdd(&outp[t], acc / (float)rows);
}

// wA2[c] = sum_h wattA[h]*Wlin[h,c];  wA2[HH] = sum_h blin[h]*wattA[h]
__global__ void k_wprep(const float* __restrict__ Wlin, const float* __restrict__ blin,
                        const float* __restrict__ Watt, float* __restrict__ wA2){
  int c = threadIdx.x;
  float s = 0.f;
  for (int hh = 0; hh < HH; ++hh) s += Watt[hh] * Wlin[hh*HH + c];
  wA2[c] = s;
  if (c == 0){
    float q = 0.f;
    for (int hh = 0; hh < HH; ++hh) q += blin[hh] * Watt[hh];
    wA2[HH] = q;
  }
}

__global__ void k_xdot(const float* __restrict__ x2, const float* __restrict__ Watt, float* __restrict__ xdot){
  __shared__ float red[128];
  int n = blockIdx.x, t = threadIdx.x;
  float v = redSum128(red, t, x2[n*HH + t] * Watt[HH + t]);
  if (t == 0) xdot[n] = v;
}

// per dst node v: xq max -> qdot; edge-softmax stats m, ssum; x_new
__global__ void k_pool(const float* __restrict__ x2, const int* __restrict__ rowD, const int* __restrict__ colD,
                       const float* __restrict__ xdotA, const float* __restrict__ wA2, const float* __restrict__ battp,
                       float* qdotA, float* mA, float* sA, float* __restrict__ xnew){
  __shared__ float red[128];
  __shared__ float wmem[128];
  __shared__ int uc[128];
  int v = blockIdx.x, t = threadIdx.x;
  int beg = rowD[v], end = rowD[v+1];
  float batt = battp[0];
  float mx = -3.402823466e38f;
  for (int p = beg; p < end; ++p){ int u = colD[p]; mx = fmaxf(mx, x2[u*HH + t]); }
  float qd = redSum128(red, t, mx * wA2[t]) + wA2[HH];
  float lm = -3.402823466e38f;
  for (int p = beg + t; p < end; p += 128) lm = fmaxf(lm, lrelu02(qd + xdotA[colD[p]] + batt));
  float mm = redMax128(red, t, lm);
  float ls = 0.f;
  for (int p = beg + t; p < end; p += 128) ls += expf(lrelu02(qd + xdotA[colD[p]] + batt) - mm);
  float ss = redSum128(red, t, ls);
  float acc = 0.f;
  for (int basep = beg; basep < end; basep += 128){
    int cnt = min(128, end - basep);
    if (t < cnt){
      int u = colD[basep + t];
      uc[t] = u;
      wmem[t] = expf(lrelu02(qd + xdotA[u] + batt) - mm) / ss;
    }
    __syncthreads();
    for (int i = 0; i < cnt; ++i) acc += wmem[i] * x2[uc[i]*HH + t];
    __syncthreads();
  }
  xnew[v*HH + t] = acc;
  if (t == 0){ qdotA[v] = qd; mA[v] = mm; sA[v] = ss; }
}

__global__ void k_abc(const float* __restrict__ xnew, const float* __restrict__ W1, const float* __restrict__ b1,
                      const float* __restrict__ W2, const float* __restrict__ W3, const float* __restrict__ b3,
                      float* aA, float* bA, float* cA){
  __shared__ float red[128];
  int n = blockIdx.x, t = threadIdx.x;
  float xv = xnew[n*HH + t];
  float s1 = redSum128(red, t, xv * W1[t]);
  float s2 = redSum128(red, t, xv * W2[t]);
  float s3 = redSum128(red, t, xv * W3[t]);
  if (t == 0){ aA[n] = s1 + b1[0]; bA[n] = s2; cA[n] = s3 + b3[0]; }
}

__global__ void k_fit(const int* __restrict__ rowD, const int* __restrict__ colD,
                      const float* __restrict__ aA, const float* __restrict__ bA, const float* __restrict__ cA,
                      float* __restrict__ fitA){
  __shared__ float red[128];
  int v = blockIdx.x, t = threadIdx.x;
  int beg = rowD[v], end = rowD[v+1];
  float la = 0.f;
  for (int p = beg + t; p < end; p += 128) la += aA[colD[p]];
  float s = redSum128(red, t, la);
  if (t == 0){
    float g = s - (float)(end - beg) * bA[v] + cA[v];
    fitA[v] = 1.f / (1.f + expf(-g));
  }
}

// one-block bitonic sort of (desc fitness, asc idx) packed u64 keys
__global__ void k_topk(const float* __restrict__ fitA, int* perm, float* fitk, int* kcol){
  __shared__ unsigned long long keys[NN];
  int t = threadIdx.x;
  for (int i = t; i < NN; i += 1024){
    unsigned b = __float_as_uint(fitA[i]);
    unsigned msk = (b & 0x80000000u) ? 0xFFFFFFFFu : 0x80000000u;
    unsigned desc = ~(b ^ msk);
    keys[i] = ((unsigned long long)desc << 32) | (unsigned)i;
  }
  __syncthreads();
  for (int k = 2; k <= NN; k <<= 1){
    for (int j = k >> 1; j > 0; j >>= 1){
      for (int i = t; i < NN; i += 1024){
        int ixj = i ^ j;
        if (ixj > i){
          unsigned long long A = keys[i], B = keys[ixj];
          bool up = ((i & k) == 0);
          bool sw = up ? (A > B) : (A < B);
          if (sw){ keys[i] = B; keys[ixj] = A; }
        }
      }
      __syncthreads();
    }
  }
  for (int r = t; r < NN; r += 1024){
    int idx = (int)(keys[r] & 0xFFFFFFFFu);
    if (r < KC){ perm[r] = idx; fitk[r] = fitA[idx]; kcol[idx] = r; }
    else kcol[idx] = -1;
  }
}

__global__ void k_xp(const float* __restrict__ xnew, const int* __restrict__ perm,
                     const float* __restrict__ fitk, float* __restrict__ xp){
  int idx = blockIdx.x * blockDim.x + threadIdx.x;
  if (idx >= KC*HH) return;
  int r = idx >> 7, h = idx & 127;
  xp[idx] = xnew[perm[r]*HH + h] * fitk[r];
}

// row k1 of A2 = S^T (A S): phase1 P = (S^T A)[k1,:] in LDS over N, phase2 scatter P[j]*score(j->t)
__global__ void k_A2(const int* __restrict__ rowD, const int* __restrict__ colD,
                     const int* __restrict__ rowS, const int* __restrict__ dstS,
                     const int* __restrict__ perm, const int* __restrict__ kcol,
                     const float* __restrict__ qdotA, const float* __restrict__ xdotA,
                     const float* __restrict__ mA, const float* __restrict__ sA,
                     const float* __restrict__ battp, float* __restrict__ A2){
  __shared__ float P[NN];     // 16 KB
  __shared__ float acc[KPAD]; // 13 KB
  int t = threadIdx.x;
  for (int i = t; i < NN; i += 256) P[i] = 0.f;
  for (int i = t; i < KPAD; i += 256) acc[i] = 0.f;
  __syncthreads();
  int k1 = blockIdx.x;
  int v1 = perm[k1];
  float batt = battp[0];
  float qv = qdotA[v1], mv = mA[v1], sv = sA[v1];
  int beg = rowD[v1], end = rowD[v1+1];
  for (int p = beg; p < end; ++p){
    int n = colD[p];
    float s1 = expf(lrelu02(qv + xdotA[n] + batt) - mv) / sv;
    int b2 = rowS[n], e2 = rowS[n+1];
    for (int q = b2 + t; q < e2; q += 256) atomicAdd(&P[dstS[q]], s1);
  }
  __syncthreads();
  for (int j = t; j < NN; j += 256){
    float pj = P[j];
    if (pj == 0.f) continue;
    float xj = xdotA[j];
    int b2 = rowS[j], e2 = rowS[j+1];
    for (int q = b2; q < e2; ++q){
      int tt = dstS[q]; int k2 = kcol[tt];
      if (k2 < 0) continue;
      float w = expf(lrelu02(qdotA[tt] + xj + batt) - mA[tt]) / sA[tt];
      atomicAdd(&acc[k2], pj * w);
    }
  }
  __syncthreads();
  size_t rb = (size_t)k1 * KC;
  for (int k2 = t; k2 < KC; k2 += 256) A2[rb + k2] = (k2 == k1) ? 0.f : acc[k2];
}

__global__ void k_zero_agg(float* aggd, int* deg){
  int i = blockIdx.x * blockDim.x + threadIdx.x;
  if (i < KC*HH) aggd[i] = 0.f;
  if (i < KC) deg[i] = 0;
}

// aggd[i,h] += sum_j A2[j,i]*X[j,h] over a j-chunk (atomic across chunks)
__global__ void k_dagg(const float* __restrict__ A2, const float* __restrict__ X, float* __restrict__ aggd){
  __shared__ float As[32][64];
  __shared__ float Xs[32][HH];
  int tid = threadIdx.x;
  int bi = blockIdx.x % NTI, jc = blockIdx.x / NTI;
  int i0 = bi * 64;
  int j0c = jc * JCH, jend = min(KC, j0c + JCH);
  int hi = tid & 31, ii = tid >> 5;
  float acc[8][4];
  #pragma unroll
  for (int r = 0; r < 8; ++r){ acc[r][0]=0.f; acc[r][1]=0.f; acc[r][2]=0.f; acc[r][3]=0.f; }
  for (int j0 = j0c; j0 < jend; j0 += 32){
    for (int l = tid; l < 2048; l += 256){
      int r = l >> 6, c = l & 63; int j = j0 + r, i = i0 + c;
      As[r][c] = (j < jend && i < KC) ? A2[(size_t)j*KC + i] : 0.f;
    }
    for (int l = tid; l < 4096; l += 256){
      int r = l >> 7, c = l & 127; int j = j0 + r;
      Xs[r][c] = (j < jend) ? X[j*HH + c] : 0.f;
    }
    __syncthreads();
    #pragma unroll 8
    for (int jj = 0; jj < 32; ++jj){
      float4 xv = *(const float4*)&Xs[jj][hi*4];
      #pragma unroll
      for (int r = 0; r < 8; ++r){
        float a = As[jj][ii*8 + r];
        acc[r][0] += a*xv.x; acc[r][1] += a*xv.y; acc[r][2] += a*xv.z; acc[r][3] += a*xv.w;
      }
    }
    __syncthreads();
  }
  #pragma unroll
  for (int r = 0; r < 8; ++r){
    int i = i0 + ii*8 + r;
    if (i < KC){
      #pragma unroll
      for (int c2 = 0; c2 < 4; ++c2) atomicAdd(&aggd[i*HH + hi*4 + c2], acc[r][c2]);
    }
  }
}

__global__ void k_deg(const float* __restrict__ A2, int* __restrict__ deg){
  int t = threadIdx.x;
  int ib = blockIdx.x % DIB, jc = blockIdx.x / DIB;
  int i = ib*256 + t;
  if (i >= KC) return;
  int j0 = jc * DJCH, jend = min(KC, j0 + DJCH);
  int c = 0;
  for (int j = j0; j < jend; ++j) c += (A2[(size_t)j*KC + i] != 0.f) ? 1 : 0;
  atomicAdd(&deg[i], c);
}

__global__ void k_div(const float* __restrict__ aggd, const int* __restrict__ deg, float* __restrict__ meanb){
  int idx = blockIdx.x * blockDim.x + threadIdx.x;
  if (idx >= KC*HH) return;
  meanb[idx] = aggd[idx] / fmaxf((float)deg[idx >> 7], 1.f);
}

} // namespace

extern "C" void kernel_launch(void* const* d_in, const int* in_sizes, int n_in,
                              void* d_out, int out_size, void* d_ws, size_t ws_size,
                              hipStream_t stream){
  (void)in_sizes; (void)n_in; (void)out_size; (void)ws_size;
  const float* x      = (const float*)d_in[0];
  const int*   ei     = (const int*)d_in[1];
  const float* c0Wrel = (const float*)d_in[2];
  const float* c0brel = (const float*)d_in[3];
  const float* c0Wroot= (const float*)d_in[4];
  const float* c1Wrel = (const float*)d_in[5];
  const float* c1brel = (const float*)d_in[6];
  const float* c1Wroot= (const float*)d_in[7];
  const float* c2Wrel = (const float*)d_in[8];
  const float* c2brel = (const float*)d_in[9];
  const float* c2Wroot= (const float*)d_in[10];
  const float* c3Wrel = (const float*)d_in[11];
  const float* c3brel = (const float*)d_in[12];
  const float* c3Wroot= (const float*)d_in[13];
  const float* Wlin   = (const float*)d_in[14];
  const float* blin   = (const float*)d_in[15];
  const float* Watt   = (const float*)d_in[16];
  const float* batt   = (const float*)d_in[17];
  const float* W1     = (const float*)d_in[18];
  const float* b1     = (const float*)d_in[19];
  const float* W2     = (const float*)d_in[20];
  const float* W3     = (const float*)d_in[21];
  const float* b3     = (const float*)d_in[22];
  float* out = (float*)d_out;

  char* base = (char*)d_ws;
  size_t off = 0;
  auto carve = [&](size_t bytes) -> void* {
    void* p = base + off;
    off += (bytes + 255) & ~(size_t)255;
    return p;
  };
  float* x1    = (float*)carve((size_t)NN*HH*4);
  float* x2b   = (float*)carve((size_t)NN*HH*4);
  float* meanb = (float*)carve((size_t)NN*HH*4);
  float* xnew  = (float*)carve((size_t)NN*HH*4);
  float* xp    = (float*)carve((size_t)KC*HH*4);
  float* x3    = (float*)carve((size_t)KC*HH*4);
  float* x4    = (float*)carve((size_t)KC*HH*4);
  float* aggd  = (float*)carve((size_t)KC*HH*4);
  float* A2    = (float*)carve((size_t)KC*KC*4);   // 43 MB
  float* xdot  = (float*)carve(NN*4);
  float* qdot  = (float*)carve(NN*4);
  float* mmaxA = (float*)carve(NN*4);
  float* ssumA = (float*)carve(NN*4);
  float* aA    = (float*)carve(NN*4);
  float* bA    = (float*)carve(NN*4);
  float* cA    = (float*)carve(NN*4);
  float* fitA  = (float*)carve(NN*4);
  float* fitk  = (float*)carve(KC*4);
  float* wA2   = (float*)carve((HH+1)*4);
  int* rowD = (int*)carve((NN+1)*4);
  int* rowS = (int*)carve((NN+1)*4);
  int* cntD = (int*)carve(NN*4);
  int* cntS = (int*)carve(NN*4);
  int* curD = (int*)carve(NN*4);
  int* curS = (int*)carve(NN*4);
  int* colD = (int*)carve((size_t)E2*4);
  int* dstS = (int*)carve((size_t)E2*4);
  int* perm = (int*)carve(KC*4);
  int* kcol = (int*)carve(NN*4);
  int* deg3 = (int*)carve(KC*4);
  // total workspace ~60 MB

  k_zero_init<<<NN/256, 256, 0, stream>>>(cntD, cntS, out);
  k_count<<<(E2+255)/256, 256, 0, stream>>>(ei, cntD, cntS);
  k_scan<<<1, 1024, 0, stream>>>(cntD, cntS, rowD, rowS, curD, curS);
  k_scatter<<<(E2+255)/256, 256, 0, stream>>>(ei, curD, curS, colD, dstS);

  // conv0
  k_edge_mean<<<NN, 128, 0, stream>>>(x, rowD, colD, meanb);
  k_lin<<<(NN+15)/16, 256, 0, stream>>>(meanb, x, c0Wrel, c0brel, c0Wroot, x1, NN);
  k_colmean<<<(NN+63)/64, 128, 0, stream>>>(x1, NN, out + 0);

  // conv1
  k_edge_mean<<<NN, 128, 0, stream>>>(x1, rowD, colD, meanb);
  k_lin<<<(NN+15)/16, 256, 0, stream>>>(meanb, x1, c1Wrel, c1brel, c1Wroot, x2b, NN);
  k_colmean<<<(NN+63)/64, 128, 0, stream>>>(x2b, NN, out + 128);

  // ASAP pool
  k_wprep<<<1, 128, 0, stream>>>(Wlin, blin, Watt, wA2);
  k_xdot<<<NN, 128, 0, stream>>>(x2b, Watt, xdot);
  k_pool<<<NN, 128, 0, stream>>>(x2b, rowD, colD, xdot, wA2, batt, qdot, mmaxA, ssumA, xnew);
  k_abc<<<NN, 128, 0, stream>>>(xnew, W1, b1, W2, W3, b3, aA, bA, cA);
  k_fit<<<NN, 128, 0, stream>>>(rowD, colD, aA, bA, cA, fitA);
  k_topk<<<1, 1024, 0, stream>>>(fitA, perm, fitk, kcol);
  k_xp<<<(KC*HH+255)/256, 256, 0, stream>>>(xnew, perm, fitk, xp);
  k_A2<<<KC, 256, 0, stream>>>(rowD, colD, rowS, dstS, perm, kcol, qdot, xdot, mmaxA, ssumA, batt, A2);

  // conv2 (dense)
  k_zero_agg<<<(KC*HH+255)/256, 256, 0, stream>>>(aggd, deg3);
  k_dagg<<<NTI*NJC, 256, 0, stream>>>(A2, xp, aggd);
  k_deg<<<DIB*DJC, 256, 0, stream>>>(A2, deg3);
  k_div<<<(KC*HH+255)/256, 256, 0, stream>>>(aggd, deg3, meanb);
  k_lin<<<(KC+15)/16, 256, 0, stream>>>(meanb, xp, c2Wrel, c2brel, c2Wroot, x3, KC);
  k_colmean<<<(KC+63)/64, 128, 0, stream>>>(x3, KC, out + 256);

  // conv3 (dense)
  k_zero_agg<<<(KC*HH+255)/256, 256, 0, stream>>>(aggd, deg3);
  k_dagg<<<NTI*NJC, 256, 0, stream>>>(A2, x3, aggd);
  k_deg<<<DIB*DJC, 256, 0, stream>>>(A2, deg3);
  k_div<<<(KC*HH+255)/256, 256, 0, stream>>>(aggd, deg3, meanb);
  k_lin<<<(KC+15)/16, 256, 0, stream>>>(meanb, x3, c3Wrel, c3brel, c3Wroot, x4, KC);
  k_colmean<<<(KC+63)/64, 128, 0, stream>>>(x4, KC, out + 384);
}

// Round 2
// 796.473 us; speedup vs baseline: 2.6248x; 2.6248x over previous
//
#include <hip/hip_runtime.h>
#include <hip/hip_fp16.h>
#include <math.h>

namespace {

constexpr int NN = 4096;
constexpr int EE = 131072;
constexpr int E2 = EE + NN;      // 135168 pool edges (orig + self loops)
constexpr int HH = 128;
constexpr int KC = 3277;         // ceil(0.8*4096)
constexpr int UP = 3584;         // U row stride (7*512, half2-friendly)
constexpr int A2P = 3328;        // A2 row stride (even, padded)

constexpr int NTI = (KC + 63) / 64;    // 52 i-tiles for dense agg
constexpr int NJC = 8;                  // j-chunks for dense agg
constexpr int JCH = (KC + NJC - 1) / NJC;  // 410

__device__ __forceinline__ float lrelu02(float x){ return x > 0.f ? x : 0.2f * x; }

__device__ __forceinline__ float redSum128(float* red, int t, float v){
  red[t] = v; __syncthreads();
  #pragma unroll
  for (int s = 64; s > 0; s >>= 1){ if (t < s) red[t] += red[t + s]; __syncthreads(); }
  float r = red[0]; __syncthreads();
  return r;
}
__device__ __forceinline__ float redMax128(float* red, int t, float v){
  red[t] = v; __syncthreads();
  #pragma unroll
  for (int s = 64; s > 0; s >>= 1){ if (t < s) red[t] = fmaxf(red[t], red[t + s]); __syncthreads(); }
  float r = red[0]; __syncthreads();
  return r;
}

__global__ void k_zero_init(int* cntD, int* cntS, float* out){
  int i = blockIdx.x * blockDim.x + threadIdx.x;
  if (i < NN){ cntD[i] = 0; cntS[i] = 0; }
  if (i < 512) out[i] = 0.f;
}

__global__ void k_count(const int* __restrict__ ei, int* cntD, int* cntS){
  int e = blockIdx.x * blockDim.x + threadIdx.x;
  if (e >= E2) return;
  int u, v;
  if (e < EE){ u = ei[e]; v = ei[EE + e]; } else { u = e - EE; v = u; }
  atomicAdd(&cntD[v], 1);
  atomicAdd(&cntS[u], 1);
}

__global__ void k_scan(const int* cntD, const int* cntS, int* rowD, int* rowS, int* curD, int* curS){
  __shared__ int sc[1024];
  int t = threadIdx.x;
  for (int pass = 0; pass < 2; ++pass){
    const int* cnt = pass ? cntS : cntD;
    int* row = pass ? rowS : rowD;
    int* cur = pass ? curS : curD;
    int c0 = cnt[t*4+0], c1 = cnt[t*4+1], c2 = cnt[t*4+2], c3 = cnt[t*4+3];
    int tot = c0 + c1 + c2 + c3;
    sc[t] = tot; __syncthreads();
    for (int offs = 1; offs < 1024; offs <<= 1){
      int v = (t >= offs) ? sc[t - offs] : 0;
      __syncthreads();
      sc[t] += v;
      __syncthreads();
    }
    int excl = sc[t] - tot;
    int r0 = excl, r1 = r0 + c0, r2 = r1 + c1, r3 = r2 + c2;
    row[t*4+0] = r0; row[t*4+1] = r1; row[t*4+2] = r2; row[t*4+3] = r3;
    cur[t*4+0] = r0; cur[t*4+1] = r1; cur[t*4+2] = r2; cur[t*4+3] = r3;
    if (t == 1023) row[NN] = r3 + c3;
    __syncthreads();
  }
}

__global__ void k_scatter(const int* __restrict__ ei, int* curD, int* curS,
                          int* colD, int* dstS, int* mapSD){
  int e = blockIdx.x * blockDim.x + threadIdx.x;
  if (e >= E2) return;
  int u, v;
  if (e < EE){ u = ei[e]; v = ei[EE + e]; } else { u = e - EE; v = u; }
  int p = atomicAdd(&curD[v], 1); colD[p] = u;
  int q = atomicAdd(&curS[u], 1); dstS[q] = v; mapSD[q] = p;
}

// mean over in-neighbors (original edges only -> skip the self loop entry u==v)
__global__ void k_edge_mean(const float* __restrict__ xin, const int* __restrict__ rowD,
                            const int* __restrict__ colD, float* __restrict__ meanb){
  int v = blockIdx.x, t = threadIdx.x;
  int beg = rowD[v], end = rowD[v+1];
  float acc = 0.f;
  for (int p = beg; p < end; ++p){ int u = colD[p]; if (u != v) acc += xin[u*HH + t]; }
  float dg = (float)(end - beg - 1);
  meanb[v*HH + t] = acc / fmaxf(dg, 1.f);
}

// xout = relu(meanb @ Wrel^T + brel + xin @ Wroot^T), 16 rows/block
__global__ void k_lin(const float* __restrict__ meanb, const float* __restrict__ xin,
                      const float* __restrict__ Wrel, const float* __restrict__ brel,
                      const float* __restrict__ Wroot, float* __restrict__ xout, int rows){
  __shared__ float ms[16][HH];
  __shared__ float xs[16][HH];
  int tid = threadIdx.x;
  int r0 = blockIdx.x * 16;
  for (int l = tid; l < 16*HH; l += 256){
    int r = l >> 7, c = l & 127; int gr = r0 + r;
    float mv = 0.f, xv = 0.f;
    if (gr < rows){ mv = meanb[gr*HH + c]; xv = xin[gr*HH + c]; }
    ms[r][c] = mv; xs[r][c] = xv;
  }
  __syncthreads();
  int h = tid & 127, hgrp = tid >> 7;
  float acc[8] = {0.f,0.f,0.f,0.f,0.f,0.f,0.f,0.f};
  for (int c = 0; c < HH; ++c){
    float wr = Wrel[h*HH + c], wo = Wroot[h*HH + c];
    #pragma unroll
    for (int r = 0; r < 8; ++r) acc[r] += ms[hgrp*8 + r][c]*wr + xs[hgrp*8 + r][c]*wo;
  }
  float bb = brel[h];
  #pragma unroll
  for (int r = 0; r < 8; ++r){
    int gr = r0 + hgrp*8 + r;
    if (gr < rows) xout[gr*HH + h] = fmaxf(acc[r] + bb, 0.f);
  }
}

__global__ void k_colmean(const float* __restrict__ x, int rows, float* __restrict__ outp){
  int t = threadIdx.x;
  int r0 = blockIdx.x * 64;
  int rend = min(rows, r0 + 64);
  float acc = 0.f;
  for (int r = r0; r < rend; ++r) acc += x[r*HH + t];
  atomicAdd(&outp[t], acc / (float)rows);
}

// wA2[c] = sum_h wattA[h]*Wlin[h,c];  wA2[HH] = sum_h blin[h]*wattA[h]
__global__ void k_wprep(const float* __restrict__ Wlin, const float* __restrict__ blin,
                        const float* __restrict__ Watt, float* __restrict__ wA2){
  int c = threadIdx.x;
  float s = 0.f;
  for (int hh = 0; hh < HH; ++hh) s += Watt[hh] * Wlin[hh*HH + c];
  wA2[c] = s;
  if (c == 0){
    float q = 0.f;
    for (int hh = 0; hh < HH; ++hh) q += blin[hh] * Watt[hh];
    wA2[HH] = q;
  }
}

__global__ void k_xdot(const float* __restrict__ x2, const float* __restrict__ Watt, float* __restrict__ xdot){
  __shared__ float red[128];
  int n = blockIdx.x, t = threadIdx.x;
  float v = redSum128(red, t, x2[n*HH + t] * Watt[HH + t]);
  if (t == 0) xdot[n] = v;
}

// per dst node v: xq max -> qdot; edge-softmax stats m, ssum; x_new; per-edge weight wD
__global__ void k_pool(const float* __restrict__ x2, const int* __restrict__ rowD, const int* __restrict__ colD,
                       const float* __restrict__ xdotA, const float* __restrict__ wA2, const float* __restrict__ battp,
                       float* qdotA, float* mA, float* sA, float* __restrict__ xnew, float* __restrict__ wD){
  __shared__ float red[128];
  __shared__ float wmem[128];
  __shared__ int uc[128];
  int v = blockIdx.x, t = threadIdx.x;
  int beg = rowD[v], end = rowD[v+1];
  float batt = battp[0];
  float mx = -3.402823466e38f;
  for (int p = beg; p < end; ++p){ int u = colD[p]; mx = fmaxf(mx, x2[u*HH + t]); }
  float qd = redSum128(red, t, mx * wA2[t]) + wA2[HH];
  float lm = -3.402823466e38f;
  for (int p = beg + t; p < end; p += 128) lm = fmaxf(lm, lrelu02(qd + xdotA[colD[p]] + batt));
  float mm = redMax128(red, t, lm);
  float ls = 0.f;
  for (int p = beg + t; p < end; p += 128) ls += expf(lrelu02(qd + xdotA[colD[p]] + batt) - mm);
  float ss = redSum128(red, t, ls);
  float acc = 0.f;
  for (int basep = beg; basep < end; basep += 128){
    int cnt = min(128, end - basep);
    if (t < cnt){
      int u = colD[basep + t];
      uc[t] = u;
      float w = expf(lrelu02(qd + xdotA[u] + batt) - mm) / ss;
      wmem[t] = w;
      wD[basep + t] = w;
    }
    __syncthreads();
    for (int i = 0; i < cnt; ++i) acc += wmem[i] * x2[uc[i]*HH + t];
    __syncthreads();
  }
  xnew[v*HH + t] = acc;
  if (t == 0){ qdotA[v] = qd; mA[v] = mm; sA[v] = ss; }
}

__global__ void k_abc(const float* __restrict__ xnew, const float* __restrict__ W1, const float* __restrict__ b1,
                      const float* __restrict__ W2, const float* __restrict__ W3, const float* __restrict__ b3,
                      float* aA, float* bA, float* cA){
  __shared__ float red[128];
  int n = blockIdx.x, t = threadIdx.x;
  float xv = xnew[n*HH + t];
  float s1 = redSum128(red, t, xv * W1[t]);
  float s2 = redSum128(red, t, xv * W2[t]);
  float s3 = redSum128(red, t, xv * W3[t]);
  if (t == 0){ aA[n] = s1 + b1[0]; bA[n] = s2; cA[n] = s3 + b3[0]; }
}

__global__ void k_fit(const int* __restrict__ rowD, const int* __restrict__ colD,
                      const float* __restrict__ aA, const float* __restrict__ bA, const float* __restrict__ cA,
                      float* __restrict__ fitA){
  __shared__ float red[128];
  int v = blockIdx.x, t = threadIdx.x;
  int beg = rowD[v], end = rowD[v+1];
  float la = 0.f;
  for (int p = beg + t; p < end; p += 128) la += aA[colD[p]];
  float s = redSum128(red, t, la);
  if (t == 0){
    float g = s - (float)(end - beg) * bA[v] + cA[v];
    fitA[v] = 1.f / (1.f + expf(-g));
  }
}

// one-block bitonic sort of (desc fitness, asc idx) packed u64 keys
__global__ void k_topk(const float* __restrict__ fitA, int* perm, float* fitk, int* kcol){
  __shared__ unsigned long long keys[NN];
  int t = threadIdx.x;
  for (int i = t; i < NN; i += 1024){
    unsigned b = __float_as_uint(fitA[i]);
    unsigned msk = (b & 0x80000000u) ? 0xFFFFFFFFu : 0x80000000u;
    unsigned desc = ~(b ^ msk);
    keys[i] = ((unsigned long long)desc << 32) | (unsigned)i;
  }
  __syncthreads();
  for (int k = 2; k <= NN; k <<= 1){
    for (int j = k >> 1; j > 0; j >>= 1){
      for (int i = t; i < NN; i += 1024){
        int ixj = i ^ j;
        if (ixj > i){
          unsigned long long A = keys[i], B = keys[ixj];
          bool up = ((i & k) == 0);
          bool sw = up ? (A > B) : (A < B);
          if (sw){ keys[i] = B; keys[ixj] = A; }
        }
      }
      __syncthreads();
    }
  }
  for (int r = t; r < NN; r += 1024){
    int idx = (int)(keys[r] & 0xFFFFFFFFu);
    if (r < KC){ perm[r] = idx; fitk[r] = fitA[idx]; kcol[idx] = r; }
    else kcol[idx] = -1;
  }
}

__global__ void k_xp(const float* __restrict__ xnew, const int* __restrict__ perm,
                     const float* __restrict__ fitk, float* __restrict__ xp){
  int idx = blockIdx.x * blockDim.x + threadIdx.x;
  if (idx >= KC*HH) return;
  int r = idx >> 7, h = idx & 127;
  xp[idx] = xnew[perm[r]*HH + h] * fitk[r];
}

// src-ordered per-edge weight + kept-cluster index of target
__global__ void k_wS(const int* __restrict__ mapSD, const int* __restrict__ dstS,
                     const int* __restrict__ kcol, const float* __restrict__ wD,
                     float* __restrict__ wS, int* __restrict__ kS){
  int q = blockIdx.x * blockDim.x + threadIdx.x;
  if (q >= E2) return;
  wS[q] = wD[mapSD[q]];
  kS[q] = kcol[dstS[q]];
}

// U[n,:] = (A @ S)[n,:]  (dense f16 row, stride UP, zero-padded)
__global__ void k_U(const int* __restrict__ rowS, const int* __restrict__ dstS,
                    const float* __restrict__ wS, const int* __restrict__ kS,
                    __half* __restrict__ U){
  __shared__ float acc[UP];   // 14 KB
  int t = threadIdx.x, n = blockIdx.x;
  for (int i = t; i < UP; i += 256) acc[i] = 0.f;
  __syncthreads();
  int b = rowS[n], e = rowS[n+1];
  for (int p = b; p < e; ++p){
    int j = dstS[p];
    int b2 = rowS[j], e2 = rowS[j+1];
    for (int q = b2 + t; q < e2; q += 256){
      int k = kS[q];
      if (k >= 0) atomicAdd(&acc[k], wS[q]);
    }
  }
  __syncthreads();
  __half2* Ur = (__half2*)(U + (size_t)n * UP);
  for (int i = t; i < UP/2; i += 256)
    Ur[i] = __halves2half2(__float2half(acc[2*i]), __float2half(acc[2*i+1]));
}

// A2[k1,:] = sum over in-edges (n -> v1=perm[k1]) of wD[p] * U[n,:]; zero diag
__global__ void k_A2B(const int* __restrict__ rowD, const int* __restrict__ colD,
                      const float* __restrict__ wD, const int* __restrict__ perm,
                      const __half* __restrict__ U, __half* __restrict__ A2){
  __shared__ int ns[64];
  __shared__ float ws[64];
  int t = threadIdx.x;
  int k1 = blockIdx.x;
  int v1 = perm[k1];
  int beg = rowD[v1], end = rowD[v1+1];
  float2 a[7];
  #pragma unroll
  for (int r = 0; r < 7; ++r){ a[r].x = 0.f; a[r].y = 0.f; }
  for (int base = beg; base < end; base += 64){
    int cnt = min(64, end - base);
    if (t < cnt){ ns[t] = colD[base + t]; ws[t] = wD[base + t]; }
    __syncthreads();
    for (int i = 0; i < cnt; ++i){
      const __half2* Un = (const __half2*)(U + (size_t)ns[i] * UP) + t;
      float w = ws[i];
      #pragma unroll
      for (int r = 0; r < 7; ++r){
        float2 f = __half22float2(Un[r*256]);
        a[r].x += w * f.x;
        a[r].y += w * f.y;
      }
    }
    __syncthreads();
  }
  size_t rb = (size_t)k1 * A2P;
  #pragma unroll
  for (int r = 0; r < 7; ++r){
    int k2 = 512*r + 2*t;
    if (k2 < KC){
      float lo = (k2 == k1) ? 0.f : a[r].x;
      float hi = (k2 + 1 == k1 || k2 + 1 >= KC) ? 0.f : a[r].y;
      *(__half2*)(A2 + rb + k2) = __halves2half2(__float2half(lo), __float2half(hi));
    }
  }
}

__global__ void k_zero_agg(float* aggd, int* deg){
  int i = blockIdx.x * blockDim.x + threadIdx.x;
  if (i < KC*HH) aggd[i] = 0.f;
  if (i < KC) deg[i] = 0;
}

// aggd[i,h] += sum_j A2[j,i]*X[j,h] over a j-chunk; fused nonzero count -> deg
__global__ void k_dagg(const __half* __restrict__ A2, const float* __restrict__ X,
                       float* __restrict__ aggd, int* __restrict__ deg){
  __shared__ float As[32][64];
  __shared__ float Xs[32][HH];
  int tid = threadIdx.x;
  int bi = blockIdx.x % NTI, jc = blockIdx.x / NTI;
  int i0 = bi * 64;
  int j0c = jc * JCH, jend = min(KC, j0c + JCH);
  int hi = tid & 31, ii = tid >> 5;
  float acc[8][4];
  #pragma unroll
  for (int r = 0; r < 8; ++r){ acc[r][0]=0.f; acc[r][1]=0.f; acc[r][2]=0.f; acc[r][3]=0.f; }
  int nzc = 0;
  for (int j0 = j0c; j0 < jend; j0 += 32){
    for (int l = tid; l < 2048; l += 256){
      int r = l >> 6, c = l & 63; int j = j0 + r, i = i0 + c;
      float v = (j < jend && i < KC) ? __half2float(A2[(size_t)j*A2P + i]) : 0.f;
      As[r][c] = v;
      nzc += (v != 0.f) ? 1 : 0;
    }
    for (int l = tid; l < 4096; l += 256){
      int r = l >> 7, c = l & 127; int j = j0 + r;
      Xs[r][c] = (j < jend) ? X[j*HH + c] : 0.f;
    }
    __syncthreads();
    #pragma unroll 8
    for (int jj = 0; jj < 32; ++jj){
      float4 xv = *(const float4*)&Xs[jj][hi*4];
      #pragma unroll
      for (int r = 0; r < 8; ++r){
        float aval = As[jj][ii*8 + r];
        acc[r][0] += aval*xv.x; acc[r][1] += aval*xv.y; acc[r][2] += aval*xv.z; acc[r][3] += aval*xv.w;
      }
    }
    __syncthreads();
  }
  #pragma unroll
  for (int r = 0; r < 8; ++r){
    int i = i0 + ii*8 + r;
    if (i < KC){
      #pragma unroll
      for (int c2 = 0; c2 < 4; ++c2) atomicAdd(&aggd[i*HH + hi*4 + c2], acc[r][c2]);
    }
  }
  int ic = i0 + (tid & 63);
  if (nzc > 0 && ic < KC) atomicAdd(&deg[ic], nzc);
}

__global__ void k_div(const float* __restrict__ aggd, const int* __restrict__ deg, float* __restrict__ meanb){
  int idx = blockIdx.x * blockDim.x + threadIdx.x;
  if (idx >= KC*HH) return;
  meanb[idx] = aggd[idx] / fmaxf((float)deg[idx >> 7], 1.f);
}

} // namespace

extern "C" void kernel_launch(void* const* d_in, const int* in_sizes, int n_in,
                              void* d_out, int out_size, void* d_ws, size_t ws_size,
                              hipStream_t stream){
  (void)in_sizes; (void)n_in; (void)out_size; (void)ws_size;
  const float* x      = (const float*)d_in[0];
  const int*   ei     = (const int*)d_in[1];
  const float* c0Wrel = (const float*)d_in[2];
  const float* c0brel = (const float*)d_in[3];
  const float* c0Wroot= (const float*)d_in[4];
  const float* c1Wrel = (const float*)d_in[5];
  const float* c1brel = (const float*)d_in[6];
  const float* c1Wroot= (const float*)d_in[7];
  const float* c2Wrel = (const float*)d_in[8];
  const float* c2brel = (const float*)d_in[9];
  const float* c2Wroot= (const float*)d_in[10];
  const float* c3Wrel = (const float*)d_in[11];
  const float* c3brel = (const float*)d_in[12];
  const float* c3Wroot= (const float*)d_in[13];
  const float* Wlin   = (const float*)d_in[14];
  const float* blin   = (const float*)d_in[15];
  const float* Watt   = (const float*)d_in[16];
  const float* batt   = (const float*)d_in[17];
  const float* W1     = (const float*)d_in[18];
  const float* b1     = (const float*)d_in[19];
  const float* W2     = (const float*)d_in[20];
  const float* W3     = (const float*)d_in[21];
  const float* b3     = (const float*)d_in[22];
  float* out = (float*)d_out;

  char* base = (char*)d_ws;
  size_t off = 0;
  auto carve = [&](size_t bytes) -> void* {
    void* p = base + off;
    off += (bytes + 255) & ~(size_t)255;
    return p;
  };
  float* x1    = (float*)carve((size_t)NN*HH*4);
  float* x2b   = (float*)carve((size_t)NN*HH*4);
  float* meanb = (float*)carve((size_t)NN*HH*4);
  float* xnew  = (float*)carve((size_t)NN*HH*4);
  float* xp    = (float*)carve((size_t)KC*HH*4);
  float* x3    = (float*)carve((size_t)KC*HH*4);
  float* x4    = (float*)carve((size_t)KC*HH*4);
  float* aggd  = (float*)carve((size_t)KC*HH*4);
  __half* A2   = (__half*)carve((size_t)KC*A2P*2);   // ~22 MB
  __half* U    = (__half*)carve((size_t)NN*UP*2);    // ~29 MB
  float* xdot  = (float*)carve(NN*4);
  float* qdot  = (float*)carve(NN*4);
  float* mmaxA = (float*)carve(NN*4);
  float* ssumA = (float*)carve(NN*4);
  float* aA    = (float*)carve(NN*4);
  float* bA    = (float*)carve(NN*4);
  float* cA    = (float*)carve(NN*4);
  float* fitA  = (float*)carve(NN*4);
  float* fitk  = (float*)carve(KC*4);
  float* wA2   = (float*)carve((HH+1)*4);
  float* wD    = (float*)carve((size_t)E2*4);
  float* wSar  = (float*)carve((size_t)E2*4);
  int* rowD = (int*)carve((NN+1)*4);
  int* rowS = (int*)carve((NN+1)*4);
  int* cntD = (int*)carve(NN*4);
  int* cntS = (int*)carve(NN*4);
  int* curD = (int*)carve(NN*4);
  int* curS = (int*)carve(NN*4);
  int* colD = (int*)carve((size_t)E2*4);
  int* dstS = (int*)carve((size_t)E2*4);
  int* mapSD= (int*)carve((size_t)E2*4);
  int* kSar = (int*)carve((size_t)E2*4);
  int* perm = (int*)carve(KC*4);
  int* kcol = (int*)carve(NN*4);
  int* deg3 = (int*)carve(KC*4);

  k_zero_init<<<NN/256, 256, 0, stream>>>(cntD, cntS, out);
  k_count<<<(E2+255)/256, 256, 0, stream>>>(ei, cntD, cntS);
  k_scan<<<1, 1024, 0, stream>>>(cntD, cntS, rowD, rowS, curD, curS);
  k_scatter<<<(E2+255)/256, 256, 0, stream>>>(ei, curD, curS, colD, dstS, mapSD);

  // conv0
  k_edge_mean<<<NN, 128, 0, stream>>>(x, rowD, colD, meanb);
  k_lin<<<(NN+15)/16, 256, 0, stream>>>(meanb, x, c0Wrel, c0brel, c0Wroot, x1, NN);
  k_colmean<<<(NN+63)/64, 128, 0, stream>>>(x1, NN, out + 0);

  // conv1
  k_edge_mean<<<NN, 128, 0, stream>>>(x1, rowD, colD, meanb);
  k_lin<<<(NN+15)/16, 256, 0, stream>>>(meanb, x1, c1Wrel, c1brel, c1Wroot, x2b, NN);
  k_colmean<<<(NN+63)/64, 128, 0, stream>>>(x2b, NN, out + 128);

  // ASAP pool
  k_wprep<<<1, 128, 0, stream>>>(Wlin, blin, Watt, wA2);
  k_xdot<<<NN, 128, 0, stream>>>(x2b, Watt, xdot);
  k_pool<<<NN, 128, 0, stream>>>(x2b, rowD, colD, xdot, wA2, batt, qdot, mmaxA, ssumA, xnew, wD);
  k_abc<<<NN, 128, 0, stream>>>(xnew, W1, b1, W2, W3, b3, aA, bA, cA);
  k_fit<<<NN, 128, 0, stream>>>(rowD, colD, aA, bA, cA, fitA);
  k_topk<<<1, 1024, 0, stream>>>(fitA, perm, fitk, kcol);
  k_xp<<<(KC*HH+255)/256, 256, 0, stream>>>(xnew, perm, fitk, xp);
  k_wS<<<(E2+255)/256, 256, 0, stream>>>(mapSD, dstS, kcol, wD, wSar, kSar);
  k_U<<<NN, 256, 0, stream>>>(rowS, dstS, wSar, kSar, U);
  k_A2B<<<KC, 256, 0, stream>>>(rowD, colD, wD, perm, U, A2);

  // conv2 (dense)
  k_zero_agg<<<(KC*HH+255)/256, 256, 0, stream>>>(aggd, deg3);
  k_dagg<<<NTI*NJC, 256, 0, stream>>>(A2, xp, aggd, deg3);
  k_div<<<(KC*HH+255)/256, 256, 0, stream>>>(aggd, deg3, meanb);
  k_lin<<<(KC+15)/16, 256, 0, stream>>>(meanb, xp, c2Wrel, c2brel, c2Wroot, x3, KC);
  k_colmean<<<(KC+63)/64, 128, 0, stream>>>(x3, KC, out + 256);

  // conv3 (dense)
  k_zero_agg<<<(KC*HH+255)/256, 256, 0, stream>>>(aggd, deg3);
  k_dagg<<<NTI*NJC, 256, 0, stream>>>(A2, x3, aggd, deg3);
  k_div<<<(KC*HH+255)/256, 256, 0, stream>>>(aggd, deg3, meanb);
  k_lin<<<(KC+15)/16, 256, 0, stream>>>(meanb, x3, c3Wrel, c3brel, c3Wroot, x4, KC);
  k_colmean<<<(KC+63)/64, 128, 0, stream>>>(x4, KC, out + 384);
}

// Round 4
// 591.966 us; speedup vs baseline: 3.5317x; 1.3455x over previous
//
#include <hip/hip_runtime.h>
#include <hip/hip_fp16.h>
#include <math.h>

namespace {

constexpr int NN = 4096;
constexpr int EE = 131072;
constexpr int E2 = EE + NN;      // 135168 pool edges (orig + self loops)
constexpr int HH = 128;
constexpr int KC = 3277;         // ceil(0.8*4096)
constexpr int UP = 3584;         // U row stride (7*512, half2-friendly)
constexpr int A2P = 3328;        // A2 row/col padded dim (13*256)

typedef _Float16 f16x8 __attribute__((ext_vector_type(8)));
typedef float f32x4 __attribute__((ext_vector_type(4)));

constexpr int MMIT = A2P / 128;  // 26 i-tiles for MFMA dagg
constexpr int MMKS = 13;         // K-splits (chunk 256 = 8 mfma k-steps)

__device__ __forceinline__ float lrelu02(float x){ return x > 0.f ? x : 0.2f * x; }

__device__ __forceinline__ float redSum128(float* red, int t, float v){
  red[t] = v; __syncthreads();
  #pragma unroll
  for (int s = 64; s > 0; s >>= 1){ if (t < s) red[t] += red[t + s]; __syncthreads(); }
  float r = red[0]; __syncthreads();
  return r;
}
__device__ __forceinline__ float redMax128(float* red, int t, float v){
  red[t] = v; __syncthreads();
  #pragma unroll
  for (int s = 64; s > 0; s >>= 1){ if (t < s) red[t] = fmaxf(red[t], red[t + s]); __syncthreads(); }
  float r = red[0]; __syncthreads();
  return r;
}

__global__ void k_zero_init(int* cntD, int* cntS, float* out){
  int i = blockIdx.x * blockDim.x + threadIdx.x;
  if (i < NN){ cntD[i] = 0; cntS[i] = 0; }
  if (i < 512) out[i] = 0.f;
}

__global__ void k_count(const int* __restrict__ ei, int* cntD, int* cntS){
  int e = blockIdx.x * blockDim.x + threadIdx.x;
  if (e >= E2) return;
  int u, v;
  if (e < EE){ u = ei[e]; v = ei[EE + e]; } else { u = e - EE; v = u; }
  atomicAdd(&cntD[v], 1);
  atomicAdd(&cntS[u], 1);
}

__global__ void k_scan(const int* cntD, const int* cntS, int* rowD, int* rowS, int* curD, int* curS){
  __shared__ int sc[1024];
  int t = threadIdx.x;
  for (int pass = 0; pass < 2; ++pass){
    const int* cnt = pass ? cntS : cntD;
    int* row = pass ? rowS : rowD;
    int* cur = pass ? curS : curD;
    int c0 = cnt[t*4+0], c1 = cnt[t*4+1], c2 = cnt[t*4+2], c3 = cnt[t*4+3];
    int tot = c0 + c1 + c2 + c3;
    sc[t] = tot; __syncthreads();
    for (int offs = 1; offs < 1024; offs <<= 1){
      int v = (t >= offs) ? sc[t - offs] : 0;
      __syncthreads();
      sc[t] += v;
      __syncthreads();
    }
    int excl = sc[t] - tot;
    int r0 = excl, r1 = r0 + c0, r2 = r1 + c1, r3 = r2 + c2;
    row[t*4+0] = r0; row[t*4+1] = r1; row[t*4+2] = r2; row[t*4+3] = r3;
    cur[t*4+0] = r0; cur[t*4+1] = r1; cur[t*4+2] = r2; cur[t*4+3] = r3;
    if (t == 1023) row[NN] = r3 + c3;
    __syncthreads();
  }
}

__global__ void k_scatter(const int* __restrict__ ei, int* curD, int* curS,
                          int* colD, int* dstS, int* mapSD){
  int e = blockIdx.x * blockDim.x + threadIdx.x;
  if (e >= E2) return;
  int u, v;
  if (e < EE){ u = ei[e]; v = ei[EE + e]; } else { u = e - EE; v = u; }
  int p = atomicAdd(&curD[v], 1); colD[p] = u;
  int q = atomicAdd(&curS[u], 1); dstS[q] = v; mapSD[q] = p;
}

// mean over in-neighbors (original edges only -> skip the self loop entry u==v)
__global__ void k_edge_mean(const float* __restrict__ xin, const int* __restrict__ rowD,
                            const int* __restrict__ colD, float* __restrict__ meanb){
  int v = blockIdx.x, t = threadIdx.x;
  int beg = rowD[v], end = rowD[v+1];
  float acc = 0.f;
  for (int p = beg; p < end; ++p){ int u = colD[p]; if (u != v) acc += xin[u*HH + t]; }
  float dg = (float)(end - beg - 1);
  meanb[v*HH + t] = acc / fmaxf(dg, 1.f);
}

// xout = relu(meanb @ Wrel^T + brel + xin @ Wroot^T), 16 rows/block
__global__ void k_lin(const float* __restrict__ meanb, const float* __restrict__ xin,
                      const float* __restrict__ Wrel, const float* __restrict__ brel,
                      const float* __restrict__ Wroot, float* __restrict__ xout, int rows){
  __shared__ float ms[16][HH];
  __shared__ float xs[16][HH];
  int tid = threadIdx.x;
  int r0 = blockIdx.x * 16;
  for (int l = tid; l < 16*HH; l += 256){
    int r = l >> 7, c = l & 127; int gr = r0 + r;
    float mv = 0.f, xv = 0.f;
    if (gr < rows){ mv = meanb[gr*HH + c]; xv = xin[gr*HH + c]; }
    ms[r][c] = mv; xs[r][c] = xv;
  }
  __syncthreads();
  int h = tid & 127, hgrp = tid >> 7;
  float acc[8] = {0.f,0.f,0.f,0.f,0.f,0.f,0.f,0.f};
  for (int c = 0; c < HH; ++c){
    float wr = Wrel[h*HH + c], wo = Wroot[h*HH + c];
    #pragma unroll
    for (int r = 0; r < 8; ++r) acc[r] += ms[hgrp*8 + r][c]*wr + xs[hgrp*8 + r][c]*wo;
  }
  float bb = brel[h];
  #pragma unroll
  for (int r = 0; r < 8; ++r){
    int gr = r0 + hgrp*8 + r;
    if (gr < rows) xout[gr*HH + h] = fmaxf(acc[r] + bb, 0.f);
  }
}

__global__ void k_colmean(const float* __restrict__ x, int rows, float* __restrict__ outp){
  int t = threadIdx.x;
  int r0 = blockIdx.x * 64;
  int rend = min(rows, r0 + 64);
  float acc = 0.f;
  for (int r = r0; r < rend; ++r) acc += x[r*HH + t];
  atomicAdd(&outp[t], acc / (float)rows);
}

// wA2[c] = sum_h wattA[h]*Wlin[h,c];  wA2[HH] = sum_h blin[h]*wattA[h]
__global__ void k_wprep(const float* __restrict__ Wlin, const float* __restrict__ blin,
                        const float* __restrict__ Watt, float* __restrict__ wA2){
  int c = threadIdx.x;
  float s = 0.f;
  for (int hh = 0; hh < HH; ++hh) s += Watt[hh] * Wlin[hh*HH + c];
  wA2[c] = s;
  if (c == 0){
    float q = 0.f;
    for (int hh = 0; hh < HH; ++hh) q += blin[hh] * Watt[hh];
    wA2[HH] = q;
  }
}

__global__ void k_xdot(const float* __restrict__ x2, const float* __restrict__ Watt, float* __restrict__ xdot){
  __shared__ float red[128];
  int n = blockIdx.x, t = threadIdx.x;
  float v = redSum128(red, t, x2[n*HH + t] * Watt[HH + t]);
  if (t == 0) xdot[n] = v;
}

// per dst node v: xq max -> qdot; edge-softmax stats m, ssum; x_new; per-edge weight wD
__global__ void k_pool(const float* __restrict__ x2, const int* __restrict__ rowD, const int* __restrict__ colD,
                       const float* __restrict__ xdotA, const float* __restrict__ wA2, const float* __restrict__ battp,
                       float* qdotA, float* mA, float* sA, float* __restrict__ xnew, float* __restrict__ wD){
  __shared__ float red[128];
  __shared__ float wmem[128];
  __shared__ int uc[128];
  int v = blockIdx.x, t = threadIdx.x;
  int beg = rowD[v], end = rowD[v+1];
  float batt = battp[0];
  float mx = -3.402823466e38f;
  for (int p = beg; p < end; ++p){ int u = colD[p]; mx = fmaxf(mx, x2[u*HH + t]); }
  float qd = redSum128(red, t, mx * wA2[t]) + wA2[HH];
  float lm = -3.402823466e38f;
  for (int p = beg + t; p < end; p += 128) lm = fmaxf(lm, lrelu02(qd + xdotA[colD[p]] + batt));
  float mm = redMax128(red, t, lm);
  float ls = 0.f;
  for (int p = beg + t; p < end; p += 128) ls += expf(lrelu02(qd + xdotA[colD[p]] + batt) - mm);
  float ss = redSum128(red, t, ls);
  float acc = 0.f;
  for (int basep = beg; basep < end; basep += 128){
    int cnt = min(128, end - basep);
    if (t < cnt){
      int u = colD[basep + t];
      uc[t] = u;
      float w = expf(lrelu02(qd + xdotA[u] + batt) - mm) / ss;
      wmem[t] = w;
      wD[basep + t] = w;
    }
    __syncthreads();
    for (int i = 0; i < cnt; ++i) acc += wmem[i] * x2[uc[i]*HH + t];
    __syncthreads();
  }
  xnew[v*HH + t] = acc;
  if (t == 0){ qdotA[v] = qd; mA[v] = mm; sA[v] = ss; }
}

__global__ void k_abc(const float* __restrict__ xnew, const float* __restrict__ W1, const float* __restrict__ b1,
                      const float* __restrict__ W2, const float* __restrict__ W3, const float* __restrict__ b3,
                      float* aA, float* bA, float* cA){
  __shared__ float red[128];
  int n = blockIdx.x, t = threadIdx.x;
  float xv = xnew[n*HH + t];
  float s1 = redSum128(red, t, xv * W1[t]);
  float s2 = redSum128(red, t, xv * W2[t]);
  float s3 = redSum128(red, t, xv * W3[t]);
  if (t == 0){ aA[n] = s1 + b1[0]; bA[n] = s2; cA[n] = s3 + b3[0]; }
}

__global__ void k_fit(const int* __restrict__ rowD, const int* __restrict__ colD,
                      const float* __restrict__ aA, const float* __restrict__ bA, const float* __restrict__ cA,
                      float* __restrict__ fitA){
  __shared__ float red[128];
  int v = blockIdx.x, t = threadIdx.x;
  int beg = rowD[v], end = rowD[v+1];
  float la = 0.f;
  for (int p = beg + t; p < end; p += 128) la += aA[colD[p]];
  float s = redSum128(red, t, la);
  if (t == 0){
    float g = s - (float)(end - beg) * bA[v] + cA[v];
    fitA[v] = 1.f / (1.f + expf(-g));
  }
}

// one-block bitonic sort of (desc fitness, asc idx) packed u64 keys
__global__ void k_topk(const float* __restrict__ fitA, int* perm, float* fitk, int* kcol){
  __shared__ unsigned long long keys[NN];
  int t = threadIdx.x;
  for (int i = t; i < NN; i += 1024){
    unsigned b = __float_as_uint(fitA[i]);
    unsigned msk = (b & 0x80000000u) ? 0xFFFFFFFFu : 0x80000000u;
    unsigned desc = ~(b ^ msk);
    keys[i] = ((unsigned long long)desc << 32) | (unsigned)i;
  }
  __syncthreads();
  for (int k = 2; k <= NN; k <<= 1){
    for (int j = k >> 1; j > 0; j >>= 1){
      for (int i = t; i < NN; i += 1024){
        int ixj = i ^ j;
        if (ixj > i){
          unsigned long long A = keys[i], B = keys[ixj];
          bool up = ((i & k) == 0);
          bool sw = up ? (A > B) : (A < B);
          if (sw){ keys[i] = B; keys[ixj] = A; }
        }
      }
      __syncthreads();
    }
  }
  for (int r = t; r < NN; r += 1024){
    int idx = (int)(keys[r] & 0xFFFFFFFFu);
    if (r < KC){ perm[r] = idx; fitk[r] = fitA[idx]; kcol[idx] = r; }
    else kcol[idx] = -1;
  }
}

__global__ void k_xp(const float* __restrict__ xnew, const int* __restrict__ perm,
                     const float* __restrict__ fitk, float* __restrict__ xp){
  int idx = blockIdx.x * blockDim.x + threadIdx.x;
  if (idx >= KC*HH) return;
  int r = idx >> 7, h = idx & 127;
  xp[idx] = xnew[perm[r]*HH + h] * fitk[r];
}

// src-ordered per-edge weight + kept-cluster index of target
__global__ void k_wS(const int* __restrict__ mapSD, const int* __restrict__ dstS,
                     const int* __restrict__ kcol, const float* __restrict__ wD,
                     float* __restrict__ wS, int* __restrict__ kS){
  int q = blockIdx.x * blockDim.x + threadIdx.x;
  if (q >= E2) return;
  wS[q] = wD[mapSD[q]];
  kS[q] = kcol[dstS[q]];
}

// U[n,:] = (A @ S)[n,:]  (dense f16 row, stride UP, zero-padded)
__global__ void k_U(const int* __restrict__ rowS, const int* __restrict__ dstS,
                    const float* __restrict__ wS, const int* __restrict__ kS,
                    __half* __restrict__ U){
  __shared__ float acc[UP];   // 14 KB
  int t = threadIdx.x, n = blockIdx.x;
  for (int i = t; i < UP; i += 256) acc[i] = 0.f;
  __syncthreads();
  int b = rowS[n], e = rowS[n+1];
  for (int p = b; p < e; ++p){
    int j = dstS[p];
    int b2 = rowS[j], e2 = rowS[j+1];
    for (int q = b2 + t; q < e2; q += 256){
      int k = kS[q];
      if (k >= 0) atomicAdd(&acc[k], wS[q]);
    }
  }
  __syncthreads();
  __half2* Ur = (__half2*)(U + (size_t)n * UP);
  for (int i = t; i < UP/2; i += 256)
    Ur[i] = __halves2half2(__float2half(acc[2*i]), __float2half(acc[2*i+1]));
}

// A2[k1,:] = sum over in-edges (n -> v1=perm[k1]) of wD[p] * U[n,:]; zero diag; zero-pad cols >= KC
__global__ void k_A2B(const int* __restrict__ rowD, const int* __restrict__ colD,
                      const float* __restrict__ wD, const int* __restrict__ perm,
                      const __half* __restrict__ U, __half* __restrict__ A2){
  __shared__ int ns[64];
  __shared__ float ws[64];
  int t = threadIdx.x;
  int k1 = blockIdx.x;
  int v1 = perm[k1];
  int beg = rowD[v1], end = rowD[v1+1];
  float2 a[7];
  #pragma unroll
  for (int r = 0; r < 7; ++r){ a[r].x = 0.f; a[r].y = 0.f; }
  for (int base = beg; base < end; base += 64){
    int cnt = min(64, end - base);
    if (t < cnt){ ns[t] = colD[base + t]; ws[t] = wD[base + t]; }
    __syncthreads();
    for (int i = 0; i < cnt; ++i){
      const __half2* Un = (const __half2*)(U + (size_t)ns[i] * UP) + t;
      float w = ws[i];
      #pragma unroll
      for (int r = 0; r < 7; ++r){
        float2 f = __half22float2(Un[r*256]);
        a[r].x += w * f.x;
        a[r].y += w * f.y;
      }
    }
    __syncthreads();
  }
  size_t rb = (size_t)k1 * A2P;
  #pragma unroll
  for (int r = 0; r < 7; ++r){
    int k2 = 512*r + 2*t;
    if (k2 + 1 < A2P){
      float lo = (k2 == k1 || k2 >= KC) ? 0.f : a[r].x;
      float hi = (k2 + 1 == k1 || k2 + 1 >= KC) ? 0.f : a[r].y;
      *(__half2*)(A2 + rb + k2) = __halves2half2(__float2half(lo), __float2half(hi));
    }
  }
}

// A2T[i][j] = A2[j][i]; rows j >= KC are zero. Block: 256 j x 32 i.
__global__ void k_tr(const __half* __restrict__ A2, __half* __restrict__ A2T){
  int t = threadIdx.x;
  int jt = blockIdx.x % (A2P/256);   // 13
  int it = blockIdx.x / (A2P/256);   // 104
  int i0 = it*32 + (t >> 6)*8;
  int lane = t & 63;
  _Float16* A2Tf = (_Float16*)A2T;
  #pragma unroll
  for (int sub = 0; sub < 4; ++sub){
    int j = jt*256 + sub*64 + lane;
    f16x8 v;
    if (j < KC) v = *(const f16x8*)(A2 + (size_t)j*A2P + i0);
    else { v = (f16x8)(_Float16)0; }
    #pragma unroll
    for (int e = 0; e < 8; ++e)
      A2Tf[(size_t)(i0 + e)*A2P + j] = v[e];
  }
}

// deg[i] = # nonzeros in A2T row i (j < KC; pad is zero anyway)
__global__ void k_deg2(const __half* __restrict__ A2T, int* __restrict__ deg){
  __shared__ int sred[256];
  int i = blockIdx.x, t = threadIdx.x;
  const _Float16* row = (const _Float16*)(A2T + (size_t)i*A2P);
  int cnt = 0;
  for (int sl = t; sl < A2P/8; sl += 256){
    f16x8 v = *(const f16x8*)(row + sl*8);
    #pragma unroll
    for (int e = 0; e < 8; ++e) cnt += (v[e] != (_Float16)0) ? 1 : 0;
  }
  sred[t] = cnt; __syncthreads();
  #pragma unroll
  for (int s = 128; s > 0; s >>= 1){ if (t < s) sred[t] += sred[t + s]; __syncthreads(); }
  if (t == 0) deg[i] = sred[0];
}

// Xt[h][j] = (f16) X[j][h], zero-padded for j >= KC. Block: 64 j x 128 h.
__global__ void k_xt(const float* __restrict__ X, __half* __restrict__ Xt){
  __shared__ float T2[64][129];
  int t = threadIdx.x;
  int j0 = blockIdx.x * 64;
  for (int l = t; l < 64*32; l += 256){
    int jl = l >> 5, hg = (l & 31) * 4;
    int j = j0 + jl;
    float4 v = make_float4(0.f, 0.f, 0.f, 0.f);
    if (j < KC) v = *(const float4*)(X + (size_t)j*HH + hg);
    T2[jl][hg] = v.x; T2[jl][hg+1] = v.y; T2[jl][hg+2] = v.z; T2[jl][hg+3] = v.w;
  }
  __syncthreads();
  for (int idx = t; idx < 128*64; idx += 256){
    int h = idx >> 6, jl = idx & 63;
    Xt[(size_t)h*A2P + j0 + jl] = __float2half(T2[jl][h]);
  }
}

__global__ void k_zero_agg(float* aggd){
  int i = blockIdx.x * blockDim.x + threadIdx.x;
  if (i < KC*HH) aggd[i] = 0.f;
}

// MFMA dagg: aggd[i,h] += sum_j A2T[i,j]*Xt[h,j].  4 waves, tile 128i x 128h, K-split MMKS.
__global__ void k_mm(const __half* __restrict__ A2Th, const __half* __restrict__ Xth,
                     float* __restrict__ aggd){
  const _Float16* A2T = (const _Float16*)A2Th;
  const _Float16* Xt  = (const _Float16*)Xth;
  int t = threadIdx.x;
  int lane = t & 63, w = t >> 6;
  int it = blockIdx.x % MMIT, ks = blockIdx.x / MMIT;
  int i0 = it*128 + w*32;
  int kk0 = ks * 256;
  f32x4 acc[2][8];
  #pragma unroll
  for (int s = 0; s < 2; ++s)
    #pragma unroll
    for (int ns = 0; ns < 8; ++ns) acc[s][ns] = (f32x4)0.f;
  int l15 = lane & 15, lk = (lane >> 4) * 8;
  for (int kk = kk0; kk < kk0 + 256; kk += 32){
    int krow = kk + lk;
    f16x8 a0 = *(const f16x8*)(A2T + (size_t)(i0 + l15) * A2P + krow);
    f16x8 a1 = *(const f16x8*)(A2T + (size_t)(i0 + 16 + l15) * A2P + krow);
    #pragma unroll
    for (int ns = 0; ns < 8; ++ns){
      f16x8 b = *(const f16x8*)(Xt + (size_t)(ns*16 + l15) * A2P + krow);
      acc[0][ns] = __builtin_amdgcn_mfma_f32_16x16x32_f16(a0, b, acc[0][ns], 0, 0, 0);
      acc[1][ns] = __builtin_amdgcn_mfma_f32_16x16x32_f16(a1, b, acc[1][ns], 0, 0, 0);
    }
  }
  int rbase = (lane >> 4) * 4;
  #pragma unroll
  for (int s = 0; s < 2; ++s){
    #pragma unroll
    for (int r = 0; r < 4; ++r){
      int i = i0 + s*16 + rbase + r;
      if (i < KC){
        #pragma unroll
        for (int ns = 0; ns < 8; ++ns)
          atomicAdd(&aggd[(size_t)i*HH + ns*16 + l15], acc[s][ns][r]);
      }
    }
  }
}

__global__ void k_div(const float* __restrict__ aggd, const int* __restrict__ deg, float* __restrict__ meanb){
  int idx = blockIdx.x * blockDim.x + threadIdx.x;
  if (idx >= KC*HH) return;
  meanb[idx] = aggd[idx] / fmaxf((float)deg[idx >> 7], 1.f);
}

} // namespace

extern "C" void kernel_launch(void* const* d_in, const int* in_sizes, int n_in,
                              void* d_out, int out_size, void* d_ws, size_t ws_size,
                              hipStream_t stream){
  (void)in_sizes; (void)n_in; (void)out_size; (void)ws_size;
  const float* x      = (const float*)d_in[0];
  const int*   ei     = (const int*)d_in[1];
  const float* c0Wrel = (const float*)d_in[2];
  const float* c0brel = (const float*)d_in[3];
  const float* c0Wroot= (const float*)d_in[4];
  const float* c1Wrel = (const float*)d_in[5];
  const float* c1brel = (const float*)d_in[6];
  const float* c1Wroot= (const float*)d_in[7];
  const float* c2Wrel = (const float*)d_in[8];
  const float* c2brel = (const float*)d_in[9];
  const float* c2Wroot= (const float*)d_in[10];
  const float* c3Wrel = (const float*)d_in[11];
  const float* c3brel = (const float*)d_in[12];
  const float* c3Wroot= (const float*)d_in[13];
  const float* Wlin   = (const float*)d_in[14];
  const float* blin   = (const float*)d_in[15];
  const float* Watt   = (const float*)d_in[16];
  const float* batt   = (const float*)d_in[17];
  const float* W1     = (const float*)d_in[18];
  const float* b1     = (const float*)d_in[19];
  const float* W2     = (const float*)d_in[20];
  const float* W3     = (const float*)d_in[21];
  const float* b3     = (const float*)d_in[22];
  float* out = (float*)d_out;

  char* base = (char*)d_ws;
  size_t off = 0;
  auto carve = [&](size_t bytes) -> void* {
    void* p = base + off;
    off += (bytes + 255) & ~(size_t)255;
    return p;
  };
  float* x1    = (float*)carve((size_t)NN*HH*4);
  float* x2b   = (float*)carve((size_t)NN*HH*4);
  float* meanb = (float*)carve((size_t)NN*HH*4);
  float* xnew  = (float*)carve((size_t)NN*HH*4);
  float* xp    = (float*)carve((size_t)KC*HH*4);
  float* x3    = (float*)carve((size_t)KC*HH*4);
  float* x4    = (float*)carve((size_t)KC*HH*4);
  float* aggd  = (float*)carve((size_t)KC*HH*4);
  __half* A2   = (__half*)carve((size_t)KC*A2P*2);   // ~22 MB
  __half* U    = (__half*)carve((size_t)NN*UP*2);    // ~29 MB; dead after k_A2B -> reused as A2T
  __half* A2T  = U;                                   // [A2P][A2P] f16 = 22.2 MB, fits in U's 29.4 MB
  __half* Xt   = (__half*)carve((size_t)HH*A2P*2);   // 852 KB
  float* xdot  = (float*)carve(NN*4);
  float* qdot  = (float*)carve(NN*4);
  float* mmaxA = (float*)carve(NN*4);
  float* ssumA = (float*)carve(NN*4);
  float* aA    = (float*)carve(NN*4);
  float* bA    = (float*)carve(NN*4);
  float* cA    = (float*)carve(NN*4);
  float* fitA  = (float*)carve(NN*4);
  float* fitk  = (float*)carve(KC*4);
  float* wA2   = (float*)carve((HH+1)*4);
  float* wD    = (float*)carve((size_t)E2*4);
  float* wSar  = (float*)carve((size_t)E2*4);
  int* rowD = (int*)carve((NN+1)*4);
  int* rowS = (int*)carve((NN+1)*4);
  int* cntD = (int*)carve(NN*4);
  int* cntS = (int*)carve(NN*4);
  int* curD = (int*)carve(NN*4);
  int* curS = (int*)carve(NN*4);
  int* colD = (int*)carve((size_t)E2*4);
  int* dstS = (int*)carve((size_t)E2*4);
  int* mapSD= (int*)carve((size_t)E2*4);
  int* kSar = (int*)carve((size_t)E2*4);
  int* perm = (int*)carve(KC*4);
  int* kcol = (int*)carve(NN*4);
  int* deg3 = (int*)carve(KC*4);

  k_zero_init<<<NN/256, 256, 0, stream>>>(cntD, cntS, out);
  k_count<<<(E2+255)/256, 256, 0, stream>>>(ei, cntD, cntS);
  k_scan<<<1, 1024, 0, stream>>>(cntD, cntS, rowD, rowS, curD, curS);
  k_scatter<<<(E2+255)/256, 256, 0, stream>>>(ei, curD, curS, colD, dstS, mapSD);

  // conv0
  k_edge_mean<<<NN, 128, 0, stream>>>(x, rowD, colD, meanb);
  k_lin<<<(NN+15)/16, 256, 0, stream>>>(meanb, x, c0Wrel, c0brel, c0Wroot, x1, NN);
  k_colmean<<<(NN+63)/64, 128, 0, stream>>>(x1, NN, out + 0);

  // conv1
  k_edge_mean<<<NN, 128, 0, stream>>>(x1, rowD, colD, meanb);
  k_lin<<<(NN+15)/16, 256, 0, stream>>>(meanb, x1, c1Wrel, c1brel, c1Wroot, x2b, NN);
  k_colmean<<<(NN+63)/64, 128, 0, stream>>>(x2b, NN, out + 128);

  // ASAP pool
  k_wprep<<<1, 128, 0, stream>>>(Wlin, blin, Watt, wA2);
  k_xdot<<<NN, 128, 0, stream>>>(x2b, Watt, xdot);
  k_pool<<<NN, 128, 0, stream>>>(x2b, rowD, colD, xdot, wA2, batt, qdot, mmaxA, ssumA, xnew, wD);
  k_abc<<<NN, 128, 0, stream>>>(xnew, W1, b1, W2, W3, b3, aA, bA, cA);
  k_fit<<<NN, 128, 0, stream>>>(rowD, colD, aA, bA, cA, fitA);
  k_topk<<<1, 1024, 0, stream>>>(fitA, perm, fitk, kcol);
  k_xp<<<(KC*HH+255)/256, 256, 0, stream>>>(xnew, perm, fitk, xp);
  k_wS<<<(E2+255)/256, 256, 0, stream>>>(mapSD, dstS, kcol, wD, wSar, kSar);
  k_U<<<NN, 256, 0, stream>>>(rowS, dstS, wSar, kSar, U);
  k_A2B<<<KC, 256, 0, stream>>>(rowD, colD, wD, perm, U, A2);

  // transpose A2 -> A2T (U is dead now; A2T aliases it), deg from A2T
  k_tr<<<(A2P/256)*(A2P/32), 256, 0, stream>>>(A2, A2T);
  k_deg2<<<KC, 256, 0, stream>>>(A2T, deg3);

  // conv2 (dense, MFMA)
  k_xt<<<A2P/64, 256, 0, stream>>>(xp, Xt);
  k_zero_agg<<<(KC*HH+255)/256, 256, 0, stream>>>(aggd);
  k_mm<<<MMIT*MMKS, 256, 0, stream>>>(A2T, Xt, aggd);
  k_div<<<(KC*HH+255)/256, 256, 0, stream>>>(aggd, deg3, meanb);
  k_lin<<<(KC+15)/16, 256, 0, stream>>>(meanb, xp, c2Wrel, c2brel, c2Wroot, x3, KC);
  k_colmean<<<(KC+63)/64, 128, 0, stream>>>(x3, KC, out + 256);

  // conv3 (dense, MFMA)
  k_xt<<<A2P/64, 256, 0, stream>>>(x3, Xt);
  k_zero_agg<<<(KC*HH+255)/256, 256, 0, stream>>>(aggd);
  k_mm<<<MMIT*MMKS, 256, 0, stream>>>(A2T, Xt, aggd);
  k_div<<<(KC*HH+255)/256, 256, 0, stream>>>(aggd, deg3, meanb);
  k_lin<<<(KC+15)/16, 256, 0, stream>>>(meanb, x3, c3Wrel, c3brel, c3Wroot, x4, KC);
  k_colmean<<<(KC+63)/64, 128, 0, stream>>>(x4, KC, out + 384);
}

// Round 5
// 554.197 us; speedup vs baseline: 3.7723x; 1.0682x over previous
//
#include <hip/hip_runtime.h>
#include <hip/hip_fp16.h>
#include <math.h>

namespace {

constexpr int NN = 4096;
constexpr int EE = 131072;
constexpr int E2 = EE + NN;      // 135168 pool edges (orig + self loops)
constexpr int HH = 128;
constexpr int KC = 3277;         // ceil(0.8*4096)
constexpr int UP = 3584;         // U row stride (7*512, half2-friendly)
constexpr int A2P = 3328;        // A2 row/col padded dim (13*256)

typedef _Float16 f16x8 __attribute__((ext_vector_type(8)));
typedef float f32x4 __attribute__((ext_vector_type(4)));

constexpr int MMIT = A2P / 128;  // 26 i-tiles for MFMA dagg
constexpr int MMKS = 13;         // K-splits (chunk 256 = 8 mfma k-steps)

// k_A2B chunking: 7 column-chunks of 512 (L2-resident 4MB U slice per XCD),
// 16 rows/block -> 205 kt tiles; grid = 205*8, cc = bid%8 (XCD pin), cc=7 idle.
constexpr int A2B_KT = (KC + 15) / 16;   // 205

__device__ __forceinline__ float lrelu02(float x){ return x > 0.f ? x : 0.2f * x; }

__device__ __forceinline__ float redSum128(float* red, int t, float v){
  red[t] = v; __syncthreads();
  #pragma unroll
  for (int s = 64; s > 0; s >>= 1){ if (t < s) red[t] += red[t + s]; __syncthreads(); }
  float r = red[0]; __syncthreads();
  return r;
}
__device__ __forceinline__ float redMax128(float* red, int t, float v){
  red[t] = v; __syncthreads();
  #pragma unroll
  for (int s = 64; s > 0; s >>= 1){ if (t < s) red[t] = fmaxf(red[t], red[t + s]); __syncthreads(); }
  float r = red[0]; __syncthreads();
  return r;
}

__global__ void k_zero_init(int* cntD, int* cntS, float* out){
  int i = blockIdx.x * blockDim.x + threadIdx.x;
  if (i < NN){ cntD[i] = 0; cntS[i] = 0; }
  if (i < 512) out[i] = 0.f;
}

__global__ void k_count(const int* __restrict__ ei, int* cntD, int* cntS){
  int e = blockIdx.x * blockDim.x + threadIdx.x;
  if (e >= E2) return;
  int u, v;
  if (e < EE){ u = ei[e]; v = ei[EE + e]; } else { u = e - EE; v = u; }
  atomicAdd(&cntD[v], 1);
  atomicAdd(&cntS[u], 1);
}

__global__ void k_scan(const int* cntD, const int* cntS, int* rowD, int* rowS, int* curD, int* curS){
  __shared__ int sc[1024];
  int t = threadIdx.x;
  for (int pass = 0; pass < 2; ++pass){
    const int* cnt = pass ? cntS : cntD;
    int* row = pass ? rowS : rowD;
    int* cur = pass ? curS : curD;
    int c0 = cnt[t*4+0], c1 = cnt[t*4+1], c2 = cnt[t*4+2], c3 = cnt[t*4+3];
    int tot = c0 + c1 + c2 + c3;
    sc[t] = tot; __syncthreads();
    for (int offs = 1; offs < 1024; offs <<= 1){
      int v = (t >= offs) ? sc[t - offs] : 0;
      __syncthreads();
      sc[t] += v;
      __syncthreads();
    }
    int excl = sc[t] - tot;
    int r0 = excl, r1 = r0 + c0, r2 = r1 + c1, r3 = r2 + c2;
    row[t*4+0] = r0; row[t*4+1] = r1; row[t*4+2] = r2; row[t*4+3] = r3;
    cur[t*4+0] = r0; cur[t*4+1] = r1; cur[t*4+2] = r2; cur[t*4+3] = r3;
    if (t == 1023) row[NN] = r3 + c3;
    __syncthreads();
  }
}

__global__ void k_scatter(const int* __restrict__ ei, int* curD, int* curS,
                          int* colD, int* dstS, int* mapSD){
  int e = blockIdx.x * blockDim.x + threadIdx.x;
  if (e >= E2) return;
  int u, v;
  if (e < EE){ u = ei[e]; v = ei[EE + e]; } else { u = e - EE; v = u; }
  int p = atomicAdd(&curD[v], 1); colD[p] = u;
  int q = atomicAdd(&curS[u], 1); dstS[q] = v; mapSD[q] = p;
}

// mean over in-neighbors (original edges only -> skip the self loop entry u==v)
__global__ void k_edge_mean(const float* __restrict__ xin, const int* __restrict__ rowD,
                            const int* __restrict__ colD, float* __restrict__ meanb){
  int v = blockIdx.x, t = threadIdx.x;
  int beg = rowD[v], end = rowD[v+1];
  float acc = 0.f;
  for (int p = beg; p < end; ++p){ int u = colD[p]; if (u != v) acc += xin[u*HH + t]; }
  float dg = (float)(end - beg - 1);
  meanb[v*HH + t] = acc / fmaxf(dg, 1.f);
}

// xout = relu(meanb @ Wrel^T + brel + xin @ Wroot^T), 16 rows/block
__global__ void k_lin(const float* __restrict__ meanb, const float* __restrict__ xin,
                      const float* __restrict__ Wrel, const float* __restrict__ brel,
                      const float* __restrict__ Wroot, float* __restrict__ xout, int rows){
  __shared__ float ms[16][HH];
  __shared__ float xs[16][HH];
  int tid = threadIdx.x;
  int r0 = blockIdx.x * 16;
  for (int l = tid; l < 16*HH; l += 256){
    int r = l >> 7, c = l & 127; int gr = r0 + r;
    float mv = 0.f, xv = 0.f;
    if (gr < rows){ mv = meanb[gr*HH + c]; xv = xin[gr*HH + c]; }
    ms[r][c] = mv; xs[r][c] = xv;
  }
  __syncthreads();
  int h = tid & 127, hgrp = tid >> 7;
  float acc[8] = {0.f,0.f,0.f,0.f,0.f,0.f,0.f,0.f};
  for (int c = 0; c < HH; ++c){
    float wr = Wrel[h*HH + c], wo = Wroot[h*HH + c];
    #pragma unroll
    for (int r = 0; r < 8; ++r) acc[r] += ms[hgrp*8 + r][c]*wr + xs[hgrp*8 + r][c]*wo;
  }
  float bb = brel[h];
  #pragma unroll
  for (int r = 0; r < 8; ++r){
    int gr = r0 + hgrp*8 + r;
    if (gr < rows) xout[gr*HH + h] = fmaxf(acc[r] + bb, 0.f);
  }
}

__global__ void k_colmean(const float* __restrict__ x, int rows, float* __restrict__ outp){
  int t = threadIdx.x;
  int r0 = blockIdx.x * 64;
  int rend = min(rows, r0 + 64);
  float acc = 0.f;
  for (int r = r0; r < rend; ++r) acc += x[r*HH + t];
  atomicAdd(&outp[t], acc / (float)rows);
}

// wA2[c] = sum_h wattA[h]*Wlin[h,c];  wA2[HH] = sum_h blin[h]*wattA[h]
__global__ void k_wprep(const float* __restrict__ Wlin, const float* __restrict__ blin,
                        const float* __restrict__ Watt, float* __restrict__ wA2){
  int c = threadIdx.x;
  float s = 0.f;
  for (int hh = 0; hh < HH; ++hh) s += Watt[hh] * Wlin[hh*HH + c];
  wA2[c] = s;
  if (c == 0){
    float q = 0.f;
    for (int hh = 0; hh < HH; ++hh) q += blin[hh] * Watt[hh];
    wA2[HH] = q;
  }
}

__global__ void k_xdot(const float* __restrict__ x2, const float* __restrict__ Watt, float* __restrict__ xdot){
  __shared__ float red[128];
  int n = blockIdx.x, t = threadIdx.x;
  float v = redSum128(red, t, x2[n*HH + t] * Watt[HH + t]);
  if (t == 0) xdot[n] = v;
}

// per dst node v: xq max -> qdot; edge-softmax stats m, ssum; x_new; per-edge weight wD
__global__ void k_pool(const float* __restrict__ x2, const int* __restrict__ rowD, const int* __restrict__ colD,
                       const float* __restrict__ xdotA, const float* __restrict__ wA2, const float* __restrict__ battp,
                       float* qdotA, float* mA, float* sA, float* __restrict__ xnew, float* __restrict__ wD){
  __shared__ float red[128];
  __shared__ float wmem[128];
  __shared__ int uc[128];
  int v = blockIdx.x, t = threadIdx.x;
  int beg = rowD[v], end = rowD[v+1];
  float batt = battp[0];
  float mx = -3.402823466e38f;
  for (int p = beg; p < end; ++p){ int u = colD[p]; mx = fmaxf(mx, x2[u*HH + t]); }
  float qd = redSum128(red, t, mx * wA2[t]) + wA2[HH];
  float lm = -3.402823466e38f;
  for (int p = beg + t; p < end; p += 128) lm = fmaxf(lm, lrelu02(qd + xdotA[colD[p]] + batt));
  float mm = redMax128(red, t, lm);
  float ls = 0.f;
  for (int p = beg + t; p < end; p += 128) ls += expf(lrelu02(qd + xdotA[colD[p]] + batt) - mm);
  float ss = redSum128(red, t, ls);
  float acc = 0.f;
  for (int basep = beg; basep < end; basep += 128){
    int cnt = min(128, end - basep);
    if (t < cnt){
      int u = colD[basep + t];
      uc[t] = u;
      float w = expf(lrelu02(qd + xdotA[u] + batt) - mm) / ss;
      wmem[t] = w;
      wD[basep + t] = w;
    }
    __syncthreads();
    for (int i = 0; i < cnt; ++i) acc += wmem[i] * x2[uc[i]*HH + t];
    __syncthreads();
  }
  xnew[v*HH + t] = acc;
  if (t == 0){ qdotA[v] = qd; mA[v] = mm; sA[v] = ss; }
}

__global__ void k_abc(const float* __restrict__ xnew, const float* __restrict__ W1, const float* __restrict__ b1,
                      const float* __restrict__ W2, const float* __restrict__ W3, const float* __restrict__ b3,
                      float* aA, float* bA, float* cA){
  __shared__ float red[128];
  int n = blockIdx.x, t = threadIdx.x;
  float xv = xnew[n*HH + t];
  float s1 = redSum128(red, t, xv * W1[t]);
  float s2 = redSum128(red, t, xv * W2[t]);
  float s3 = redSum128(red, t, xv * W3[t]);
  if (t == 0){ aA[n] = s1 + b1[0]; bA[n] = s2; cA[n] = s3 + b3[0]; }
}

__global__ void k_fit(const int* __restrict__ rowD, const int* __restrict__ colD,
                      const float* __restrict__ aA, const float* __restrict__ bA, const float* __restrict__ cA,
                      float* __restrict__ fitA){
  __shared__ float red[128];
  int v = blockIdx.x, t = threadIdx.x;
  int beg = rowD[v], end = rowD[v+1];
  float la = 0.f;
  for (int p = beg + t; p < end; p += 128) la += aA[colD[p]];
  float s = redSum128(red, t, la);
  if (t == 0){
    float g = s - (float)(end - beg) * bA[v] + cA[v];
    fitA[v] = 1.f / (1.f + expf(-g));
  }
}

// one-block bitonic sort of (desc fitness, asc idx) packed u64 keys
__global__ void k_topk(const float* __restrict__ fitA, int* perm, float* fitk, int* kcol){
  __shared__ unsigned long long keys[NN];
  int t = threadIdx.x;
  for (int i = t; i < NN; i += 1024){
    unsigned b = __float_as_uint(fitA[i]);
    unsigned msk = (b & 0x80000000u) ? 0xFFFFFFFFu : 0x80000000u;
    unsigned desc = ~(b ^ msk);
    keys[i] = ((unsigned long long)desc << 32) | (unsigned)i;
  }
  __syncthreads();
  for (int k = 2; k <= NN; k <<= 1){
    for (int j = k >> 1; j > 0; j >>= 1){
      for (int i = t; i < NN; i += 1024){
        int ixj = i ^ j;
        if (ixj > i){
          unsigned long long A = keys[i], B = keys[ixj];
          bool up = ((i & k) == 0);
          bool sw = up ? (A > B) : (A < B);
          if (sw){ keys[i] = B; keys[ixj] = A; }
        }
      }
      __syncthreads();
    }
  }
  for (int r = t; r < NN; r += 1024){
    int idx = (int)(keys[r] & 0xFFFFFFFFu);
    if (r < KC){ perm[r] = idx; fitk[r] = fitA[idx]; kcol[idx] = r; }
    else kcol[idx] = -1;
  }
}

__global__ void k_xp(const float* __restrict__ xnew, const int* __restrict__ perm,
                     const float* __restrict__ fitk, float* __restrict__ xp){
  int idx = blockIdx.x * blockDim.x + threadIdx.x;
  if (idx >= KC*HH) return;
  int r = idx >> 7, h = idx & 127;
  xp[idx] = xnew[perm[r]*HH + h] * fitk[r];
}

// src-ordered per-edge weight + kept-cluster index of target
__global__ void k_wS(const int* __restrict__ mapSD, const int* __restrict__ dstS,
                     const int* __restrict__ kcol, const float* __restrict__ wD,
                     float* __restrict__ wS, int* __restrict__ kS){
  int q = blockIdx.x * blockDim.x + threadIdx.x;
  if (q >= E2) return;
  wS[q] = wD[mapSD[q]];
  kS[q] = kcol[dstS[q]];
}

// U[n,:] = (A @ S)[n,:]  (dense f16 row, stride UP, zero-padded)
__global__ void k_U(const int* __restrict__ rowS, const int* __restrict__ dstS,
                    const float* __restrict__ wS, const int* __restrict__ kS,
                    __half* __restrict__ U){
  __shared__ float acc[UP];   // 14 KB
  int t = threadIdx.x, n = blockIdx.x;
  for (int i = t; i < UP; i += 256) acc[i] = 0.f;
  __syncthreads();
  int b = rowS[n], e = rowS[n+1];
  for (int p = b; p < e; ++p){
    int j = dstS[p];
    int b2 = rowS[j], e2 = rowS[j+1];
    for (int q = b2 + t; q < e2; q += 256){
      int k = kS[q];
      if (k >= 0) atomicAdd(&acc[k], wS[q]);
    }
  }
  __syncthreads();
  __half2* Ur = (__half2*)(U + (size_t)n * UP);
  for (int i = t; i < UP/2; i += 256)
    Ur[i] = __halves2half2(__float2half(acc[2*i]), __float2half(acc[2*i+1]));
}

// A2[k1, cc*512 .. +511] = sum over in-edges (n -> v1=perm[k1]) of wD[p] * U[n, chunk]
// grid = A2B_KT * 8; cc = bid%8 (XCD-pinned chunk, cc=7 idle); 4 waves x 4 rows; 64 lanes x f16x8.
__global__ void k_A2B(const int* __restrict__ rowD, const int* __restrict__ colD,
                      const float* __restrict__ wD, const int* __restrict__ perm,
                      const __half* __restrict__ Uh, __half* __restrict__ A2){
  int cc = blockIdx.x & 7;
  if (cc >= 7) return;
  int kt = blockIdx.x >> 3;
  int t = threadIdx.x;
  int w = t >> 6, lane = t & 63;
  int cb = cc * 512;
  const _Float16* U = (const _Float16*)Uh;
  const _Float16* Ul = U + cb + lane * 8;

  float acc[4][8];
  #pragma unroll
  for (int j = 0; j < 4; ++j)
    #pragma unroll
    for (int e = 0; e < 8; ++e) acc[j][e] = 0.f;

  #pragma unroll
  for (int j = 0; j < 4; ++j){
    int k1 = kt*16 + w*4 + j;
    if (k1 >= KC) continue;
    int v1 = perm[k1];
    int beg = rowD[v1], end = rowD[v1+1];
    int p = beg;
    for (; p + 4 <= end; p += 4){
      int n0 = colD[p], n1 = colD[p+1], n2 = colD[p+2], n3 = colD[p+3];
      float w0 = wD[p], w1 = wD[p+1], w2 = wD[p+2], w3 = wD[p+3];
      f16x8 u0 = *(const f16x8*)(Ul + (size_t)n0 * UP);
      f16x8 u1 = *(const f16x8*)(Ul + (size_t)n1 * UP);
      f16x8 u2 = *(const f16x8*)(Ul + (size_t)n2 * UP);
      f16x8 u3 = *(const f16x8*)(Ul + (size_t)n3 * UP);
      #pragma unroll
      for (int e = 0; e < 8; ++e)
        acc[j][e] += w0*(float)u0[e] + w1*(float)u1[e] + w2*(float)u2[e] + w3*(float)u3[e];
    }
    for (; p < end; ++p){
      int n0 = colD[p];
      float w0 = wD[p];
      f16x8 u0 = *(const f16x8*)(Ul + (size_t)n0 * UP);
      #pragma unroll
      for (int e = 0; e < 8; ++e) acc[j][e] += w0*(float)u0[e];
    }
  }

  int col0 = cb + lane * 8;
  if (col0 + 8 > A2P) return;   // chunk 6, lanes >= 32
  #pragma unroll
  for (int j = 0; j < 4; ++j){
    int k1 = kt*16 + w*4 + j;
    if (k1 >= KC) continue;
    f16x8 o;
    #pragma unroll
    for (int e = 0; e < 8; ++e){
      int col = col0 + e;
      float val = (col == k1 || col >= KC) ? 0.f : acc[j][e];
      o[e] = (_Float16)val;
    }
    *(f16x8*)(A2 + (size_t)k1 * A2P + col0) = o;
  }
}

// LDS-tiled transpose: A2T[i][j] = A2[j][i]; rows j >= KC read as zero.
// grid = (A2P/64, A2P/64), 64x64 f16 tiles, coalesced f16x8 both sides.
__global__ void k_tr(const __half* __restrict__ A2, __half* __restrict__ A2T){
  __shared__ float tile[64][65];
  int t = threadIdx.x;
  int i0 = blockIdx.x * 64, j0 = blockIdx.y * 64;
  int sl = t & 7;
  #pragma unroll
  for (int p = 0; p < 2; ++p){
    int jl = (t >> 3) + p*32;
    int j = j0 + jl;
    f16x8 v;
    if (j < KC) v = *(const f16x8*)(A2 + (size_t)j*A2P + i0 + sl*8);
    else v = (f16x8)(_Float16)0;
    #pragma unroll
    for (int e = 0; e < 8; ++e) tile[jl][sl*8 + e] = (float)v[e];
  }
  __syncthreads();
  #pragma unroll
  for (int p = 0; p < 2; ++p){
    int il = (t >> 3) + p*32;
    int i = i0 + il;
    f16x8 o;
    #pragma unroll
    for (int e = 0; e < 8; ++e) o[e] = (_Float16)tile[sl*8 + e][il];
    *(f16x8*)(A2T + (size_t)i*A2P + j0 + sl*8) = o;
  }
}

// deg[i] = # nonzeros in A2T row i (j < KC; pad is zero anyway)
__global__ void k_deg2(const __half* __restrict__ A2T, int* __restrict__ deg){
  __shared__ int sred[256];
  int i = blockIdx.x, t = threadIdx.x;
  const _Float16* row = (const _Float16*)(A2T + (size_t)i*A2P);
  int cnt = 0;
  for (int sl = t; sl < A2P/8; sl += 256){
    f16x8 v = *(const f16x8*)(row + sl*8);
    #pragma unroll
    for (int e = 0; e < 8; ++e) cnt += (v[e] != (_Float16)0) ? 1 : 0;
  }
  sred[t] = cnt; __syncthreads();
  #pragma unroll
  for (int s = 128; s > 0; s >>= 1){ if (t < s) sred[t] += sred[t + s]; __syncthreads(); }
  if (t == 0) deg[i] = sred[0];
}

// Xt[h][j] = (f16) X[j][h], zero-padded for j >= KC. Block: 64 j x 128 h.
__global__ void k_xt(const float* __restrict__ X, __half* __restrict__ Xt){
  __shared__ float T2[64][129];
  int t = threadIdx.x;
  int j0 = blockIdx.x * 64;
  for (int l = t; l < 64*32; l += 256){
    int jl = l >> 5, hg = (l & 31) * 4;
    int j = j0 + jl;
    float4 v = make_float4(0.f, 0.f, 0.f, 0.f);
    if (j < KC) v = *(const float4*)(X + (size_t)j*HH + hg);
    T2[jl][hg] = v.x; T2[jl][hg+1] = v.y; T2[jl][hg+2] = v.z; T2[jl][hg+3] = v.w;
  }
  __syncthreads();
  for (int idx = t; idx < 128*64; idx += 256){
    int h = idx >> 6, jl = idx & 63;
    Xt[(size_t)h*A2P + j0 + jl] = __float2half(T2[jl][h]);
  }
}

__global__ void k_zero_agg(float* aggd){
  int i = blockIdx.x * blockDim.x + threadIdx.x;
  if (i < KC*HH) aggd[i] = 0.f;
}

// MFMA dagg: aggd[i,h] += sum_j A2T[i,j]*Xt[h,j].  4 waves, tile 128i x 128h, K-split MMKS.
__global__ void k_mm(const __half* __restrict__ A2Th, const __half* __restrict__ Xth,
                     float* __restrict__ aggd){
  const _Float16* A2T = (const _Float16*)A2Th;
  const _Float16* Xt  = (const _Float16*)Xth;
  int t = threadIdx.x;
  int lane = t & 63, w = t >> 6;
  int it = blockIdx.x % MMIT, ks = blockIdx.x / MMIT;
  int i0 = it*128 + w*32;
  int kk0 = ks * 256;
  f32x4 acc[2][8];
  #pragma unroll
  for (int s = 0; s < 2; ++s)
    #pragma unroll
    for (int ns = 0; ns < 8; ++ns) acc[s][ns] = (f32x4)0.f;
  int l15 = lane & 15, lk = (lane >> 4) * 8;
  for (int kk = kk0; kk < kk0 + 256; kk += 32){
    int krow = kk + lk;
    f16x8 a0 = *(const f16x8*)(A2T + (size_t)(i0 + l15) * A2P + krow);
    f16x8 a1 = *(const f16x8*)(A2T + (size_t)(i0 + 16 + l15) * A2P + krow);
    #pragma unroll
    for (int ns = 0; ns < 8; ++ns){
      f16x8 b = *(const f16x8*)(Xt + (size_t)(ns*16 + l15) * A2P + krow);
      acc[0][ns] = __builtin_amdgcn_mfma_f32_16x16x32_f16(a0, b, acc[0][ns], 0, 0, 0);
      acc[1][ns] = __builtin_amdgcn_mfma_f32_16x16x32_f16(a1, b, acc[1][ns], 0, 0, 0);
    }
  }
  int rbase = (lane >> 4) * 4;
  #pragma unroll
  for (int s = 0; s < 2; ++s){
    #pragma unroll
    for (int r = 0; r < 4; ++r){
      int i = i0 + s*16 + rbase + r;
      if (i < KC){
        #pragma unroll
        for (int ns = 0; ns < 8; ++ns)
          atomicAdd(&aggd[(size_t)i*HH + ns*16 + l15], acc[s][ns][r]);
      }
    }
  }
}

__global__ void k_div(const float* __restrict__ aggd, const int* __restrict__ deg, float* __restrict__ meanb){
  int idx = blockIdx.x * blockDim.x + threadIdx.x;
  if (idx >= KC*HH) return;
  meanb[idx] = aggd[idx] / fmaxf((float)deg[idx >> 7], 1.f);
}

} // namespace

extern "C" void kernel_launch(void* const* d_in, const int* in_sizes, int n_in,
                              void* d_out, int out_size, void* d_ws, size_t ws_size,
                              hipStream_t stream){
  (void)in_sizes; (void)n_in; (void)out_size; (void)ws_size;
  const float* x      = (const float*)d_in[0];
  const int*   ei     = (const int*)d_in[1];
  const float* c0Wrel = (const float*)d_in[2];
  const float* c0brel = (const float*)d_in[3];
  const float* c0Wroot= (const float*)d_in[4];
  const float* c1Wrel = (const float*)d_in[5];
  const float* c1brel = (const float*)d_in[6];
  const float* c1Wroot= (const float*)d_in[7];
  const float* c2Wrel = (const float*)d_in[8];
  const float* c2brel = (const float*)d_in[9];
  const float* c2Wroot= (const float*)d_in[10];
  const float* c3Wrel = (const float*)d_in[11];
  const float* c3brel = (const float*)d_in[12];
  const float* c3Wroot= (const float*)d_in[13];
  const float* Wlin   = (const float*)d_in[14];
  const float* blin   = (const float*)d_in[15];
  const float* Watt   = (const float*)d_in[16];
  const float* batt   = (const float*)d_in[17];
  const float* W1     = (const float*)d_in[18];
  const float* b1     = (const float*)d_in[19];
  const float* W2     = (const float*)d_in[20];
  const float* W3     = (const float*)d_in[21];
  const float* b3     = (const float*)d_in[22];
  float* out = (float*)d_out;

  char* base = (char*)d_ws;
  size_t off = 0;
  auto carve = [&](size_t bytes) -> void* {
    void* p = base + off;
    off += (bytes + 255) & ~(size_t)255;
    return p;
  };
  float* x1    = (float*)carve((size_t)NN*HH*4);
  float* x2b   = (float*)carve((size_t)NN*HH*4);
  float* meanb = (float*)carve((size_t)NN*HH*4);
  float* xnew  = (float*)carve((size_t)NN*HH*4);
  float* xp    = (float*)carve((size_t)KC*HH*4);
  float* x3    = (float*)carve((size_t)KC*HH*4);
  float* x4    = (float*)carve((size_t)KC*HH*4);
  float* aggd  = (float*)carve((size_t)KC*HH*4);
  __half* A2   = (__half*)carve((size_t)KC*A2P*2);   // ~22 MB
  __half* U    = (__half*)carve((size_t)NN*UP*2);    // ~29 MB; dead after k_A2B -> reused as A2T
  __half* A2T  = U;                                   // [A2P][A2P] f16 = 22.2 MB, fits in U's 29.4 MB
  __half* Xt   = (__half*)carve((size_t)HH*A2P*2);   // 852 KB
  float* xdot  = (float*)carve(NN*4);
  float* qdot  = (float*)carve(NN*4);
  float* mmaxA = (float*)carve(NN*4);
  float* ssumA = (float*)carve(NN*4);
  float* aA    = (float*)carve(NN*4);
  float* bA    = (float*)carve(NN*4);
  float* cA    = (float*)carve(NN*4);
  float* fitA  = (float*)carve(NN*4);
  float* fitk  = (float*)carve(KC*4);
  float* wA2   = (float*)carve((HH+1)*4);
  float* wD    = (float*)carve((size_t)E2*4);
  float* wSar  = (float*)carve((size_t)E2*4);
  int* rowD = (int*)carve((NN+1)*4);
  int* rowS = (int*)carve((NN+1)*4);
  int* cntD = (int*)carve(NN*4);
  int* cntS = (int*)carve(NN*4);
  int* curD = (int*)carve(NN*4);
  int* curS = (int*)carve(NN*4);
  int* colD = (int*)carve((size_t)E2*4);
  int* dstS = (int*)carve((size_t)E2*4);
  int* mapSD= (int*)carve((size_t)E2*4);
  int* kSar = (int*)carve((size_t)E2*4);
  int* perm = (int*)carve(KC*4);
  int* kcol = (int*)carve(NN*4);
  int* deg3 = (int*)carve(KC*4);

  k_zero_init<<<NN/256, 256, 0, stream>>>(cntD, cntS, out);
  k_count<<<(E2+255)/256, 256, 0, stream>>>(ei, cntD, cntS);
  k_scan<<<1, 1024, 0, stream>>>(cntD, cntS, rowD, rowS, curD, curS);
  k_scatter<<<(E2+255)/256, 256, 0, stream>>>(ei, curD, curS, colD, dstS, mapSD);

  // conv0
  k_edge_mean<<<NN, 128, 0, stream>>>(x, rowD, colD, meanb);
  k_lin<<<(NN+15)/16, 256, 0, stream>>>(meanb, x, c0Wrel, c0brel, c0Wroot, x1, NN);
  k_colmean<<<(NN+63)/64, 128, 0, stream>>>(x1, NN, out + 0);

  // conv1
  k_edge_mean<<<NN, 128, 0, stream>>>(x1, rowD, colD, meanb);
  k_lin<<<(NN+15)/16, 256, 0, stream>>>(meanb, x1, c1Wrel, c1brel, c1Wroot, x2b, NN);
  k_colmean<<<(NN+63)/64, 128, 0, stream>>>(x2b, NN, out + 128);

  // ASAP pool
  k_wprep<<<1, 128, 0, stream>>>(Wlin, blin, Watt, wA2);
  k_xdot<<<NN, 128, 0, stream>>>(x2b, Watt, xdot);
  k_pool<<<NN, 128, 0, stream>>>(x2b, rowD, colD, xdot, wA2, batt, qdot, mmaxA, ssumA, xnew, wD);
  k_abc<<<NN, 128, 0, stream>>>(xnew, W1, b1, W2, W3, b3, aA, bA, cA);
  k_fit<<<NN, 128, 0, stream>>>(rowD, colD, aA, bA, cA, fitA);
  k_topk<<<1, 1024, 0, stream>>>(fitA, perm, fitk, kcol);
  k_xp<<<(KC*HH+255)/256, 256, 0, stream>>>(xnew, perm, fitk, xp);
  k_wS<<<(E2+255)/256, 256, 0, stream>>>(mapSD, dstS, kcol, wD, wSar, kSar);
  k_U<<<NN, 256, 0, stream>>>(rowS, dstS, wSar, kSar, U);
  k_A2B<<<A2B_KT*8, 256, 0, stream>>>(rowD, colD, wD, perm, U, A2);

  // transpose A2 -> A2T (U is dead now; A2T aliases it), deg from A2T
  k_tr<<<dim3(A2P/64, A2P/64), 256, 0, stream>>>(A2, A2T);
  k_deg2<<<KC, 256, 0, stream>>>(A2T, deg3);

  // conv2 (dense, MFMA)
  k_xt<<<A2P/64, 256, 0, stream>>>(xp, Xt);
  k_zero_agg<<<(KC*HH+255)/256, 256, 0, stream>>>(aggd);
  k_mm<<<MMIT*MMKS, 256, 0, stream>>>(A2T, Xt, aggd);
  k_div<<<(KC*HH+255)/256, 256, 0, stream>>>(aggd, deg3, meanb);
  k_lin<<<(KC+15)/16, 256, 0, stream>>>(meanb, xp, c2Wrel, c2brel, c2Wroot, x3, KC);
  k_colmean<<<(KC+63)/64, 128, 0, stream>>>(x3, KC, out + 256);

  // conv3 (dense, MFMA)
  k_xt<<<A2P/64, 256, 0, stream>>>(x3, Xt);
  k_zero_agg<<<(KC*HH+255)/256, 256, 0, stream>>>(aggd);
  k_mm<<<MMIT*MMKS, 256, 0, stream>>>(A2T, Xt, aggd);
  k_div<<<(KC*HH+255)/256, 256, 0, stream>>>(aggd, deg3, meanb);
  k_lin<<<(KC+15)/16, 256, 0, stream>>>(meanb, x3, c3Wrel, c3brel, c3Wroot, x4, KC);
  k_colmean<<<(KC+63)/64, 128, 0, stream>>>(x4, KC, out + 384);
}

// Round 6
// 526.559 us; speedup vs baseline: 3.9703x; 1.0525x over previous
//
#include <hip/hip_runtime.h>
#include <hip/hip_fp16.h>
#include <math.h>

namespace {

constexpr int NN = 4096;
constexpr int EE = 131072;
constexpr int E2 = EE + NN;      // 135168 pool edges (orig + self loops)
constexpr int HH = 128;
constexpr int KC = 3277;         // ceil(0.8*4096)
constexpr int UP = 3584;         // U row stride (7*512)
constexpr int A2P = 3328;        // A2 row/col padded dim (13*256)

typedef _Float16 f16x8 __attribute__((ext_vector_type(8)));
typedef float f32x4 __attribute__((ext_vector_type(4)));

// k_A2B: 7 column-chunks of 512 (4MB L2-resident U slice per XCD), wave-per-row.
constexpr int A2B_RT = (KC + 3) / 4;   // 820 row-groups (4 waves/block)

__device__ __forceinline__ float lrelu02(float x){ return x > 0.f ? x : 0.2f * x; }

__device__ __forceinline__ float redSum128(float* red, int t, float v){
  red[t] = v; __syncthreads();
  #pragma unroll
  for (int s = 64; s > 0; s >>= 1){ if (t < s) red[t] += red[t + s]; __syncthreads(); }
  float r = red[0]; __syncthreads();
  return r;
}
__device__ __forceinline__ float redMax128(float* red, int t, float v){
  red[t] = v; __syncthreads();
  #pragma unroll
  for (int s = 64; s > 0; s >>= 1){ if (t < s) red[t] = fmaxf(red[t], red[t + s]); __syncthreads(); }
  float r = red[0]; __syncthreads();
  return r;
}

__global__ void k_zero_init(int* cntD, int* cntS, int* deg, float* out){
  int i = blockIdx.x * blockDim.x + threadIdx.x;
  if (i < NN){ cntD[i] = 0; cntS[i] = 0; }
  if (i < KC) deg[i] = 0;
  if (i < 512) out[i] = 0.f;
}

__global__ void k_count(const int* __restrict__ ei, int* cntD, int* cntS){
  int e = blockIdx.x * blockDim.x + threadIdx.x;
  if (e >= E2) return;
  int u, v;
  if (e < EE){ u = ei[e]; v = ei[EE + e]; } else { u = e - EE; v = u; }
  atomicAdd(&cntD[v], 1);
  atomicAdd(&cntS[u], 1);
}

__global__ void k_scan(const int* cntD, const int* cntS, int* rowD, int* rowS, int* curD, int* curS){
  __shared__ int sc[1024];
  int t = threadIdx.x;
  for (int pass = 0; pass < 2; ++pass){
    const int* cnt = pass ? cntS : cntD;
    int* row = pass ? rowS : rowD;
    int* cur = pass ? curS : curD;
    int c0 = cnt[t*4+0], c1 = cnt[t*4+1], c2 = cnt[t*4+2], c3 = cnt[t*4+3];
    int tot = c0 + c1 + c2 + c3;
    sc[t] = tot; __syncthreads();
    for (int offs = 1; offs < 1024; offs <<= 1){
      int v = (t >= offs) ? sc[t - offs] : 0;
      __syncthreads();
      sc[t] += v;
      __syncthreads();
    }
    int excl = sc[t] - tot;
    int r0 = excl, r1 = r0 + c0, r2 = r1 + c1, r3 = r2 + c2;
    row[t*4+0] = r0; row[t*4+1] = r1; row[t*4+2] = r2; row[t*4+3] = r3;
    cur[t*4+0] = r0; cur[t*4+1] = r1; cur[t*4+2] = r2; cur[t*4+3] = r3;
    if (t == 1023) row[NN] = r3 + c3;
    __syncthreads();
  }
}

__global__ void k_scatter(const int* __restrict__ ei, int* curD, int* curS,
                          int* colD, int* dstS, int* mapSD){
  int e = blockIdx.x * blockDim.x + threadIdx.x;
  if (e >= E2) return;
  int u, v;
  if (e < EE){ u = ei[e]; v = ei[EE + e]; } else { u = e - EE; v = u; }
  int p = atomicAdd(&curD[v], 1); colD[p] = u;
  int q = atomicAdd(&curS[u], 1); dstS[q] = v; mapSD[q] = p;
}

// mean over in-neighbors (original edges only -> skip the self loop entry u==v)
__global__ void k_edge_mean(const float* __restrict__ xin, const int* __restrict__ rowD,
                            const int* __restrict__ colD, float* __restrict__ meanb){
  int v = blockIdx.x, t = threadIdx.x;
  int beg = rowD[v], end = rowD[v+1];
  float acc = 0.f;
  int p = beg;
  for (; p + 4 <= end; p += 4){
    int u0 = colD[p], u1 = colD[p+1], u2 = colD[p+2], u3 = colD[p+3];
    float a0 = xin[(size_t)u0*HH + t];
    float a1 = xin[(size_t)u1*HH + t];
    float a2 = xin[(size_t)u2*HH + t];
    float a3 = xin[(size_t)u3*HH + t];
    if (u0 != v) acc += a0;
    if (u1 != v) acc += a1;
    if (u2 != v) acc += a2;
    if (u3 != v) acc += a3;
  }
  for (; p < end; ++p){ int u = colD[p]; if (u != v) acc += xin[(size_t)u*HH + t]; }
  float dg = (float)(end - beg - 1);
  meanb[v*HH + t] = acc / fmaxf(dg, 1.f);
}

// xout = relu(meanb @ Wrel^T + brel + xin @ Wroot^T), 16 rows/block
__global__ void k_lin(const float* __restrict__ meanb, const float* __restrict__ xin,
                      const float* __restrict__ Wrel, const float* __restrict__ brel,
                      const float* __restrict__ Wroot, float* __restrict__ xout, int rows){
  __shared__ float ms[16][HH];
  __shared__ float xs[16][HH];
  int tid = threadIdx.x;
  int r0 = blockIdx.x * 16;
  for (int l = tid; l < 16*HH; l += 256){
    int r = l >> 7, c = l & 127; int gr = r0 + r;
    float mv = 0.f, xv = 0.f;
    if (gr < rows){ mv = meanb[gr*HH + c]; xv = xin[gr*HH + c]; }
    ms[r][c] = mv; xs[r][c] = xv;
  }
  __syncthreads();
  int h = tid & 127, hgrp = tid >> 7;
  float acc[8] = {0.f,0.f,0.f,0.f,0.f,0.f,0.f,0.f};
  for (int c = 0; c < HH; ++c){
    float wr = Wrel[h*HH + c], wo = Wroot[h*HH + c];
    #pragma unroll
    for (int r = 0; r < 8; ++r) acc[r] += ms[hgrp*8 + r][c]*wr + xs[hgrp*8 + r][c]*wo;
  }
  float bb = brel[h];
  #pragma unroll
  for (int r = 0; r < 8; ++r){
    int gr = r0 + hgrp*8 + r;
    if (gr < rows) xout[gr*HH + h] = fmaxf(acc[r] + bb, 0.f);
  }
}

__global__ void k_colmean(const float* __restrict__ x, int rows, float* __restrict__ outp){
  int t = threadIdx.x;
  int r0 = blockIdx.x * 64;
  int rend = min(rows, r0 + 64);
  float acc = 0.f;
  for (int r = r0; r < rend; ++r) acc += x[r*HH + t];
  atomicAdd(&outp[t], acc / (float)rows);
}

// wA2[c] = sum_h wattA[h]*Wlin[h,c];  wA2[HH] = sum_h blin[h]*wattA[h]
__global__ void k_wprep(const float* __restrict__ Wlin, const float* __restrict__ blin,
                        const float* __restrict__ Watt, float* __restrict__ wA2){
  int c = threadIdx.x;
  float s = 0.f;
  for (int hh = 0; hh < HH; ++hh) s += Watt[hh] * Wlin[hh*HH + c];
  wA2[c] = s;
  if (c == 0){
    float q = 0.f;
    for (int hh = 0; hh < HH; ++hh) q += blin[hh] * Watt[hh];
    wA2[HH] = q;
  }
}

__global__ void k_xdot(const float* __restrict__ x2, const float* __restrict__ Watt, float* __restrict__ xdot){
  __shared__ float red[128];
  int n = blockIdx.x, t = threadIdx.x;
  float v = redSum128(red, t, x2[n*HH + t] * Watt[HH + t]);
  if (t == 0) xdot[n] = v;
}

// per dst node v: xq max -> qdot; edge-softmax stats m, ssum; x_new; per-edge weight wD
__global__ void k_pool(const float* __restrict__ x2, const int* __restrict__ rowD, const int* __restrict__ colD,
                       const float* __restrict__ xdotA, const float* __restrict__ wA2, const float* __restrict__ battp,
                       float* qdotA, float* mA, float* sA, float* __restrict__ xnew, float* __restrict__ wD){
  __shared__ float red[128];
  __shared__ float wmem[128];
  __shared__ int uc[128];
  int v = blockIdx.x, t = threadIdx.x;
  int beg = rowD[v], end = rowD[v+1];
  float batt = battp[0];
  float mx = -3.402823466e38f;
  int p = beg;
  for (; p + 4 <= end; p += 4){
    float a0 = x2[(size_t)colD[p]*HH + t];
    float a1 = x2[(size_t)colD[p+1]*HH + t];
    float a2 = x2[(size_t)colD[p+2]*HH + t];
    float a3 = x2[(size_t)colD[p+3]*HH + t];
    mx = fmaxf(fmaxf(fmaxf(fmaxf(mx, a0), a1), a2), a3);
  }
  for (; p < end; ++p) mx = fmaxf(mx, x2[(size_t)colD[p]*HH + t]);
  float qd = redSum128(red, t, mx * wA2[t]) + wA2[HH];
  float lm = -3.402823466e38f;
  for (p = beg + t; p < end; p += 128) lm = fmaxf(lm, lrelu02(qd + xdotA[colD[p]] + batt));
  float mm = redMax128(red, t, lm);
  float ls = 0.f;
  for (p = beg + t; p < end; p += 128) ls += expf(lrelu02(qd + xdotA[colD[p]] + batt) - mm);
  float ss = redSum128(red, t, ls);
  float acc = 0.f;
  for (int basep = beg; basep < end; basep += 128){
    int cnt = min(128, end - basep);
    if (t < cnt){
      int u = colD[basep + t];
      uc[t] = u;
      float w = expf(lrelu02(qd + xdotA[u] + batt) - mm) / ss;
      wmem[t] = w;
      wD[basep + t] = w;
    }
    __syncthreads();
    int i = 0;
    for (; i + 4 <= cnt; i += 4){
      float a0 = x2[(size_t)uc[i]*HH + t];
      float a1 = x2[(size_t)uc[i+1]*HH + t];
      float a2 = x2[(size_t)uc[i+2]*HH + t];
      float a3 = x2[(size_t)uc[i+3]*HH + t];
      acc += wmem[i]*a0 + wmem[i+1]*a1 + wmem[i+2]*a2 + wmem[i+3]*a3;
    }
    for (; i < cnt; ++i) acc += wmem[i] * x2[(size_t)uc[i]*HH + t];
    __syncthreads();
  }
  xnew[v*HH + t] = acc;
  if (t == 0){ qdotA[v] = qd; mA[v] = mm; sA[v] = ss; }
}

__global__ void k_abc(const float* __restrict__ xnew, const float* __restrict__ W1, const float* __restrict__ b1,
                      const float* __restrict__ W2, const float* __restrict__ W3, const float* __restrict__ b3,
                      float* aA, float* bA, float* cA){
  __shared__ float red[128];
  int n = blockIdx.x, t = threadIdx.x;
  float xv = xnew[n*HH + t];
  float s1 = redSum128(red, t, xv * W1[t]);
  float s2 = redSum128(red, t, xv * W2[t]);
  float s3 = redSum128(red, t, xv * W3[t]);
  if (t == 0){ aA[n] = s1 + b1[0]; bA[n] = s2; cA[n] = s3 + b3[0]; }
}

__global__ void k_fit(const int* __restrict__ rowD, const int* __restrict__ colD,
                      const float* __restrict__ aA, const float* __restrict__ bA, const float* __restrict__ cA,
                      float* __restrict__ fitA){
  __shared__ float red[128];
  int v = blockIdx.x, t = threadIdx.x;
  int beg = rowD[v], end = rowD[v+1];
  float la = 0.f;
  for (int p = beg + t; p < end; p += 128) la += aA[colD[p]];
  float s = redSum128(red, t, la);
  if (t == 0){
    float g = s - (float)(end - beg) * bA[v] + cA[v];
    fitA[v] = 1.f / (1.f + expf(-g));
  }
}

// one-block bitonic sort of (desc fitness, asc idx) packed u64 keys
__global__ void k_topk(const float* __restrict__ fitA, int* perm, float* fitk, int* kcol){
  __shared__ unsigned long long keys[NN];
  int t = threadIdx.x;
  for (int i = t; i < NN; i += 1024){
    unsigned b = __float_as_uint(fitA[i]);
    unsigned msk = (b & 0x80000000u) ? 0xFFFFFFFFu : 0x80000000u;
    unsigned desc = ~(b ^ msk);
    keys[i] = ((unsigned long long)desc << 32) | (unsigned)i;
  }
  __syncthreads();
  for (int k = 2; k <= NN; k <<= 1){
    for (int j = k >> 1; j > 0; j >>= 1){
      for (int i = t; i < NN; i += 1024){
        int ixj = i ^ j;
        if (ixj > i){
          unsigned long long A = keys[i], B = keys[ixj];
          bool up = ((i & k) == 0);
          bool sw = up ? (A > B) : (A < B);
          if (sw){ keys[i] = B; keys[ixj] = A; }
        }
      }
      __syncthreads();
    }
  }
  for (int r = t; r < NN; r += 1024){
    int idx = (int)(keys[r] & 0xFFFFFFFFu);
    if (r < KC){ perm[r] = idx; fitk[r] = fitA[idx]; kcol[idx] = r; }
    else kcol[idx] = -1;
  }
}

__global__ void k_xp(const float* __restrict__ xnew, const int* __restrict__ perm,
                     const float* __restrict__ fitk, float* __restrict__ xp){
  int idx = blockIdx.x * blockDim.x + threadIdx.x;
  if (idx >= KC*HH) return;
  int r = idx >> 7, h = idx & 127;
  xp[idx] = xnew[perm[r]*HH + h] * fitk[r];
}

// src-ordered per-edge weight + kept-cluster index of target
__global__ void k_wS(const int* __restrict__ mapSD, const int* __restrict__ dstS,
                     const int* __restrict__ kcol, const float* __restrict__ wD,
                     float* __restrict__ wS, int* __restrict__ kS){
  int q = blockIdx.x * blockDim.x + threadIdx.x;
  if (q >= E2) return;
  wS[q] = wD[mapSD[q]];
  kS[q] = kcol[dstS[q]];
}

// U[n,:] = (A @ S)[n,:]  (dense f16 row, stride UP, zero-padded)
__global__ void k_U(const int* __restrict__ rowS, const int* __restrict__ dstS,
                    const float* __restrict__ wS, const int* __restrict__ kS,
                    __half* __restrict__ U){
  __shared__ float acc[UP];   // 14 KB
  int t = threadIdx.x, n = blockIdx.x;
  for (int i = t; i < UP; i += 256) acc[i] = 0.f;
  __syncthreads();
  int b = rowS[n], e = rowS[n+1];
  for (int p = b; p < e; ++p){
    int j = dstS[p];
    int b2 = rowS[j], e2 = rowS[j+1];
    for (int q = b2 + t; q < e2; q += 256){
      int k = kS[q];
      if (k >= 0) atomicAdd(&acc[k], wS[q]);
    }
  }
  __syncthreads();
  __half2* Ur = (__half2*)(U + (size_t)n * UP);
  for (int i = t; i < UP/2; i += 256)
    Ur[i] = __halves2half2(__float2half(acc[2*i]), __float2half(acc[2*i+1]));
}

// A2[k1, cc*512 .. +511] = sum over in-edges of wD * U[n, chunk]; wave-per-row, 8-deep ILP.
// grid = A2B_RT*8; cc = bid&7 (XCD pin, cc=7 idle); fused per-row nonzero count -> deg.
__global__ void k_A2B(const int* __restrict__ rowD, const int* __restrict__ colD,
                      const float* __restrict__ wD, const int* __restrict__ perm,
                      const __half* __restrict__ Uh, __half* __restrict__ A2,
                      int* __restrict__ deg){
  int cc = blockIdx.x & 7;
  if (cc >= 7) return;
  int rt = blockIdx.x >> 3;
  int t = threadIdx.x;
  int w = t >> 6, lane = t & 63;
  int k1 = rt*4 + w;
  if (k1 >= KC) return;
  int cb = cc * 512;
  const _Float16* Ul = (const _Float16*)Uh + cb + lane * 8;

  float acc[8] = {0.f,0.f,0.f,0.f,0.f,0.f,0.f,0.f};
  int v1 = perm[k1];
  int beg = rowD[v1], end = rowD[v1+1];

  auto edge1 = [&](int pp){
    int n0 = colD[pp]; float w0 = wD[pp];
    f16x8 u0 = *(const f16x8*)(Ul + (size_t)n0 * UP);
    #pragma unroll
    for (int e = 0; e < 8; ++e) acc[e] += w0 * (float)u0[e];
  };

  int p = beg;
  int pre = (4 - (p & 3)) & 3;
  if (pre > end - p) pre = end - p;
  for (int z = 0; z < pre; ++z){ edge1(p); ++p; }
  for (; p + 8 <= end; p += 8){
    int4 nA = *(const int4*)(colD + p);
    int4 nB = *(const int4*)(colD + p + 4);
    float4 wA = *(const float4*)(wD + p);
    float4 wB = *(const float4*)(wD + p + 4);
    f16x8 u0 = *(const f16x8*)(Ul + (size_t)nA.x * UP);
    f16x8 u1 = *(const f16x8*)(Ul + (size_t)nA.y * UP);
    f16x8 u2 = *(const f16x8*)(Ul + (size_t)nA.z * UP);
    f16x8 u3 = *(const f16x8*)(Ul + (size_t)nA.w * UP);
    f16x8 u4 = *(const f16x8*)(Ul + (size_t)nB.x * UP);
    f16x8 u5 = *(const f16x8*)(Ul + (size_t)nB.y * UP);
    f16x8 u6 = *(const f16x8*)(Ul + (size_t)nB.z * UP);
    f16x8 u7 = *(const f16x8*)(Ul + (size_t)nB.w * UP);
    #pragma unroll
    for (int e = 0; e < 8; ++e){
      acc[e] += wA.x*(float)u0[e] + wA.y*(float)u1[e] + wA.z*(float)u2[e] + wA.w*(float)u3[e]
              + wB.x*(float)u4[e] + wB.y*(float)u5[e] + wB.z*(float)u6[e] + wB.w*(float)u7[e];
    }
  }
  for (; p + 4 <= end; p += 4){
    int4 nA = *(const int4*)(colD + p);
    float4 wA = *(const float4*)(wD + p);
    f16x8 u0 = *(const f16x8*)(Ul + (size_t)nA.x * UP);
    f16x8 u1 = *(const f16x8*)(Ul + (size_t)nA.y * UP);
    f16x8 u2 = *(const f16x8*)(Ul + (size_t)nA.z * UP);
    f16x8 u3 = *(const f16x8*)(Ul + (size_t)nA.w * UP);
    #pragma unroll
    for (int e = 0; e < 8; ++e)
      acc[e] += wA.x*(float)u0[e] + wA.y*(float)u1[e] + wA.z*(float)u2[e] + wA.w*(float)u3[e];
  }
  for (; p < end; ++p) edge1(p);

  int col0 = cb + lane * 8;
  f16x8 o;
  int c = 0;
  #pragma unroll
  for (int e = 0; e < 8; ++e){
    int col = col0 + e;
    float val = (col == k1 || col >= KC) ? 0.f : acc[e];
    _Float16 hv = (_Float16)val;
    o[e] = hv;
    c += (hv != (_Float16)0) ? 1 : 0;
  }
  #pragma unroll
  for (int s = 32; s > 0; s >>= 1) c += __shfl_down(c, s);
  if (lane == 0) atomicAdd(&deg[k1], c);
  if (col0 + 8 <= A2P)
    *(f16x8*)(A2 + (size_t)k1 * A2P + col0) = o;
}

// LDS-tiled transpose: A2T[i][j] = A2[j][i]; rows j >= KC read as zero.
__global__ void k_tr(const __half* __restrict__ A2, __half* __restrict__ A2T){
  __shared__ float tile[64][65];
  int t = threadIdx.x;
  int i0 = blockIdx.x * 64, j0 = blockIdx.y * 64;
  int sl = t & 7;
  #pragma unroll
  for (int p = 0; p < 2; ++p){
    int jl = (t >> 3) + p*32;
    int j = j0 + jl;
    f16x8 v;
    if (j < KC) v = *(const f16x8*)(A2 + (size_t)j*A2P + i0 + sl*8);
    else v = (f16x8)(_Float16)0;
    #pragma unroll
    for (int e = 0; e < 8; ++e) tile[jl][sl*8 + e] = (float)v[e];
  }
  __syncthreads();
  #pragma unroll
  for (int p = 0; p < 2; ++p){
    int il = (t >> 3) + p*32;
    int i = i0 + il;
    f16x8 o;
    #pragma unroll
    for (int e = 0; e < 8; ++e) o[e] = (_Float16)tile[sl*8 + e][il];
    *(f16x8*)(A2T + (size_t)i*A2P + j0 + sl*8) = o;
  }
}

// Xt[h][j] = (f16) X[j][h], zero-padded for j >= KC. Block: 64 j x 128 h.
__global__ void k_xt(const float* __restrict__ X, __half* __restrict__ Xt){
  __shared__ float T2[64][129];
  int t = threadIdx.x;
  int j0 = blockIdx.x * 64;
  for (int l = t; l < 64*32; l += 256){
    int jl = l >> 5, hg = (l & 31) * 4;
    int j = j0 + jl;
    float4 v = make_float4(0.f, 0.f, 0.f, 0.f);
    if (j < KC) v = *(const float4*)(X + (size_t)j*HH + hg);
    T2[jl][hg] = v.x; T2[jl][hg+1] = v.y; T2[jl][hg+2] = v.z; T2[jl][hg+3] = v.w;
  }
  __syncthreads();
  for (int idx = t; idx < 128*64; idx += 256){
    int h = idx >> 6, jl = idx & 63;
    Xt[(size_t)h*A2P + j0 + jl] = __float2half(T2[jl][h]);
  }
}

// MFMA dagg, output-stationary: meanb[i,h] = (sum_j A2T[i,j]*Xt[h,j]) / max(deg[i],1).
// grid = A2P/16 = 208 blocks; 4 waves, each 16i x 32h, full K, K-unroll 2, no atomics.
__global__ void k_mm(const __half* __restrict__ A2Th, const __half* __restrict__ Xth,
                     const int* __restrict__ deg, float* __restrict__ meanb){
  const _Float16* A2T = (const _Float16*)A2Th;
  const _Float16* Xt  = (const _Float16*)Xth;
  int t = threadIdx.x;
  int lane = t & 63, w = t >> 6;
  int i0 = blockIdx.x * 16;
  int l15 = lane & 15, lk = (lane >> 4) * 8;
  const _Float16* Arow = A2T + (size_t)(i0 + l15) * A2P + lk;
  const _Float16* B0 = Xt + (size_t)(w*32 + l15) * A2P + lk;
  const _Float16* B1 = B0 + (size_t)16 * A2P;
  f32x4 acc0 = (f32x4)0.f, acc1 = (f32x4)0.f;
  for (int kk = 0; kk < A2P; kk += 64){
    f16x8 a0 = *(const f16x8*)(Arow + kk);
    f16x8 a1 = *(const f16x8*)(Arow + kk + 32);
    f16x8 b00 = *(const f16x8*)(B0 + kk);
    f16x8 b01 = *(const f16x8*)(B1 + kk);
    f16x8 b10 = *(const f16x8*)(B0 + kk + 32);
    f16x8 b11 = *(const f16x8*)(B1 + kk + 32);
    acc0 = __builtin_amdgcn_mfma_f32_16x16x32_f16(a0, b00, acc0, 0, 0, 0);
    acc1 = __builtin_amdgcn_mfma_f32_16x16x32_f16(a0, b01, acc1, 0, 0, 0);
    acc0 = __builtin_amdgcn_mfma_f32_16x16x32_f16(a1, b10, acc0, 0, 0, 0);
    acc1 = __builtin_amdgcn_mfma_f32_16x16x32_f16(a1, b11, acc1, 0, 0, 0);
  }
  int rbase = (lane >> 4) * 4;
  #pragma unroll
  for (int r = 0; r < 4; ++r){
    int i = i0 + rbase + r;
    if (i < KC){
      float d = fmaxf((float)deg[i], 1.f);
      meanb[(size_t)i*HH + w*32 + l15] = acc0[r] / d;
      meanb[(size_t)i*HH + w*32 + 16 + l15] = acc1[r] / d;
    }
  }
}

} // namespace

extern "C" void kernel_launch(void* const* d_in, const int* in_sizes, int n_in,
                              void* d_out, int out_size, void* d_ws, size_t ws_size,
                              hipStream_t stream){
  (void)in_sizes; (void)n_in; (void)out_size; (void)ws_size;
  const float* x      = (const float*)d_in[0];
  const int*   ei     = (const int*)d_in[1];
  const float* c0Wrel = (const float*)d_in[2];
  const float* c0brel = (const float*)d_in[3];
  const float* c0Wroot= (const float*)d_in[4];
  const float* c1Wrel = (const float*)d_in[5];
  const float* c1brel = (const float*)d_in[6];
  const float* c1Wroot= (const float*)d_in[7];
  const float* c2Wrel = (const float*)d_in[8];
  const float* c2brel = (const float*)d_in[9];
  const float* c2Wroot= (const float*)d_in[10];
  const float* c3Wrel = (const float*)d_in[11];
  const float* c3brel = (const float*)d_in[12];
  const float* c3Wroot= (const float*)d_in[13];
  const float* Wlin   = (const float*)d_in[14];
  const float* blin   = (const float*)d_in[15];
  const float* Watt   = (const float*)d_in[16];
  const float* batt   = (const float*)d_in[17];
  const float* W1     = (const float*)d_in[18];
  const float* b1     = (const float*)d_in[19];
  const float* W2     = (const float*)d_in[20];
  const float* W3     = (const float*)d_in[21];
  const float* b3     = (const float*)d_in[22];
  float* out = (float*)d_out;

  char* base = (char*)d_ws;
  size_t off = 0;
  auto carve = [&](size_t bytes) -> void* {
    void* p = base + off;
    off += (bytes + 255) & ~(size_t)255;
    return p;
  };
  float* x1    = (float*)carve((size_t)NN*HH*4);
  float* x2b   = (float*)carve((size_t)NN*HH*4);
  float* meanb = (float*)carve((size_t)NN*HH*4);
  float* xnew  = (float*)carve((size_t)NN*HH*4);
  float* xp    = (float*)carve((size_t)KC*HH*4);
  float* x3    = (float*)carve((size_t)KC*HH*4);
  float* x4    = (float*)carve((size_t)KC*HH*4);
  __half* A2   = (__half*)carve((size_t)KC*A2P*2);   // ~22 MB
  __half* U    = (__half*)carve((size_t)NN*UP*2);    // ~29 MB; dead after k_A2B -> reused as A2T
  __half* A2T  = U;                                   // [A2P][A2P] f16 = 22.2 MB fits in U's 29.4 MB
  __half* Xt   = (__half*)carve((size_t)HH*A2P*2);   // 852 KB
  float* xdot  = (float*)carve(NN*4);
  float* qdot  = (float*)carve(NN*4);
  float* mmaxA = (float*)carve(NN*4);
  float* ssumA = (float*)carve(NN*4);
  float* aA    = (float*)carve(NN*4);
  float* bA    = (float*)carve(NN*4);
  float* cA    = (float*)carve(NN*4);
  float* fitA  = (float*)carve(NN*4);
  float* fitk  = (float*)carve(KC*4);
  float* wA2   = (float*)carve((HH+1)*4);
  float* wD    = (float*)carve((size_t)E2*4);
  float* wSar  = (float*)carve((size_t)E2*4);
  int* rowD = (int*)carve((NN+1)*4);
  int* rowS = (int*)carve((NN+1)*4);
  int* cntD = (int*)carve(NN*4);
  int* cntS = (int*)carve(NN*4);
  int* curD = (int*)carve(NN*4);
  int* curS = (int*)carve(NN*4);
  int* colD = (int*)carve((size_t)E2*4);
  int* dstS = (int*)carve((size_t)E2*4);
  int* mapSD= (int*)carve((size_t)E2*4);
  int* kSar = (int*)carve((size_t)E2*4);
  int* perm = (int*)carve(KC*4);
  int* kcol = (int*)carve(NN*4);
  int* deg3 = (int*)carve(KC*4);

  k_zero_init<<<NN/256, 256, 0, stream>>>(cntD, cntS, deg3, out);
  k_count<<<(E2+255)/256, 256, 0, stream>>>(ei, cntD, cntS);
  k_scan<<<1, 1024, 0, stream>>>(cntD, cntS, rowD, rowS, curD, curS);
  k_scatter<<<(E2+255)/256, 256, 0, stream>>>(ei, curD, curS, colD, dstS, mapSD);

  // conv0
  k_edge_mean<<<NN, 128, 0, stream>>>(x, rowD, colD, meanb);
  k_lin<<<(NN+15)/16, 256, 0, stream>>>(meanb, x, c0Wrel, c0brel, c0Wroot, x1, NN);
  k_colmean<<<(NN+63)/64, 128, 0, stream>>>(x1, NN, out + 0);

  // conv1
  k_edge_mean<<<NN, 128, 0, stream>>>(x1, rowD, colD, meanb);
  k_lin<<<(NN+15)/16, 256, 0, stream>>>(meanb, x1, c1Wrel, c1brel, c1Wroot, x2b, NN);
  k_colmean<<<(NN+63)/64, 128, 0, stream>>>(x2b, NN, out + 128);

  // ASAP pool
  k_wprep<<<1, 128, 0, stream>>>(Wlin, blin, Watt, wA2);
  k_xdot<<<NN, 128, 0, stream>>>(x2b, Watt, xdot);
  k_pool<<<NN, 128, 0, stream>>>(x2b, rowD, colD, xdot, wA2, batt, qdot, mmaxA, ssumA, xnew, wD);
  k_abc<<<NN, 128, 0, stream>>>(xnew, W1, b1, W2, W3, b3, aA, bA, cA);
  k_fit<<<NN, 128, 0, stream>>>(rowD, colD, aA, bA, cA, fitA);
  k_topk<<<1, 1024, 0, stream>>>(fitA, perm, fitk, kcol);
  k_xp<<<(KC*HH+255)/256, 256, 0, stream>>>(xnew, perm, fitk, xp);
  k_wS<<<(E2+255)/256, 256, 0, stream>>>(mapSD, dstS, kcol, wD, wSar, kSar);
  k_U<<<NN, 256, 0, stream>>>(rowS, dstS, wSar, kSar, U);
  k_A2B<<<A2B_RT*8, 256, 0, stream>>>(rowD, colD, wD, perm, U, A2, deg3);

  // transpose A2 -> A2T (U is dead now; A2T aliases it)
  k_tr<<<dim3(A2P/64, A2P/64), 256, 0, stream>>>(A2, A2T);

  // conv2 (dense, MFMA; deg-divide fused)
  k_xt<<<A2P/64, 256, 0, stream>>>(xp, Xt);
  k_mm<<<A2P/16, 256, 0, stream>>>(A2T, Xt, deg3, meanb);
  k_lin<<<(KC+15)/16, 256, 0, stream>>>(meanb, xp, c2Wrel, c2brel, c2Wroot, x3, KC);
  k_colmean<<<(KC+63)/64, 128, 0, stream>>>(x3, KC, out + 256);

  // conv3 (dense, MFMA)
  k_xt<<<A2P/64, 256, 0, stream>>>(x3, Xt);
  k_mm<<<A2P/16, 256, 0, stream>>>(A2T, Xt, deg3, meanb);
  k_lin<<<(KC+15)/16, 256, 0, stream>>>(meanb, x3, c3Wrel, c3brel, c3Wroot, x4, KC);
  k_colmean<<<(KC+63)/64, 128, 0, stream>>>(x4, KC, out + 384);
}

// Round 7
// 497.331 us; speedup vs baseline: 4.2037x; 1.0588x over previous
//
#include <hip/hip_runtime.h>
#include <hip/hip_fp16.h>
#include <math.h>

namespace {

constexpr int NN = 4096;
constexpr int EE = 131072;
constexpr int E2 = EE + NN;      // 135168 pool edges (orig + self loops)
constexpr int HH = 128;
constexpr int KC = 3277;         // ceil(0.8*4096)
constexpr int UP = 3584;         // U row stride (7*512)
constexpr int A2P = 3328;        // A2 row/col padded dim (13*256)

typedef _Float16 f16x8 __attribute__((ext_vector_type(8)));
typedef float f32x4 __attribute__((ext_vector_type(4)));

// k_A2B: 7 column-chunks of 512 (4MB L2-resident U slice per XCD), wave-per-row.
constexpr int A2B_RT = (KC + 3) / 4;   // 820 row-groups (4 waves/block)

__device__ __forceinline__ float lrelu02(float x){ return x > 0.f ? x : 0.2f * x; }

__device__ __forceinline__ float redSum128(float* red, int t, float v){
  red[t] = v; __syncthreads();
  #pragma unroll
  for (int s = 64; s > 0; s >>= 1){ if (t < s) red[t] += red[t + s]; __syncthreads(); }
  float r = red[0]; __syncthreads();
  return r;
}
__device__ __forceinline__ float redMax128(float* red, int t, float v){
  red[t] = v; __syncthreads();
  #pragma unroll
  for (int s = 64; s > 0; s >>= 1){ if (t < s) red[t] = fmaxf(red[t], red[t + s]); __syncthreads(); }
  float r = red[0]; __syncthreads();
  return r;
}

__global__ void k_zero_init(int* cntD, int* cntS, int* deg, float* out){
  int i = blockIdx.x * blockDim.x + threadIdx.x;
  if (i < NN){ cntD[i] = 0; cntS[i] = 0; }
  if (i < KC) deg[i] = 0;
  if (i < 512) out[i] = 0.f;
}

__global__ void k_count(const int* __restrict__ ei, int* cntD, int* cntS){
  int e = blockIdx.x * blockDim.x + threadIdx.x;
  if (e >= E2) return;
  int u, v;
  if (e < EE){ u = ei[e]; v = ei[EE + e]; } else { u = e - EE; v = u; }
  atomicAdd(&cntD[v], 1);
  atomicAdd(&cntS[u], 1);
}

__global__ void k_scan(const int* cntD, const int* cntS, int* rowD, int* rowS, int* curD, int* curS){
  __shared__ int sc[1024];
  int t = threadIdx.x;
  for (int pass = 0; pass < 2; ++pass){
    const int* cnt = pass ? cntS : cntD;
    int* row = pass ? rowS : rowD;
    int* cur = pass ? curS : curD;
    int c0 = cnt[t*4+0], c1 = cnt[t*4+1], c2 = cnt[t*4+2], c3 = cnt[t*4+3];
    int tot = c0 + c1 + c2 + c3;
    sc[t] = tot; __syncthreads();
    for (int offs = 1; offs < 1024; offs <<= 1){
      int v = (t >= offs) ? sc[t - offs] : 0;
      __syncthreads();
      sc[t] += v;
      __syncthreads();
    }
    int excl = sc[t] - tot;
    int r0 = excl, r1 = r0 + c0, r2 = r1 + c1, r3 = r2 + c2;
    row[t*4+0] = r0; row[t*4+1] = r1; row[t*4+2] = r2; row[t*4+3] = r3;
    cur[t*4+0] = r0; cur[t*4+1] = r1; cur[t*4+2] = r2; cur[t*4+3] = r3;
    if (t == 1023) row[NN] = r3 + c3;
    __syncthreads();
  }
}

__global__ void k_scatter(const int* __restrict__ ei, int* curD, int* curS,
                          int* colD, int* dstS, int* mapSD){
  int e = blockIdx.x * blockDim.x + threadIdx.x;
  if (e >= E2) return;
  int u, v;
  if (e < EE){ u = ei[e]; v = ei[EE + e]; } else { u = e - EE; v = u; }
  int p = atomicAdd(&curD[v], 1); colD[p] = u;
  int q = atomicAdd(&curS[u], 1); dstS[q] = v; mapSD[q] = p;
}

// mean over in-neighbors (original edges only -> skip the self loop entry u==v)
__global__ void k_edge_mean(const float* __restrict__ xin, const int* __restrict__ rowD,
                            const int* __restrict__ colD, float* __restrict__ meanb){
  int v = blockIdx.x, t = threadIdx.x;
  int beg = rowD[v], end = rowD[v+1];
  float acc = 0.f;
  int p = beg;
  for (; p + 4 <= end; p += 4){
    int u0 = colD[p], u1 = colD[p+1], u2 = colD[p+2], u3 = colD[p+3];
    float a0 = xin[(size_t)u0*HH + t];
    float a1 = xin[(size_t)u1*HH + t];
    float a2 = xin[(size_t)u2*HH + t];
    float a3 = xin[(size_t)u3*HH + t];
    if (u0 != v) acc += a0;
    if (u1 != v) acc += a1;
    if (u2 != v) acc += a2;
    if (u3 != v) acc += a3;
  }
  for (; p < end; ++p){ int u = colD[p]; if (u != v) acc += xin[(size_t)u*HH + t]; }
  float dg = (float)(end - beg - 1);
  meanb[v*HH + t] = acc / fmaxf(dg, 1.f);
}

// xout = relu(meanb @ Wrel^T + brel + xin @ Wroot^T), 16 rows/block
__global__ void k_lin(const float* __restrict__ meanb, const float* __restrict__ xin,
                      const float* __restrict__ Wrel, const float* __restrict__ brel,
                      const float* __restrict__ Wroot, float* __restrict__ xout, int rows){
  __shared__ float ms[16][HH];
  __shared__ float xs[16][HH];
  int tid = threadIdx.x;
  int r0 = blockIdx.x * 16;
  for (int l = tid; l < 16*HH; l += 256){
    int r = l >> 7, c = l & 127; int gr = r0 + r;
    float mv = 0.f, xv = 0.f;
    if (gr < rows){ mv = meanb[gr*HH + c]; xv = xin[gr*HH + c]; }
    ms[r][c] = mv; xs[r][c] = xv;
  }
  __syncthreads();
  int h = tid & 127, hgrp = tid >> 7;
  float acc[8] = {0.f,0.f,0.f,0.f,0.f,0.f,0.f,0.f};
  for (int c = 0; c < HH; ++c){
    float wr = Wrel[h*HH + c], wo = Wroot[h*HH + c];
    #pragma unroll
    for (int r = 0; r < 8; ++r) acc[r] += ms[hgrp*8 + r][c]*wr + xs[hgrp*8 + r][c]*wo;
  }
  float bb = brel[h];
  #pragma unroll
  for (int r = 0; r < 8; ++r){
    int gr = r0 + hgrp*8 + r;
    if (gr < rows) xout[gr*HH + h] = fmaxf(acc[r] + bb, 0.f);
  }
}

__global__ void k_colmean(const float* __restrict__ x, int rows, float* __restrict__ outp){
  int t = threadIdx.x;
  int r0 = blockIdx.x * 64;
  int rend = min(rows, r0 + 64);
  float acc = 0.f;
  for (int r = r0; r < rend; ++r) acc += x[r*HH + t];
  atomicAdd(&outp[t], acc / (float)rows);
}

// wA2[c] = sum_h wattA[h]*Wlin[h,c];  wA2[HH] = sum_h blin[h]*wattA[h]
__global__ void k_wprep(const float* __restrict__ Wlin, const float* __restrict__ blin,
                        const float* __restrict__ Watt, float* __restrict__ wA2){
  int c = threadIdx.x;
  float s = 0.f;
  for (int hh = 0; hh < HH; ++hh) s += Watt[hh] * Wlin[hh*HH + c];
  wA2[c] = s;
  if (c == 0){
    float q = 0.f;
    for (int hh = 0; hh < HH; ++hh) q += blin[hh] * Watt[hh];
    wA2[HH] = q;
  }
}

__global__ void k_xdot(const float* __restrict__ x2, const float* __restrict__ Watt, float* __restrict__ xdot){
  __shared__ float red[128];
  int n = blockIdx.x, t = threadIdx.x;
  float v = redSum128(red, t, x2[n*HH + t] * Watt[HH + t]);
  if (t == 0) xdot[n] = v;
}

// per dst node v: xq max -> qdot; edge-softmax stats m, ssum; x_new; per-edge weight wD;
// fused LEConv partials aA/bA/cA (was k_abc).
__global__ void k_pool(const float* __restrict__ x2, const int* __restrict__ rowD, const int* __restrict__ colD,
                       const float* __restrict__ xdotA, const float* __restrict__ wA2, const float* __restrict__ battp,
                       const float* __restrict__ W1, const float* __restrict__ b1,
                       const float* __restrict__ W2, const float* __restrict__ W3, const float* __restrict__ b3,
                       float* qdotA, float* mA, float* sA, float* __restrict__ xnew, float* __restrict__ wD,
                       float* aA, float* bA, float* cA){
  __shared__ float red[128];
  __shared__ float wmem[128];
  __shared__ int uc[128];
  int v = blockIdx.x, t = threadIdx.x;
  int beg = rowD[v], end = rowD[v+1];
  float batt = battp[0];
  float mx = -3.402823466e38f;
  int p = beg;
  for (; p + 4 <= end; p += 4){
    float a0 = x2[(size_t)colD[p]*HH + t];
    float a1 = x2[(size_t)colD[p+1]*HH + t];
    float a2 = x2[(size_t)colD[p+2]*HH + t];
    float a3 = x2[(size_t)colD[p+3]*HH + t];
    mx = fmaxf(fmaxf(fmaxf(fmaxf(mx, a0), a1), a2), a3);
  }
  for (; p < end; ++p) mx = fmaxf(mx, x2[(size_t)colD[p]*HH + t]);
  float qd = redSum128(red, t, mx * wA2[t]) + wA2[HH];
  float lm = -3.402823466e38f;
  for (p = beg + t; p < end; p += 128) lm = fmaxf(lm, lrelu02(qd + xdotA[colD[p]] + batt));
  float mm = redMax128(red, t, lm);
  float ls = 0.f;
  for (p = beg + t; p < end; p += 128) ls += expf(lrelu02(qd + xdotA[colD[p]] + batt) - mm);
  float ss = redSum128(red, t, ls);
  float acc = 0.f;
  for (int basep = beg; basep < end; basep += 128){
    int cnt = min(128, end - basep);
    if (t < cnt){
      int u = colD[basep + t];
      uc[t] = u;
      float w = expf(lrelu02(qd + xdotA[u] + batt) - mm) / ss;
      wmem[t] = w;
      wD[basep + t] = w;
    }
    __syncthreads();
    int i = 0;
    for (; i + 4 <= cnt; i += 4){
      float a0 = x2[(size_t)uc[i]*HH + t];
      float a1 = x2[(size_t)uc[i+1]*HH + t];
      float a2 = x2[(size_t)uc[i+2]*HH + t];
      float a3 = x2[(size_t)uc[i+3]*HH + t];
      acc += wmem[i]*a0 + wmem[i+1]*a1 + wmem[i+2]*a2 + wmem[i+3]*a3;
    }
    for (; i < cnt; ++i) acc += wmem[i] * x2[(size_t)uc[i]*HH + t];
    __syncthreads();
  }
  xnew[v*HH + t] = acc;
  float s1 = redSum128(red, t, acc * W1[t]);
  float s2 = redSum128(red, t, acc * W2[t]);
  float s3 = redSum128(red, t, acc * W3[t]);
  if (t == 0){
    qdotA[v] = qd; mA[v] = mm; sA[v] = ss;
    aA[v] = s1 + b1[0]; bA[v] = s2; cA[v] = s3 + b3[0];
  }
}

__global__ void k_fit(const int* __restrict__ rowD, const int* __restrict__ colD,
                      const float* __restrict__ aA, const float* __restrict__ bA, const float* __restrict__ cA,
                      float* __restrict__ fitA){
  __shared__ float red[128];
  int v = blockIdx.x, t = threadIdx.x;
  int beg = rowD[v], end = rowD[v+1];
  float la = 0.f;
  for (int p = beg + t; p < end; p += 128) la += aA[colD[p]];
  float s = redSum128(red, t, la);
  if (t == 0){
    float g = s - (float)(end - beg) * bA[v] + cA[v];
    fitA[v] = 1.f / (1.f + expf(-g));
  }
}

// Exact top-K SET selection via radix-select (1 block, 1024 threads).
// Downstream is permutation-invariant over the kept set, so perm order = node-index
// order (stable, deterministic). Tie at threshold resolved index-ascending (JAX top_k).
__global__ void k_sel(const float* __restrict__ fitA, int* perm, float* fitk, int* kcol){
  __shared__ unsigned keys[NN];   // 16 KB
  __shared__ int hist[256];
  __shared__ int sc[1024];
  __shared__ int bc[2];
  int t = threadIdx.x;
  #pragma unroll
  for (int r = 0; r < 4; ++r){
    int i = t + r*1024;
    unsigned b = __float_as_uint(fitA[i]);
    keys[i] = (b & 0x80000000u) ? ~b : (b ^ 0x80000000u);   // ascending map
  }
  __syncthreads();
  unsigned prefix = 0;
  int kneed = KC;
  #pragma unroll
  for (int round = 0; round < 4; ++round){
    int shift = 24 - round*8;
    unsigned pmask = (round == 0) ? 0u : (0xFFFFFFFFu << (shift + 8));
    if (t < 256) hist[t] = 0;
    __syncthreads();
    #pragma unroll
    for (int r = 0; r < 4; ++r){
      unsigned kv = keys[t + r*1024];
      if ((kv & pmask) == prefix)
        atomicAdd(&hist[(kv >> shift) & 0xFF], 1);
    }
    __syncthreads();
    if (t == 0){
      int acc = 0, chosen = 0, rem = kneed;
      for (int bkt = 255; bkt >= 0; --bkt){
        int c = hist[bkt];
        if (acc + c >= kneed){ chosen = bkt; rem = kneed - acc; break; }
        acc += c;
      }
      bc[0] = chosen; bc[1] = rem;
    }
    __syncthreads();
    prefix |= ((unsigned)bc[0]) << shift;
    kneed = bc[1];
    __syncthreads();
  }
  unsigned T = prefix;      // exact KC-th largest key
  int need_eq = kneed;      // how many ==T to keep (index-ascending)
  // stable compaction: packed counts (gt<<16 | eq), index order
  int cnt[4]; int tot = 0;
  #pragma unroll
  for (int r = 0; r < 4; ++r){
    unsigned kv = keys[t*4 + r];
    int g = (kv > T) ? 1 : 0;
    int e = (kv == T) ? 1 : 0;
    cnt[r] = (g << 16) | e;
    tot += cnt[r];
  }
  sc[t] = tot; __syncthreads();
  for (int offs = 1; offs < 1024; offs <<= 1){
    int v = (t >= offs) ? sc[t - offs] : 0;
    __syncthreads();
    sc[t] += v;
    __syncthreads();
  }
  int gtot = sc[1023] >> 16;
  int run = sc[t] - tot;
  #pragma unroll
  for (int r = 0; r < 4; ++r){
    int i = t*4 + r;
    int g = cnt[r] >> 16, e = cnt[r] & 0xFFFF;
    int gpos = run >> 16, epos = run & 0xFFFF;
    int pos = -1;
    if (g) pos = gpos;
    else if (e && epos < need_eq) pos = gtot + epos;
    if (pos >= 0){ perm[pos] = i; fitk[pos] = fitA[i]; kcol[i] = pos; }
    else kcol[i] = -1;
    run += cnt[r];
  }
}

__global__ void k_xp(const float* __restrict__ xnew, const int* __restrict__ perm,
                     const float* __restrict__ fitk, float* __restrict__ xp){
  int idx = blockIdx.x * blockDim.x + threadIdx.x;
  if (idx >= KC*HH) return;
  int r = idx >> 7, h = idx & 127;
  xp[idx] = xnew[perm[r]*HH + h] * fitk[r];
}

// src-ordered per-edge weight + kept-cluster index of target
__global__ void k_wS(const int* __restrict__ mapSD, const int* __restrict__ dstS,
                     const int* __restrict__ kcol, const float* __restrict__ wD,
                     float* __restrict__ wS, int* __restrict__ kS){
  int q = blockIdx.x * blockDim.x + threadIdx.x;
  if (q >= E2) return;
  wS[q] = wD[mapSD[q]];
  kS[q] = kcol[dstS[q]];
}

// U[n,:] = (A @ S)[n,:]  (dense f16 row, stride UP, zero-padded)
__global__ void k_U(const int* __restrict__ rowS, const int* __restrict__ dstS,
                    const float* __restrict__ wS, const int* __restrict__ kS,
                    __half* __restrict__ U){
  __shared__ float acc[UP];   // 14 KB
  int t = threadIdx.x, n = blockIdx.x;
  for (int i = t; i < UP; i += 256) acc[i] = 0.f;
  __syncthreads();
  int b = rowS[n], e = rowS[n+1];
  for (int p = b; p < e; ++p){
    int j = dstS[p];
    int b2 = rowS[j], e2 = rowS[j+1];
    for (int q = b2 + t; q < e2; q += 256){
      int k = kS[q];
      if (k >= 0) atomicAdd(&acc[k], wS[q]);
    }
  }
  __syncthreads();
  __half2* Ur = (__half2*)(U + (size_t)n * UP);
  for (int i = t; i < UP/2; i += 256)
    Ur[i] = __halves2half2(__float2half(acc[2*i]), __float2half(acc[2*i+1]));
}

// A2[k1, cc*512 .. +511] = sum over in-edges of wD * U[n, chunk]; wave-per-row, 8-deep ILP.
// grid = A2B_RT*8; cc = bid&7 (XCD pin, cc=7 idle); fused per-row nonzero count -> deg.
__global__ void k_A2B(const int* __restrict__ rowD, const int* __restrict__ colD,
                      const float* __restrict__ wD, const int* __restrict__ perm,
                      const __half* __restrict__ Uh, __half* __restrict__ A2,
                      int* __restrict__ deg){
  int cc = blockIdx.x & 7;
  if (cc >= 7) return;
  int rt = blockIdx.x >> 3;
  int t = threadIdx.x;
  int w = t >> 6, lane = t & 63;
  int k1 = rt*4 + w;
  if (k1 >= KC) return;
  int cb = cc * 512;
  const _Float16* Ul = (const _Float16*)Uh + cb + lane * 8;

  float acc[8] = {0.f,0.f,0.f,0.f,0.f,0.f,0.f,0.f};
  int v1 = perm[k1];
  int beg = rowD[v1], end = rowD[v1+1];

  auto edge1 = [&](int pp){
    int n0 = colD[pp]; float w0 = wD[pp];
    f16x8 u0 = *(const f16x8*)(Ul + (size_t)n0 * UP);
    #pragma unroll
    for (int e = 0; e < 8; ++e) acc[e] += w0 * (float)u0[e];
  };

  int p = beg;
  int pre = (4 - (p & 3)) & 3;
  if (pre > end - p) pre = end - p;
  for (int z = 0; z < pre; ++z){ edge1(p); ++p; }
  for (; p + 8 <= end; p += 8){
    int4 nA = *(const int4*)(colD + p);
    int4 nB = *(const int4*)(colD + p + 4);
    float4 wA = *(const float4*)(wD + p);
    float4 wB = *(const float4*)(wD + p + 4);
    f16x8 u0 = *(const f16x8*)(Ul + (size_t)nA.x * UP);
    f16x8 u1 = *(const f16x8*)(Ul + (size_t)nA.y * UP);
    f16x8 u2 = *(const f16x8*)(Ul + (size_t)nA.z * UP);
    f16x8 u3 = *(const f16x8*)(Ul + (size_t)nA.w * UP);
    f16x8 u4 = *(const f16x8*)(Ul + (size_t)nB.x * UP);
    f16x8 u5 = *(const f16x8*)(Ul + (size_t)nB.y * UP);
    f16x8 u6 = *(const f16x8*)(Ul + (size_t)nB.z * UP);
    f16x8 u7 = *(const f16x8*)(Ul + (size_t)nB.w * UP);
    #pragma unroll
    for (int e = 0; e < 8; ++e){
      acc[e] += wA.x*(float)u0[e] + wA.y*(float)u1[e] + wA.z*(float)u2[e] + wA.w*(float)u3[e]
              + wB.x*(float)u4[e] + wB.y*(float)u5[e] + wB.z*(float)u6[e] + wB.w*(float)u7[e];
    }
  }
  for (; p + 4 <= end; p += 4){
    int4 nA = *(const int4*)(colD + p);
    float4 wA = *(const float4*)(wD + p);
    f16x8 u0 = *(const f16x8*)(Ul + (size_t)nA.x * UP);
    f16x8 u1 = *(const f16x8*)(Ul + (size_t)nA.y * UP);
    f16x8 u2 = *(const f16x8*)(Ul + (size_t)nA.z * UP);
    f16x8 u3 = *(const f16x8*)(Ul + (size_t)nA.w * UP);
    #pragma unroll
    for (int e = 0; e < 8; ++e)
      acc[e] += wA.x*(float)u0[e] + wA.y*(float)u1[e] + wA.z*(float)u2[e] + wA.w*(float)u3[e];
  }
  for (; p < end; ++p) edge1(p);

  int col0 = cb + lane * 8;
  f16x8 o;
  int c = 0;
  #pragma unroll
  for (int e = 0; e < 8; ++e){
    int col = col0 + e;
    float val = (col == k1 || col >= KC) ? 0.f : acc[e];
    _Float16 hv = (_Float16)val;
    o[e] = hv;
    c += (hv != (_Float16)0) ? 1 : 0;
  }
  #pragma unroll
  for (int s = 32; s > 0; s >>= 1) c += __shfl_down(c, s);
  if (lane == 0) atomicAdd(&deg[k1], c);
  if (col0 + 8 <= A2P)
    *(f16x8*)(A2 + (size_t)k1 * A2P + col0) = o;
}

// LDS-tiled transpose: A2T[i][j] = A2[j][i]; rows j >= KC read as zero.
__global__ void k_tr(const __half* __restrict__ A2, __half* __restrict__ A2T){
  __shared__ float tile[64][65];
  int t = threadIdx.x;
  int i0 = blockIdx.x * 64, j0 = blockIdx.y * 64;
  int sl = t & 7;
  #pragma unroll
  for (int p = 0; p < 2; ++p){
    int jl = (t >> 3) + p*32;
    int j = j0 + jl;
    f16x8 v;
    if (j < KC) v = *(const f16x8*)(A2 + (size_t)j*A2P + i0 + sl*8);
    else v = (f16x8)(_Float16)0;
    #pragma unroll
    for (int e = 0; e < 8; ++e) tile[jl][sl*8 + e] = (float)v[e];
  }
  __syncthreads();
  #pragma unroll
  for (int p = 0; p < 2; ++p){
    int il = (t >> 3) + p*32;
    int i = i0 + il;
    f16x8 o;
    #pragma unroll
    for (int e = 0; e < 8; ++e) o[e] = (_Float16)tile[sl*8 + e][il];
    *(f16x8*)(A2T + (size_t)i*A2P + j0 + sl*8) = o;
  }
}

// Xt[h][j] = (f16) X[j][h], zero-padded for j >= KC. Block: 64 j x 128 h.
__global__ void k_xt(const float* __restrict__ X, __half* __restrict__ Xt){
  __shared__ float T2[64][129];
  int t = threadIdx.x;
  int j0 = blockIdx.x * 64;
  for (int l = t; l < 64*32; l += 256){
    int jl = l >> 5, hg = (l & 31) * 4;
    int j = j0 + jl;
    float4 v = make_float4(0.f, 0.f, 0.f, 0.f);
    if (j < KC) v = *(const float4*)(X + (size_t)j*HH + hg);
    T2[jl][hg] = v.x; T2[jl][hg+1] = v.y; T2[jl][hg+2] = v.z; T2[jl][hg+3] = v.w;
  }
  __syncthreads();
  for (int idx = t; idx < 128*64; idx += 256){
    int h = idx >> 6, jl = idx & 63;
    Xt[(size_t)h*A2P + j0 + jl] = __float2half(T2[jl][h]);
  }
}

// MFMA dagg, output-stationary: meanb[i,h] = (sum_j A2T[i,j]*Xt[h,j]) / max(deg[i],1).
// grid = A2P/16 = 208 blocks; 4 waves, each 16i x 32h, full K, K-unroll 2, no atomics.
__global__ void k_mm(const __half* __restrict__ A2Th, const __half* __restrict__ Xth,
                     const int* __restrict__ deg, float* __restrict__ meanb){
  const _Float16* A2T = (const _Float16*)A2Th;
  const _Float16* Xt  = (const _Float16*)Xth;
  int t = threadIdx.x;
  int lane = t & 63, w = t >> 6;
  int i0 = blockIdx.x * 16;
  int l15 = lane & 15, lk = (lane >> 4) * 8;
  const _Float16* Arow = A2T + (size_t)(i0 + l15) * A2P + lk;
  const _Float16* B0 = Xt + (size_t)(w*32 + l15) * A2P + lk;
  const _Float16* B1 = B0 + (size_t)16 * A2P;
  f32x4 acc0 = (f32x4)0.f, acc1 = (f32x4)0.f;
  for (int kk = 0; kk < A2P; kk += 64){
    f16x8 a0 = *(const f16x8*)(Arow + kk);
    f16x8 a1 = *(const f16x8*)(Arow + kk + 32);
    f16x8 b00 = *(const f16x8*)(B0 + kk);
    f16x8 b01 = *(const f16x8*)(B1 + kk);
    f16x8 b10 = *(const f16x8*)(B0 + kk + 32);
    f16x8 b11 = *(const f16x8*)(B1 + kk + 32);
    acc0 = __builtin_amdgcn_mfma_f32_16x16x32_f16(a0, b00, acc0, 0, 0, 0);
    acc1 = __builtin_amdgcn_mfma_f32_16x16x32_f16(a0, b01, acc1, 0, 0, 0);
    acc0 = __builtin_amdgcn_mfma_f32_16x16x32_f16(a1, b10, acc0, 0, 0, 0);
    acc1 = __builtin_amdgcn_mfma_f32_16x16x32_f16(a1, b11, acc1, 0, 0, 0);
  }
  int rbase = (lane >> 4) * 4;
  #pragma unroll
  for (int r = 0; r < 4; ++r){
    int i = i0 + rbase + r;
    if (i < KC){
      float d = fmaxf((float)deg[i], 1.f);
      meanb[(size_t)i*HH + w*32 + l15] = acc0[r] / d;
      meanb[(size_t)i*HH + w*32 + 16 + l15] = acc1[r] / d;
    }
  }
}

} // namespace

extern "C" void kernel_launch(void* const* d_in, const int* in_sizes, int n_in,
                              void* d_out, int out_size, void* d_ws, size_t ws_size,
                              hipStream_t stream){
  (void)in_sizes; (void)n_in; (void)out_size; (void)ws_size;
  const float* x      = (const float*)d_in[0];
  const int*   ei     = (const int*)d_in[1];
  const float* c0Wrel = (const float*)d_in[2];
  const float* c0brel = (const float*)d_in[3];
  const float* c0Wroot= (const float*)d_in[4];
  const float* c1Wrel = (const float*)d_in[5];
  const float* c1brel = (const float*)d_in[6];
  const float* c1Wroot= (const float*)d_in[7];
  const float* c2Wrel = (const float*)d_in[8];
  const float* c2brel = (const float*)d_in[9];
  const float* c2Wroot= (const float*)d_in[10];
  const float* c3Wrel = (const float*)d_in[11];
  const float* c3brel = (const float*)d_in[12];
  const float* c3Wroot= (const float*)d_in[13];
  const float* Wlin   = (const float*)d_in[14];
  const float* blin   = (const float*)d_in[15];
  const float* Watt   = (const float*)d_in[16];
  const float* batt   = (const float*)d_in[17];
  const float* W1     = (const float*)d_in[18];
  const float* b1     = (const float*)d_in[19];
  const float* W2     = (const float*)d_in[20];
  const float* W3     = (const float*)d_in[21];
  const float* b3     = (const float*)d_in[22];
  float* out = (float*)d_out;

  char* base = (char*)d_ws;
  size_t off = 0;
  auto carve = [&](size_t bytes) -> void* {
    void* p = base + off;
    off += (bytes + 255) & ~(size_t)255;
    return p;
  };
  float* x1    = (float*)carve((size_t)NN*HH*4);
  float* x2b   = (float*)carve((size_t)NN*HH*4);
  float* meanb = (float*)carve((size_t)NN*HH*4);
  float* xnew  = (float*)carve((size_t)NN*HH*4);
  float* xp    = (float*)carve((size_t)KC*HH*4);
  float* x3    = (float*)carve((size_t)KC*HH*4);
  float* x4    = (float*)carve((size_t)KC*HH*4);
  __half* A2   = (__half*)carve((size_t)KC*A2P*2);   // ~22 MB
  __half* U    = (__half*)carve((size_t)NN*UP*2);    // ~29 MB; dead after k_A2B -> reused as A2T
  __half* A2T  = U;                                   // [A2P][A2P] f16 = 22.2 MB fits in U's 29.4 MB
  __half* Xt   = (__half*)carve((size_t)HH*A2P*2);   // 852 KB
  float* xdot  = (float*)carve(NN*4);
  float* qdot  = (float*)carve(NN*4);
  float* mmaxA = (float*)carve(NN*4);
  float* ssumA = (float*)carve(NN*4);
  float* aA    = (float*)carve(NN*4);
  float* bA    = (float*)carve(NN*4);
  float* cA    = (float*)carve(NN*4);
  float* fitA  = (float*)carve(NN*4);
  float* fitk  = (float*)carve(KC*4);
  float* wA2   = (float*)carve((HH+1)*4);
  float* wD    = (float*)carve((size_t)E2*4);
  float* wSar  = (float*)carve((size_t)E2*4);
  int* rowD = (int*)carve((NN+1)*4);
  int* rowS = (int*)carve((NN+1)*4);
  int* cntD = (int*)carve(NN*4);
  int* cntS = (int*)carve(NN*4);
  int* curD = (int*)carve(NN*4);
  int* curS = (int*)carve(NN*4);
  int* colD = (int*)carve((size_t)E2*4);
  int* dstS = (int*)carve((size_t)E2*4);
  int* mapSD= (int*)carve((size_t)E2*4);
  int* kSar = (int*)carve((size_t)E2*4);
  int* perm = (int*)carve(KC*4);
  int* kcol = (int*)carve(NN*4);
  int* deg3 = (int*)carve(KC*4);

  k_zero_init<<<NN/256, 256, 0, stream>>>(cntD, cntS, deg3, out);
  k_count<<<(E2+255)/256, 256, 0, stream>>>(ei, cntD, cntS);
  k_scan<<<1, 1024, 0, stream>>>(cntD, cntS, rowD, rowS, curD, curS);
  k_scatter<<<(E2+255)/256, 256, 0, stream>>>(ei, curD, curS, colD, dstS, mapSD);

  // conv0
  k_edge_mean<<<NN, 128, 0, stream>>>(x, rowD, colD, meanb);
  k_lin<<<(NN+15)/16, 256, 0, stream>>>(meanb, x, c0Wrel, c0brel, c0Wroot, x1, NN);
  k_colmean<<<(NN+63)/64, 128, 0, stream>>>(x1, NN, out + 0);

  // conv1
  k_edge_mean<<<NN, 128, 0, stream>>>(x1, rowD, colD, meanb);
  k_lin<<<(NN+15)/16, 256, 0, stream>>>(meanb, x1, c1Wrel, c1brel, c1Wroot, x2b, NN);
  k_colmean<<<(NN+63)/64, 128, 0, stream>>>(x2b, NN, out + 128);

  // ASAP pool
  k_wprep<<<1, 128, 0, stream>>>(Wlin, blin, Watt, wA2);
  k_xdot<<<NN, 128, 0, stream>>>(x2b, Watt, xdot);
  k_pool<<<NN, 128, 0, stream>>>(x2b, rowD, colD, xdot, wA2, batt,
                                 W1, b1, W2, W3, b3,
                                 qdot, mmaxA, ssumA, xnew, wD, aA, bA, cA);
  k_fit<<<NN, 128, 0, stream>>>(rowD, colD, aA, bA, cA, fitA);
  k_sel<<<1, 1024, 0, stream>>>(fitA, perm, fitk, kcol);
  k_xp<<<(KC*HH+255)/256, 256, 0, stream>>>(xnew, perm, fitk, xp);
  k_wS<<<(E2+255)/256, 256, 0, stream>>>(mapSD, dstS, kcol, wD, wSar, kSar);
  k_U<<<NN, 256, 0, stream>>>(rowS, dstS, wSar, kSar, U);
  k_A2B<<<A2B_RT*8, 256, 0, stream>>>(rowD, colD, wD, perm, U, A2, deg3);

  // transpose A2 -> A2T (U is dead now; A2T aliases it)
  k_tr<<<dim3(A2P/64, A2P/64), 256, 0, stream>>>(A2, A2T);

  // conv2 (dense, MFMA; deg-divide fused)
  k_xt<<<A2P/64, 256, 0, stream>>>(xp, Xt);
  k_mm<<<A2P/16, 256, 0, stream>>>(A2T, Xt, deg3, meanb);
  k_lin<<<(KC+15)/16, 256, 0, stream>>>(meanb, xp, c2Wrel, c2brel, c2Wroot, x3, KC);
  k_colmean<<<(KC+63)/64, 128, 0, stream>>>(x3, KC, out + 256);

  // conv3 (dense, MFMA)
  k_xt<<<A2P/64, 256, 0, stream>>>(x3, Xt);
  k_mm<<<A2P/16, 256, 0, stream>>>(A2T, Xt, deg3, meanb);
  k_lin<<<(KC+15)/16, 256, 0, stream>>>(meanb, x3, c3Wrel, c3brel, c3Wroot, x4, KC);
  k_colmean<<<(KC+63)/64, 128, 0, stream>>>(x4, KC, out + 384);
}

// Round 8
// 481.532 us; speedup vs baseline: 4.3416x; 1.0328x over previous
//
#include <hip/hip_runtime.h>
#include <hip/hip_fp16.h>
#include <math.h>

namespace {

constexpr int NN = 4096;
constexpr int EE = 131072;
constexpr int E2 = EE + NN;      // 135168 pool edges (orig + self loops)
constexpr int HH = 128;
constexpr int KC = 3277;         // ceil(0.8*4096)
constexpr int UP = 3584;         // U row stride (8*448)
constexpr int A2P = 3328;        // A2 row/col padded dim

typedef _Float16 f16x8 __attribute__((ext_vector_type(8)));
typedef float f32x4 __attribute__((ext_vector_type(4)));

constexpr int A2B_RT = (KC + 3) / 4;   // 820 row-groups (4 waves/block)
constexpr int KHALF = A2P / 2;          // 1664 (=26*64)

__device__ __forceinline__ float lrelu02(float x){ return x > 0.f ? x : 0.2f * x; }

__device__ __forceinline__ float redSum128(float* red, int t, float v){
  red[t] = v; __syncthreads();
  #pragma unroll
  for (int s = 64; s > 0; s >>= 1){ if (t < s) red[t] += red[t + s]; __syncthreads(); }
  float r = red[0]; __syncthreads();
  return r;
}
__device__ __forceinline__ float redMax128(float* red, int t, float v){
  red[t] = v; __syncthreads();
  #pragma unroll
  for (int s = 64; s > 0; s >>= 1){ if (t < s) red[t] = fmaxf(red[t], red[t + s]); __syncthreads(); }
  float r = red[0]; __syncthreads();
  return r;
}

__global__ void k_zero_init(int* cntD, int* cntS, int* deg, float* out){
  int i = blockIdx.x * blockDim.x + threadIdx.x;
  if (i < NN){ cntD[i] = 0; cntS[i] = 0; }
  if (i < KC) deg[i] = 0;
  if (i < 512) out[i] = 0.f;
}

__global__ void k_count(const int* __restrict__ ei, int* cntD, int* cntS){
  int e = blockIdx.x * blockDim.x + threadIdx.x;
  if (e >= E2) return;
  int u, v;
  if (e < EE){ u = ei[e]; v = ei[EE + e]; } else { u = e - EE; v = u; }
  atomicAdd(&cntD[v], 1);
  atomicAdd(&cntS[u], 1);
}

__global__ void k_scan(const int* cntD, const int* cntS, int* rowD, int* rowS, int* curD, int* curS){
  __shared__ int sc[1024];
  int t = threadIdx.x;
  for (int pass = 0; pass < 2; ++pass){
    const int* cnt = pass ? cntS : cntD;
    int* row = pass ? rowS : rowD;
    int* cur = pass ? curS : curD;
    int c0 = cnt[t*4+0], c1 = cnt[t*4+1], c2 = cnt[t*4+2], c3 = cnt[t*4+3];
    int tot = c0 + c1 + c2 + c3;
    sc[t] = tot; __syncthreads();
    for (int offs = 1; offs < 1024; offs <<= 1){
      int v = (t >= offs) ? sc[t - offs] : 0;
      __syncthreads();
      sc[t] += v;
      __syncthreads();
    }
    int excl = sc[t] - tot;
    int r0 = excl, r1 = r0 + c0, r2 = r1 + c1, r3 = r2 + c2;
    row[t*4+0] = r0; row[t*4+1] = r1; row[t*4+2] = r2; row[t*4+3] = r3;
    cur[t*4+0] = r0; cur[t*4+1] = r1; cur[t*4+2] = r2; cur[t*4+3] = r3;
    if (t == 1023) row[NN] = r3 + c3;
    __syncthreads();
  }
}

__global__ void k_scatter(const int* __restrict__ ei, int* curD, int* curS,
                          int* colD, int* dstS, int* mapSD){
  int e = blockIdx.x * blockDim.x + threadIdx.x;
  if (e >= E2) return;
  int u, v;
  if (e < EE){ u = ei[e]; v = ei[EE + e]; } else { u = e - EE; v = u; }
  int p = atomicAdd(&curD[v], 1); colD[p] = u;
  int q = atomicAdd(&curS[u], 1); dstS[q] = v; mapSD[q] = p;
}

// mean over in-neighbors (original edges only -> skip the self loop entry u==v)
__global__ void k_edge_mean(const float* __restrict__ xin, const int* __restrict__ rowD,
                            const int* __restrict__ colD, float* __restrict__ meanb){
  int v = blockIdx.x, t = threadIdx.x;
  int beg = rowD[v], end = rowD[v+1];
  float acc = 0.f;
  int p = beg;
  for (; p + 8 <= end; p += 8){
    int u0 = colD[p],   u1 = colD[p+1], u2 = colD[p+2], u3 = colD[p+3];
    int u4 = colD[p+4], u5 = colD[p+5], u6 = colD[p+6], u7 = colD[p+7];
    float a0 = xin[(size_t)u0*HH + t];
    float a1 = xin[(size_t)u1*HH + t];
    float a2 = xin[(size_t)u2*HH + t];
    float a3 = xin[(size_t)u3*HH + t];
    float a4 = xin[(size_t)u4*HH + t];
    float a5 = xin[(size_t)u5*HH + t];
    float a6 = xin[(size_t)u6*HH + t];
    float a7 = xin[(size_t)u7*HH + t];
    if (u0 != v) acc += a0;
    if (u1 != v) acc += a1;
    if (u2 != v) acc += a2;
    if (u3 != v) acc += a3;
    if (u4 != v) acc += a4;
    if (u5 != v) acc += a5;
    if (u6 != v) acc += a6;
    if (u7 != v) acc += a7;
  }
  for (; p < end; ++p){ int u = colD[p]; if (u != v) acc += xin[(size_t)u*HH + t]; }
  float dg = (float)(end - beg - 1);
  meanb[v*HH + t] = acc / fmaxf(dg, 1.f);
}

// xout = relu(meanb @ Wrel^T + brel + xin @ Wroot^T), 16 rows/block
__global__ void k_lin(const float* __restrict__ meanb, const float* __restrict__ xin,
                      const float* __restrict__ Wrel, const float* __restrict__ brel,
                      const float* __restrict__ Wroot, float* __restrict__ xout, int rows){
  __shared__ float ms[16][HH];
  __shared__ float xs[16][HH];
  int tid = threadIdx.x;
  int r0 = blockIdx.x * 16;
  for (int l = tid; l < 16*HH; l += 256){
    int r = l >> 7, c = l & 127; int gr = r0 + r;
    float mv = 0.f, xv = 0.f;
    if (gr < rows){ mv = meanb[(size_t)gr*HH + c]; xv = xin[(size_t)gr*HH + c]; }
    ms[r][c] = mv; xs[r][c] = xv;
  }
  __syncthreads();
  int h = tid & 127, hgrp = tid >> 7;
  float acc[8] = {0.f,0.f,0.f,0.f,0.f,0.f,0.f,0.f};
  for (int c = 0; c < HH; ++c){
    float wr = Wrel[h*HH + c], wo = Wroot[h*HH + c];
    #pragma unroll
    for (int r = 0; r < 8; ++r) acc[r] += ms[hgrp*8 + r][c]*wr + xs[hgrp*8 + r][c]*wo;
  }
  float bb = brel[h];
  #pragma unroll
  for (int r = 0; r < 8; ++r){
    int gr = r0 + hgrp*8 + r;
    if (gr < rows) xout[(size_t)gr*HH + h] = fmaxf(acc[r] + bb, 0.f);
  }
}

// dense-conv linear with fused partial-sum + deg-mean:
// mean_i = (p0[i]+p1[i]) / max(deg[i],1);  xout = relu(mean @ Wrel^T + brel + xin @ Wroot^T)
__global__ void k_lin2(const float* __restrict__ p0, const float* __restrict__ p1,
                       const int* __restrict__ deg, const float* __restrict__ xin,
                       const float* __restrict__ Wrel, const float* __restrict__ brel,
                       const float* __restrict__ Wroot, float* __restrict__ xout, int rows){
  __shared__ float ms[16][HH];
  __shared__ float xs[16][HH];
  int tid = threadIdx.x;
  int r0 = blockIdx.x * 16;
  for (int l = tid; l < 16*HH; l += 256){
    int r = l >> 7, c = l & 127; int gr = r0 + r;
    float mv = 0.f, xv = 0.f;
    if (gr < rows){
      float d = fmaxf((float)deg[gr], 1.f);
      mv = (p0[(size_t)gr*HH + c] + p1[(size_t)gr*HH + c]) / d;
      xv = xin[(size_t)gr*HH + c];
    }
    ms[r][c] = mv; xs[r][c] = xv;
  }
  __syncthreads();
  int h = tid & 127, hgrp = tid >> 7;
  float acc[8] = {0.f,0.f,0.f,0.f,0.f,0.f,0.f,0.f};
  for (int c = 0; c < HH; ++c){
    float wr = Wrel[h*HH + c], wo = Wroot[h*HH + c];
    #pragma unroll
    for (int r = 0; r < 8; ++r) acc[r] += ms[hgrp*8 + r][c]*wr + xs[hgrp*8 + r][c]*wo;
  }
  float bb = brel[h];
  #pragma unroll
  for (int r = 0; r < 8; ++r){
    int gr = r0 + hgrp*8 + r;
    if (gr < rows) xout[(size_t)gr*HH + h] = fmaxf(acc[r] + bb, 0.f);
  }
}

__global__ void k_colmean(const float* __restrict__ x, int rows, float* __restrict__ outp){
  int t = threadIdx.x;
  int r0 = blockIdx.x * 64;
  int rend = min(rows, r0 + 64);
  float acc = 0.f;
  for (int r = r0; r < rend; ++r) acc += x[(size_t)r*HH + t];
  atomicAdd(&outp[t], acc / (float)rows);
}

// wA2[c] = sum_h wattA[h]*Wlin[h,c];  wA2[HH] = sum_h blin[h]*wattA[h]
__global__ void k_wprep(const float* __restrict__ Wlin, const float* __restrict__ blin,
                        const float* __restrict__ Watt, float* __restrict__ wA2){
  int c = threadIdx.x;
  float s = 0.f;
  for (int hh = 0; hh < HH; ++hh) s += Watt[hh] * Wlin[hh*HH + c];
  wA2[c] = s;
  if (c == 0){
    float q = 0.f;
    for (int hh = 0; hh < HH; ++hh) q += blin[hh] * Watt[hh];
    wA2[HH] = q;
  }
}

__global__ void k_xdot(const float* __restrict__ x2, const float* __restrict__ Watt, float* __restrict__ xdot){
  __shared__ float red[128];
  int n = blockIdx.x, t = threadIdx.x;
  float v = redSum128(red, t, x2[(size_t)n*HH + t] * Watt[HH + t]);
  if (t == 0) xdot[n] = v;
}

// per dst node v: xq max -> qdot; edge-softmax stats m, ssum; x_new; per-edge weight wD;
// fused LEConv partials aA/bA/cA.
__global__ void k_pool(const float* __restrict__ x2, const int* __restrict__ rowD, const int* __restrict__ colD,
                       const float* __restrict__ xdotA, const float* __restrict__ wA2, const float* __restrict__ battp,
                       const float* __restrict__ W1, const float* __restrict__ b1,
                       const float* __restrict__ W2, const float* __restrict__ W3, const float* __restrict__ b3,
                       float* qdotA, float* mA, float* sA, float* __restrict__ xnew, float* __restrict__ wD,
                       float* aA, float* bA, float* cA){
  __shared__ float red[128];
  __shared__ float wmem[128];
  __shared__ int uc[128];
  int v = blockIdx.x, t = threadIdx.x;
  int beg = rowD[v], end = rowD[v+1];
  float batt = battp[0];
  float mx = -3.402823466e38f;
  int p = beg;
  for (; p + 4 <= end; p += 4){
    float a0 = x2[(size_t)colD[p]*HH + t];
    float a1 = x2[(size_t)colD[p+1]*HH + t];
    float a2 = x2[(size_t)colD[p+2]*HH + t];
    float a3 = x2[(size_t)colD[p+3]*HH + t];
    mx = fmaxf(fmaxf(fmaxf(fmaxf(mx, a0), a1), a2), a3);
  }
  for (; p < end; ++p) mx = fmaxf(mx, x2[(size_t)colD[p]*HH + t]);
  float qd = redSum128(red, t, mx * wA2[t]) + wA2[HH];
  float lm = -3.402823466e38f;
  for (p = beg + t; p < end; p += 128) lm = fmaxf(lm, lrelu02(qd + xdotA[colD[p]] + batt));
  float mm = redMax128(red, t, lm);
  float ls = 0.f;
  for (p = beg + t; p < end; p += 128) ls += expf(lrelu02(qd + xdotA[colD[p]] + batt) - mm);
  float ss = redSum128(red, t, ls);
  float acc = 0.f;
  for (int basep = beg; basep < end; basep += 128){
    int cnt = min(128, end - basep);
    if (t < cnt){
      int u = colD[basep + t];
      uc[t] = u;
      float w = expf(lrelu02(qd + xdotA[u] + batt) - mm) / ss;
      wmem[t] = w;
      wD[basep + t] = w;
    }
    __syncthreads();
    int i = 0;
    for (; i + 4 <= cnt; i += 4){
      float a0 = x2[(size_t)uc[i]*HH + t];
      float a1 = x2[(size_t)uc[i+1]*HH + t];
      float a2 = x2[(size_t)uc[i+2]*HH + t];
      float a3 = x2[(size_t)uc[i+3]*HH + t];
      acc += wmem[i]*a0 + wmem[i+1]*a1 + wmem[i+2]*a2 + wmem[i+3]*a3;
    }
    for (; i < cnt; ++i) acc += wmem[i] * x2[(size_t)uc[i]*HH + t];
    __syncthreads();
  }
  xnew[(size_t)v*HH + t] = acc;
  float s1 = redSum128(red, t, acc * W1[t]);
  float s2 = redSum128(red, t, acc * W2[t]);
  float s3 = redSum128(red, t, acc * W3[t]);
  if (t == 0){
    qdotA[v] = qd; mA[v] = mm; sA[v] = ss;
    aA[v] = s1 + b1[0]; bA[v] = s2; cA[v] = s3 + b3[0];
  }
}

__global__ void k_fit(const int* __restrict__ rowD, const int* __restrict__ colD,
                      const float* __restrict__ aA, const float* __restrict__ bA, const float* __restrict__ cA,
                      float* __restrict__ fitA){
  __shared__ float red[128];
  int v = blockIdx.x, t = threadIdx.x;
  int beg = rowD[v], end = rowD[v+1];
  float la = 0.f;
  for (int p = beg + t; p < end; p += 128) la += aA[colD[p]];
  float s = redSum128(red, t, la);
  if (t == 0){
    float g = s - (float)(end - beg) * bA[v] + cA[v];
    fitA[v] = 1.f / (1.f + expf(-g));
  }
}

// Exact top-K SET selection via radix-select (1 block, 1024 threads).
__global__ void k_sel(const float* __restrict__ fitA, int* perm, float* fitk, int* kcol){
  __shared__ unsigned keys[NN];
  __shared__ int hist[256];
  __shared__ int sc[1024];
  __shared__ int bc[2];
  int t = threadIdx.x;
  #pragma unroll
  for (int r = 0; r < 4; ++r){
    int i = t + r*1024;
    unsigned b = __float_as_uint(fitA[i]);
    keys[i] = (b & 0x80000000u) ? ~b : (b ^ 0x80000000u);
  }
  __syncthreads();
  unsigned prefix = 0;
  int kneed = KC;
  #pragma unroll
  for (int round = 0; round < 4; ++round){
    int shift = 24 - round*8;
    unsigned pmask = (round == 0) ? 0u : (0xFFFFFFFFu << (shift + 8));
    if (t < 256) hist[t] = 0;
    __syncthreads();
    #pragma unroll
    for (int r = 0; r < 4; ++r){
      unsigned kv = keys[t + r*1024];
      if ((kv & pmask) == prefix)
        atomicAdd(&hist[(kv >> shift) & 0xFF], 1);
    }
    __syncthreads();
    if (t == 0){
      int acc = 0, chosen = 0, rem = kneed;
      for (int bkt = 255; bkt >= 0; --bkt){
        int c = hist[bkt];
        if (acc + c >= kneed){ chosen = bkt; rem = kneed - acc; break; }
        acc += c;
      }
      bc[0] = chosen; bc[1] = rem;
    }
    __syncthreads();
    prefix |= ((unsigned)bc[0]) << shift;
    kneed = bc[1];
    __syncthreads();
  }
  unsigned T = prefix;
  int need_eq = kneed;
  int cnt[4]; int tot = 0;
  #pragma unroll
  for (int r = 0; r < 4; ++r){
    unsigned kv = keys[t*4 + r];
    int g = (kv > T) ? 1 : 0;
    int e = (kv == T) ? 1 : 0;
    cnt[r] = (g << 16) | e;
    tot += cnt[r];
  }
  sc[t] = tot; __syncthreads();
  for (int offs = 1; offs < 1024; offs <<= 1){
    int v = (t >= offs) ? sc[t - offs] : 0;
    __syncthreads();
    sc[t] += v;
    __syncthreads();
  }
  int gtot = sc[1023] >> 16;
  int run = sc[t] - tot;
  #pragma unroll
  for (int r = 0; r < 4; ++r){
    int i = t*4 + r;
    int g = cnt[r] >> 16, e = cnt[r] & 0xFFFF;
    int gpos = run >> 16, epos = run & 0xFFFF;
    int pos = -1;
    if (g) pos = gpos;
    else if (e && epos < need_eq) pos = gtot + epos;
    if (pos >= 0){ perm[pos] = i; fitk[pos] = fitA[i]; kcol[i] = pos; }
    else kcol[i] = -1;
    run += cnt[r];
  }
}

// fused: xp[j,:] = xnew[perm[j],:]*fitk[j]  AND  Xt[h][j] = f16(xp[j][h]) (conv2 transpose)
__global__ void k_xpt(const float* __restrict__ xnew, const int* __restrict__ perm,
                      const float* __restrict__ fitk, float* __restrict__ xp,
                      __half* __restrict__ Xt){
  __shared__ float T2[64][129];
  int t = threadIdx.x;
  int j0 = blockIdx.x * 64;
  for (int l = t; l < 64*32; l += 256){
    int jl = l >> 5, hg = (l & 31) * 4;
    int j = j0 + jl;
    float4 v = make_float4(0.f, 0.f, 0.f, 0.f);
    if (j < KC){
      float f = fitk[j];
      const float* src = xnew + (size_t)perm[j]*HH + hg;
      v.x = src[0]*f; v.y = src[1]*f; v.z = src[2]*f; v.w = src[3]*f;
      *(float4*)(xp + (size_t)j*HH + hg) = v;
    }
    T2[jl][hg] = v.x; T2[jl][hg+1] = v.y; T2[jl][hg+2] = v.z; T2[jl][hg+3] = v.w;
  }
  __syncthreads();
  for (int idx = t; idx < 128*64; idx += 256){
    int h = idx >> 6, jl = idx & 63;
    Xt[(size_t)h*A2P + j0 + jl] = __float2half(T2[jl][h]);
  }
}

// src-ordered per-edge weight + kept-cluster index of target
__global__ void k_wS(const int* __restrict__ mapSD, const int* __restrict__ dstS,
                     const int* __restrict__ kcol, const float* __restrict__ wD,
                     float* __restrict__ wS, int* __restrict__ kS){
  int q = blockIdx.x * blockDim.x + threadIdx.x;
  if (q >= E2) return;
  wS[q] = wD[mapSD[q]];
  kS[q] = kcol[dstS[q]];
}

// U[n,:] = (A @ S)[n,:]  (dense f16 row, stride UP, zero-padded)
__global__ void k_U(const int* __restrict__ rowS, const int* __restrict__ dstS,
                    const float* __restrict__ wS, const int* __restrict__ kS,
                    __half* __restrict__ U){
  __shared__ float acc[UP];   // 14 KB
  int t = threadIdx.x, n = blockIdx.x;
  for (int i = t; i < UP; i += 256) acc[i] = 0.f;
  __syncthreads();
  int b = rowS[n], e = rowS[n+1];
  for (int p = b; p < e; ++p){
    int j = dstS[p];
    int b2 = rowS[j], e2 = rowS[j+1];
    for (int q = b2 + t; q < e2; q += 256){
      int k = kS[q];
      if (k >= 0) atomicAdd(&acc[k], wS[q]);
    }
  }
  __syncthreads();
  __half2* Ur = (__half2*)(U + (size_t)n * UP);
  for (int i = t; i < UP/2; i += 256)
    Ur[i] = __halves2half2(__float2half(acc[2*i]), __float2half(acc[2*i+1]));
}

// A2[k1, cc*448 .. +447] = sum over in-edges of wD * U[n, chunk]; wave-per-row, 8-deep ILP.
// 8 chunks of 448 (3.67MB L2-resident slice per XCD, cc = bid&7); lanes 0-55 active.
// fused per-row nonzero count -> deg.
__global__ void k_A2B(const int* __restrict__ rowD, const int* __restrict__ colD,
                      const float* __restrict__ wD, const int* __restrict__ perm,
                      const __half* __restrict__ Uh, __half* __restrict__ A2,
                      int* __restrict__ deg){
  int cc = blockIdx.x & 7;
  int rt = blockIdx.x >> 3;
  int t = threadIdx.x;
  int w = t >> 6, lane = t & 63;
  int k1 = rt*4 + w;
  if (k1 >= KC) return;
  int cb = cc * 448;
  bool act = lane < 56;
  const _Float16* Ul = (const _Float16*)Uh + cb + lane * 8;

  float acc[8] = {0.f,0.f,0.f,0.f,0.f,0.f,0.f,0.f};
  int v1 = perm[k1];
  int beg = rowD[v1], end = rowD[v1+1];

  auto edge1 = [&](int pp){
    int n0 = colD[pp]; float w0 = wD[pp];
    if (act){
      f16x8 u0 = *(const f16x8*)(Ul + (size_t)n0 * UP);
      #pragma unroll
      for (int e = 0; e < 8; ++e) acc[e] += w0 * (float)u0[e];
    }
  };

  int p = beg;
  int pre = (4 - (p & 3)) & 3;
  if (pre > end - p) pre = end - p;
  for (int z = 0; z < pre; ++z){ edge1(p); ++p; }
  for (; p + 8 <= end; p += 8){
    int4 nA = *(const int4*)(colD + p);
    int4 nB = *(const int4*)(colD + p + 4);
    float4 wA = *(const float4*)(wD + p);
    float4 wB = *(const float4*)(wD + p + 4);
    if (act){
      f16x8 u0 = *(const f16x8*)(Ul + (size_t)nA.x * UP);
      f16x8 u1 = *(const f16x8*)(Ul + (size_t)nA.y * UP);
      f16x8 u2 = *(const f16x8*)(Ul + (size_t)nA.z * UP);
      f16x8 u3 = *(const f16x8*)(Ul + (size_t)nA.w * UP);
      f16x8 u4 = *(const f16x8*)(Ul + (size_t)nB.x * UP);
      f16x8 u5 = *(const f16x8*)(Ul + (size_t)nB.y * UP);
      f16x8 u6 = *(const f16x8*)(Ul + (size_t)nB.z * UP);
      f16x8 u7 = *(const f16x8*)(Ul + (size_t)nB.w * UP);
      #pragma unroll
      for (int e = 0; e < 8; ++e){
        acc[e] += wA.x*(float)u0[e] + wA.y*(float)u1[e] + wA.z*(float)u2[e] + wA.w*(float)u3[e]
                + wB.x*(float)u4[e] + wB.y*(float)u5[e] + wB.z*(float)u6[e] + wB.w*(float)u7[e];
      }
    }
  }
  for (; p + 4 <= end; p += 4){
    int4 nA = *(const int4*)(colD + p);
    float4 wA = *(const float4*)(wD + p);
    if (act){
      f16x8 u0 = *(const f16x8*)(Ul + (size_t)nA.x * UP);
      f16x8 u1 = *(const f16x8*)(Ul + (size_t)nA.y * UP);
      f16x8 u2 = *(const f16x8*)(Ul + (size_t)nA.z * UP);
      f16x8 u3 = *(const f16x8*)(Ul + (size_t)nA.w * UP);
      #pragma unroll
      for (int e = 0; e < 8; ++e)
        acc[e] += wA.x*(float)u0[e] + wA.y*(float)u1[e] + wA.z*(float)u2[e] + wA.w*(float)u3[e];
    }
  }
  for (; p < end; ++p) edge1(p);

  int col0 = cb + lane * 8;
  f16x8 o = (f16x8)(_Float16)0;
  int c = 0;
  if (act){
    #pragma unroll
    for (int e = 0; e < 8; ++e){
      int col = col0 + e;
      float val = (col == k1 || col >= KC) ? 0.f : acc[e];
      _Float16 hv = (_Float16)val;
      o[e] = hv;
      c += (hv != (_Float16)0) ? 1 : 0;
    }
  }
  #pragma unroll
  for (int s = 32; s > 0; s >>= 1) c += __shfl_down(c, s);
  if (lane == 0) atomicAdd(&deg[k1], c);
  if (act && col0 + 8 <= A2P)
    *(f16x8*)(A2 + (size_t)k1 * A2P + col0) = o;
}

// LDS-tiled transpose: A2T[i][j] = A2[j][i]; rows j >= KC read as zero.
__global__ void k_tr(const __half* __restrict__ A2, __half* __restrict__ A2T){
  __shared__ float tile[64][65];
  int t = threadIdx.x;
  int i0 = blockIdx.x * 64, j0 = blockIdx.y * 64;
  int sl = t & 7;
  #pragma unroll
  for (int p = 0; p < 2; ++p){
    int jl = (t >> 3) + p*32;
    int j = j0 + jl;
    f16x8 v;
    if (j < KC) v = *(const f16x8*)(A2 + (size_t)j*A2P + i0 + sl*8);
    else v = (f16x8)(_Float16)0;
    #pragma unroll
    for (int e = 0; e < 8; ++e) tile[jl][sl*8 + e] = (float)v[e];
  }
  __syncthreads();
  #pragma unroll
  for (int p = 0; p < 2; ++p){
    int il = (t >> 3) + p*32;
    int i = i0 + il;
    f16x8 o;
    #pragma unroll
    for (int e = 0; e < 8; ++e) o[e] = (_Float16)tile[sl*8 + e][il];
    *(f16x8*)(A2T + (size_t)i*A2P + j0 + sl*8) = o;
  }
}

// Xt[h][j] = (f16) X[j][h], zero-padded for j >= KC. Block: 64 j x 128 h.
__global__ void k_xt(const float* __restrict__ X, __half* __restrict__ Xt){
  __shared__ float T2[64][129];
  int t = threadIdx.x;
  int j0 = blockIdx.x * 64;
  for (int l = t; l < 64*32; l += 256){
    int jl = l >> 5, hg = (l & 31) * 4;
    int j = j0 + jl;
    float4 v = make_float4(0.f, 0.f, 0.f, 0.f);
    if (j < KC) v = *(const float4*)(X + (size_t)j*HH + hg);
    T2[jl][hg] = v.x; T2[jl][hg+1] = v.y; T2[jl][hg+2] = v.z; T2[jl][hg+3] = v.w;
  }
  __syncthreads();
  for (int idx = t; idx < 128*64; idx += 256){
    int h = idx >> 6, jl = idx & 63;
    Xt[(size_t)h*A2P + j0 + jl] = __float2half(T2[jl][h]);
  }
}

// MFMA dagg, K-split 2, atomic-free: part[half][i*HH+h] = sum_{j in half} A2T[i,j]*Xt[h,j].
// grid = (A2P/16)*2 = 416 blocks; 4 waves, each 16i x 32h, K-unroll 2.
__global__ void k_mm(const __half* __restrict__ A2Th, const __half* __restrict__ Xth,
                     float* __restrict__ part){
  const _Float16* A2T = (const _Float16*)A2Th;
  const _Float16* Xt  = (const _Float16*)Xth;
  int t = threadIdx.x;
  int lane = t & 63, w = t >> 6;
  int i0 = (blockIdx.x >> 1) * 16;
  int half = blockIdx.x & 1;
  int kbeg = half * KHALF;
  float* po = part + (size_t)half * KC * HH;
  int l15 = lane & 15, lk = (lane >> 4) * 8;
  const _Float16* Arow = A2T + (size_t)(i0 + l15) * A2P + lk + kbeg;
  const _Float16* B0 = Xt + (size_t)(w*32 + l15) * A2P + lk + kbeg;
  const _Float16* B1 = B0 + (size_t)16 * A2P;
  f32x4 acc0 = (f32x4)0.f, acc1 = (f32x4)0.f;
  for (int kk = 0; kk < KHALF; kk += 64){
    f16x8 a0 = *(const f16x8*)(Arow + kk);
    f16x8 a1 = *(const f16x8*)(Arow + kk + 32);
    f16x8 b00 = *(const f16x8*)(B0 + kk);
    f16x8 b01 = *(const f16x8*)(B1 + kk);
    f16x8 b10 = *(const f16x8*)(B0 + kk + 32);
    f16x8 b11 = *(const f16x8*)(B1 + kk + 32);
    acc0 = __builtin_amdgcn_mfma_f32_16x16x32_f16(a0, b00, acc0, 0, 0, 0);
    acc1 = __builtin_amdgcn_mfma_f32_16x16x32_f16(a0, b01, acc1, 0, 0, 0);
    acc0 = __builtin_amdgcn_mfma_f32_16x16x32_f16(a1, b10, acc0, 0, 0, 0);
    acc1 = __builtin_amdgcn_mfma_f32_16x16x32_f16(a1, b11, acc1, 0, 0, 0);
  }
  int rbase = (lane >> 4) * 4;
  #pragma unroll
  for (int r = 0; r < 4; ++r){
    int i = i0 + rbase + r;
    if (i < KC){
      po[(size_t)i*HH + w*32 + l15] = acc0[r];
      po[(size_t)i*HH + w*32 + 16 + l15] = acc1[r];
    }
  }
}

} // namespace

extern "C" void kernel_launch(void* const* d_in, const int* in_sizes, int n_in,
                              void* d_out, int out_size, void* d_ws, size_t ws_size,
                              hipStream_t stream){
  (void)in_sizes; (void)n_in; (void)out_size; (void)ws_size;
  const float* x      = (const float*)d_in[0];
  const int*   ei     = (const int*)d_in[1];
  const float* c0Wrel = (const float*)d_in[2];
  const float* c0brel = (const float*)d_in[3];
  const float* c0Wroot= (const float*)d_in[4];
  const float* c1Wrel = (const float*)d_in[5];
  const float* c1brel = (const float*)d_in[6];
  const float* c1Wroot= (const float*)d_in[7];
  const float* c2Wrel = (const float*)d_in[8];
  const float* c2brel = (const float*)d_in[9];
  const float* c2Wroot= (const float*)d_in[10];
  const float* c3Wrel = (const float*)d_in[11];
  const float* c3brel = (const float*)d_in[12];
  const float* c3Wroot= (const float*)d_in[13];
  const float* Wlin   = (const float*)d_in[14];
  const float* blin   = (const float*)d_in[15];
  const float* Watt   = (const float*)d_in[16];
  const float* batt   = (const float*)d_in[17];
  const float* W1     = (const float*)d_in[18];
  const float* b1     = (const float*)d_in[19];
  const float* W2     = (const float*)d_in[20];
  const float* W3     = (const float*)d_in[21];
  const float* b3     = (const float*)d_in[22];
  float* out = (float*)d_out;

  char* base = (char*)d_ws;
  size_t off = 0;
  auto carve = [&](size_t bytes) -> void* {
    void* p = base + off;
    off += (bytes + 255) & ~(size_t)255;
    return p;
  };
  float* x1    = (float*)carve((size_t)NN*HH*4);
  float* x2b   = (float*)carve((size_t)NN*HH*4);
  float* meanb = (float*)carve((size_t)NN*HH*4);
  float* xnew  = (float*)carve((size_t)NN*HH*4);
  float* xp    = (float*)carve((size_t)KC*HH*4);
  float* x3    = (float*)carve((size_t)KC*HH*4);
  float* x4    = (float*)carve((size_t)KC*HH*4);
  float* part  = (float*)carve((size_t)2*KC*HH*4);   // k_mm partials
  __half* A2   = (__half*)carve((size_t)KC*A2P*2);   // ~22 MB
  __half* U    = (__half*)carve((size_t)NN*UP*2);    // ~29 MB; dead after k_A2B -> reused as A2T
  __half* A2T  = U;                                   // [A2P][A2P] f16 = 22.2 MB fits in U's 29.4 MB
  __half* Xt   = (__half*)carve((size_t)HH*A2P*2);   // 852 KB
  float* xdot  = (float*)carve(NN*4);
  float* qdot  = (float*)carve(NN*4);
  float* mmaxA = (float*)carve(NN*4);
  float* ssumA = (float*)carve(NN*4);
  float* aA    = (float*)carve(NN*4);
  float* bA    = (float*)carve(NN*4);
  float* cA    = (float*)carve(NN*4);
  float* fitA  = (float*)carve(NN*4);
  float* fitk  = (float*)carve(KC*4);
  float* wA2   = (float*)carve((HH+1)*4);
  float* wD    = (float*)carve((size_t)E2*4);
  float* wSar  = (float*)carve((size_t)E2*4);
  int* rowD = (int*)carve((NN+1)*4);
  int* rowS = (int*)carve((NN+1)*4);
  int* cntD = (int*)carve(NN*4);
  int* cntS = (int*)carve(NN*4);
  int* curD = (int*)carve(NN*4);
  int* curS = (int*)carve(NN*4);
  int* colD = (int*)carve((size_t)E2*4);
  int* dstS = (int*)carve((size_t)E2*4);
  int* mapSD= (int*)carve((size_t)E2*4);
  int* kSar = (int*)carve((size_t)E2*4);
  int* perm = (int*)carve(KC*4);
  int* kcol = (int*)carve(NN*4);
  int* deg3 = (int*)carve(KC*4);

  k_zero_init<<<NN/256, 256, 0, stream>>>(cntD, cntS, deg3, out);
  k_count<<<(E2+255)/256, 256, 0, stream>>>(ei, cntD, cntS);
  k_scan<<<1, 1024, 0, stream>>>(cntD, cntS, rowD, rowS, curD, curS);
  k_scatter<<<(E2+255)/256, 256, 0, stream>>>(ei, curD, curS, colD, dstS, mapSD);

  // conv0
  k_edge_mean<<<NN, 128, 0, stream>>>(x, rowD, colD, meanb);
  k_lin<<<(NN+15)/16, 256, 0, stream>>>(meanb, x, c0Wrel, c0brel, c0Wroot, x1, NN);
  k_colmean<<<(NN+63)/64, 128, 0, stream>>>(x1, NN, out + 0);

  // conv1
  k_edge_mean<<<NN, 128, 0, stream>>>(x1, rowD, colD, meanb);
  k_lin<<<(NN+15)/16, 256, 0, stream>>>(meanb, x1, c1Wrel, c1brel, c1Wroot, x2b, NN);
  k_colmean<<<(NN+63)/64, 128, 0, stream>>>(x2b, NN, out + 128);

  // ASAP pool
  k_wprep<<<1, 128, 0, stream>>>(Wlin, blin, Watt, wA2);
  k_xdot<<<NN, 128, 0, stream>>>(x2b, Watt, xdot);
  k_pool<<<NN, 128, 0, stream>>>(x2b, rowD, colD, xdot, wA2, batt,
                                 W1, b1, W2, W3, b3,
                                 qdot, mmaxA, ssumA, xnew, wD, aA, bA, cA);
  k_fit<<<NN, 128, 0, stream>>>(rowD, colD, aA, bA, cA, fitA);
  k_sel<<<1, 1024, 0, stream>>>(fitA, perm, fitk, kcol);
  k_wS<<<(E2+255)/256, 256, 0, stream>>>(mapSD, dstS, kcol, wD, wSar, kSar);
  k_U<<<NN, 256, 0, stream>>>(rowS, dstS, wSar, kSar, U);
  k_A2B<<<A2B_RT*8, 256, 0, stream>>>(rowD, colD, wD, perm, U, A2, deg3);

  // transpose A2 -> A2T (U is dead now; A2T aliases it)
  k_tr<<<dim3(A2P/64, A2P/64), 256, 0, stream>>>(A2, A2T);

  // conv2 (dense, MFMA K-split 2; partial-sum + deg-mean fused into k_lin2)
  k_xpt<<<A2P/64, 256, 0, stream>>>(xnew, perm, fitk, xp, Xt);
  k_mm<<<(A2P/16)*2, 256, 0, stream>>>(A2T, Xt, part);
  k_lin2<<<(KC+15)/16, 256, 0, stream>>>(part, part + (size_t)KC*HH, deg3, xp,
                                         c2Wrel, c2brel, c2Wroot, x3, KC);
  k_colmean<<<(KC+63)/64, 128, 0, stream>>>(x3, KC, out + 256);

  // conv3 (dense, MFMA)
  k_xt<<<A2P/64, 256, 0, stream>>>(x3, Xt);
  k_mm<<<(A2P/16)*2, 256, 0, stream>>>(A2T, Xt, part);
  k_lin2<<<(KC+15)/16, 256, 0, stream>>>(part, part + (size_t)KC*HH, deg3, x3,
                                         c3Wrel, c3brel, c3Wroot, x4, KC);
  k_colmean<<<(KC+63)/64, 128, 0, stream>>>(x4, KC, out + 384);
}

// Round 9
// 475.766 us; speedup vs baseline: 4.3942x; 1.0121x over previous
//
#include <hip/hip_runtime.h>
#include <hip/hip_fp16.h>
#include <math.h>

namespace {

constexpr int NN = 4096;
constexpr int EE = 131072;
constexpr int E2 = EE + NN;      // 135168 pool edges (orig + self loops)
constexpr int HH = 128;
constexpr int KC = 3277;         // ceil(0.8*4096)
constexpr int UP = 3584;         // U row stride (8*448)
constexpr int A2P = 3328;        // A2 row/col padded dim

typedef _Float16 f16x8 __attribute__((ext_vector_type(8)));
typedef float f32x4 __attribute__((ext_vector_type(4)));

constexpr int A2B_RT = (KC + 3) / 4;   // 820 row-groups (4 waves/block)
constexpr int KHALF = A2P / 2;          // 1664

__device__ __forceinline__ float lrelu02(float x){ return x > 0.f ? x : 0.2f * x; }

__device__ __forceinline__ float redSum128(float* red, int t, float v){
  red[t] = v; __syncthreads();
  #pragma unroll
  for (int s = 64; s > 0; s >>= 1){ if (t < s) red[t] += red[t + s]; __syncthreads(); }
  float r = red[0]; __syncthreads();
  return r;
}
__device__ __forceinline__ float redMax128(float* red, int t, float v){
  red[t] = v; __syncthreads();
  #pragma unroll
  for (int s = 64; s > 0; s >>= 1){ if (t < s) red[t] = fmaxf(red[t], red[t + s]); __syncthreads(); }
  float r = red[0]; __syncthreads();
  return r;
}

__global__ void k_zero_init(int* cntD, int* cntS, int* deg, float* out){
  int i = blockIdx.x * blockDim.x + threadIdx.x;
  if (i < NN){ cntD[i] = 0; cntS[i] = 0; }
  if (i < KC) deg[i] = 0;
  if (i < 512) out[i] = 0.f;
}

__global__ void k_count(const int* __restrict__ ei, int* cntD, int* cntS){
  int e = blockIdx.x * blockDim.x + threadIdx.x;
  if (e >= E2) return;
  int u, v;
  if (e < EE){ u = ei[e]; v = ei[EE + e]; } else { u = e - EE; v = u; }
  atomicAdd(&cntD[v], 1);
  atomicAdd(&cntS[u], 1);
}

__global__ void k_scan(const int* cntD, const int* cntS, int* rowD, int* rowS, int* curD, int* curS){
  __shared__ int sc[1024];
  int t = threadIdx.x;
  for (int pass = 0; pass < 2; ++pass){
    const int* cnt = pass ? cntS : cntD;
    int* row = pass ? rowS : rowD;
    int* cur = pass ? curS : curD;
    int c0 = cnt[t*4+0], c1 = cnt[t*4+1], c2 = cnt[t*4+2], c3 = cnt[t*4+3];
    int tot = c0 + c1 + c2 + c3;
    sc[t] = tot; __syncthreads();
    for (int offs = 1; offs < 1024; offs <<= 1){
      int v = (t >= offs) ? sc[t - offs] : 0;
      __syncthreads();
      sc[t] += v;
      __syncthreads();
    }
    int excl = sc[t] - tot;
    int r0 = excl, r1 = r0 + c0, r2 = r1 + c1, r3 = r2 + c2;
    row[t*4+0] = r0; row[t*4+1] = r1; row[t*4+2] = r2; row[t*4+3] = r3;
    cur[t*4+0] = r0; cur[t*4+1] = r1; cur[t*4+2] = r2; cur[t*4+3] = r3;
    if (t == 1023) row[NN] = r3 + c3;
    __syncthreads();
  }
}

__global__ void k_scatter(const int* __restrict__ ei, int* curD, int* curS,
                          int* colD, int* dstS, int* mapSD){
  int e = blockIdx.x * blockDim.x + threadIdx.x;
  if (e >= E2) return;
  int u, v;
  if (e < EE){ u = ei[e]; v = ei[EE + e]; } else { u = e - EE; v = u; }
  int p = atomicAdd(&curD[v], 1); colD[p] = u;
  int q = atomicAdd(&curS[u], 1); dstS[q] = v; mapSD[q] = p;
}

// mean over in-neighbors (original edges only -> skip the self loop entry u==v)
__global__ void k_edge_mean(const float* __restrict__ xin, const int* __restrict__ rowD,
                            const int* __restrict__ colD, float* __restrict__ meanb){
  int v = blockIdx.x, t = threadIdx.x;
  int beg = rowD[v], end = rowD[v+1];
  float acc = 0.f;
  int p = beg;
  for (; p + 8 <= end; p += 8){
    int u0 = colD[p],   u1 = colD[p+1], u2 = colD[p+2], u3 = colD[p+3];
    int u4 = colD[p+4], u5 = colD[p+5], u6 = colD[p+6], u7 = colD[p+7];
    float a0 = xin[(size_t)u0*HH + t];
    float a1 = xin[(size_t)u1*HH + t];
    float a2 = xin[(size_t)u2*HH + t];
    float a3 = xin[(size_t)u3*HH + t];
    float a4 = xin[(size_t)u4*HH + t];
    float a5 = xin[(size_t)u5*HH + t];
    float a6 = xin[(size_t)u6*HH + t];
    float a7 = xin[(size_t)u7*HH + t];
    if (u0 != v) acc += a0;
    if (u1 != v) acc += a1;
    if (u2 != v) acc += a2;
    if (u3 != v) acc += a3;
    if (u4 != v) acc += a4;
    if (u5 != v) acc += a5;
    if (u6 != v) acc += a6;
    if (u7 != v) acc += a7;
  }
  for (; p < end; ++p){ int u = colD[p]; if (u != v) acc += xin[(size_t)u*HH + t]; }
  float dg = (float)(end - beg - 1);
  meanb[v*HH + t] = acc / fmaxf(dg, 1.f);
}

// xout = relu(meanb @ Wrel^T + brel + xin @ Wroot^T), 16 rows/block
__global__ void k_lin(const float* __restrict__ meanb, const float* __restrict__ xin,
                      const float* __restrict__ Wrel, const float* __restrict__ brel,
                      const float* __restrict__ Wroot, float* __restrict__ xout, int rows){
  __shared__ float ms[16][HH];
  __shared__ float xs[16][HH];
  int tid = threadIdx.x;
  int r0 = blockIdx.x * 16;
  for (int l = tid; l < 16*HH; l += 256){
    int r = l >> 7, c = l & 127; int gr = r0 + r;
    float mv = 0.f, xv = 0.f;
    if (gr < rows){ mv = meanb[(size_t)gr*HH + c]; xv = xin[(size_t)gr*HH + c]; }
    ms[r][c] = mv; xs[r][c] = xv;
  }
  __syncthreads();
  int h = tid & 127, hgrp = tid >> 7;
  float acc[8] = {0.f,0.f,0.f,0.f,0.f,0.f,0.f,0.f};
  for (int c = 0; c < HH; ++c){
    float wr = Wrel[h*HH + c], wo = Wroot[h*HH + c];
    #pragma unroll
    for (int r = 0; r < 8; ++r) acc[r] += ms[hgrp*8 + r][c]*wr + xs[hgrp*8 + r][c]*wo;
  }
  float bb = brel[h];
  #pragma unroll
  for (int r = 0; r < 8; ++r){
    int gr = r0 + hgrp*8 + r;
    if (gr < rows) xout[(size_t)gr*HH + h] = fmaxf(acc[r] + bb, 0.f);
  }
}

// dense-conv linear with fused partial-sum + deg-mean
__global__ void k_lin2(const float* __restrict__ p0, const float* __restrict__ p1,
                       const int* __restrict__ deg, const float* __restrict__ xin,
                       const float* __restrict__ Wrel, const float* __restrict__ brel,
                       const float* __restrict__ Wroot, float* __restrict__ xout, int rows){
  __shared__ float ms[16][HH];
  __shared__ float xs[16][HH];
  int tid = threadIdx.x;
  int r0 = blockIdx.x * 16;
  for (int l = tid; l < 16*HH; l += 256){
    int r = l >> 7, c = l & 127; int gr = r0 + r;
    float mv = 0.f, xv = 0.f;
    if (gr < rows){
      float d = fmaxf((float)deg[gr], 1.f);
      mv = (p0[(size_t)gr*HH + c] + p1[(size_t)gr*HH + c]) / d;
      xv = xin[(size_t)gr*HH + c];
    }
    ms[r][c] = mv; xs[r][c] = xv;
  }
  __syncthreads();
  int h = tid & 127, hgrp = tid >> 7;
  float acc[8] = {0.f,0.f,0.f,0.f,0.f,0.f,0.f,0.f};
  for (int c = 0; c < HH; ++c){
    float wr = Wrel[h*HH + c], wo = Wroot[h*HH + c];
    #pragma unroll
    for (int r = 0; r < 8; ++r) acc[r] += ms[hgrp*8 + r][c]*wr + xs[hgrp*8 + r][c]*wo;
  }
  float bb = brel[h];
  #pragma unroll
  for (int r = 0; r < 8; ++r){
    int gr = r0 + hgrp*8 + r;
    if (gr < rows) xout[(size_t)gr*HH + h] = fmaxf(acc[r] + bb, 0.f);
  }
}

__global__ void k_colmean(const float* __restrict__ x, int rows, float* __restrict__ outp){
  int t = threadIdx.x;
  int r0 = blockIdx.x * 64;
  int rend = min(rows, r0 + 64);
  float acc = 0.f;
  for (int r = r0; r < rend; ++r) acc += x[(size_t)r*HH + t];
  atomicAdd(&outp[t], acc / (float)rows);
}

// wA2[c] = sum_h wattA[h]*Wlin[h,c];  wA2[HH] = sum_h blin[h]*wattA[h]
__global__ void k_wprep(const float* __restrict__ Wlin, const float* __restrict__ blin,
                        const float* __restrict__ Watt, float* __restrict__ wA2){
  int c = threadIdx.x;
  float s = 0.f;
  for (int hh = 0; hh < HH; ++hh) s += Watt[hh] * Wlin[hh*HH + c];
  wA2[c] = s;
  if (c == 0){
    float q = 0.f;
    for (int hh = 0; hh < HH; ++hh) q += blin[hh] * Watt[hh];
    wA2[HH] = q;
  }
}

__global__ void k_xdot(const float* __restrict__ x2, const float* __restrict__ Watt, float* __restrict__ xdot){
  __shared__ float red[128];
  int n = blockIdx.x, t = threadIdx.x;
  float v = redSum128(red, t, x2[(size_t)n*HH + t] * Watt[HH + t]);
  if (t == 0) xdot[n] = v;
}

// per dst node v: xq max -> qdot; edge-softmax stats; x_new; wD; fused LEConv partials.
__global__ void k_pool(const float* __restrict__ x2, const int* __restrict__ rowD, const int* __restrict__ colD,
                       const float* __restrict__ xdotA, const float* __restrict__ wA2, const float* __restrict__ battp,
                       const float* __restrict__ W1, const float* __restrict__ b1,
                       const float* __restrict__ W2, const float* __restrict__ W3, const float* __restrict__ b3,
                       float* qdotA, float* mA, float* sA, float* __restrict__ xnew, float* __restrict__ wD,
                       float* aA, float* bA, float* cA){
  __shared__ float red[128];
  __shared__ float wmem[128];
  __shared__ int uc[128];
  int v = blockIdx.x, t = threadIdx.x;
  int beg = rowD[v], end = rowD[v+1];
  float batt = battp[0];
  float mx = -3.402823466e38f;
  int p = beg;
  for (; p + 4 <= end; p += 4){
    float a0 = x2[(size_t)colD[p]*HH + t];
    float a1 = x2[(size_t)colD[p+1]*HH + t];
    float a2 = x2[(size_t)colD[p+2]*HH + t];
    float a3 = x2[(size_t)colD[p+3]*HH + t];
    mx = fmaxf(fmaxf(fmaxf(fmaxf(mx, a0), a1), a2), a3);
  }
  for (; p < end; ++p) mx = fmaxf(mx, x2[(size_t)colD[p]*HH + t]);
  float qd = redSum128(red, t, mx * wA2[t]) + wA2[HH];
  float lm = -3.402823466e38f;
  for (p = beg + t; p < end; p += 128) lm = fmaxf(lm, lrelu02(qd + xdotA[colD[p]] + batt));
  float mm = redMax128(red, t, lm);
  float ls = 0.f;
  for (p = beg + t; p < end; p += 128) ls += expf(lrelu02(qd + xdotA[colD[p]] + batt) - mm);
  float ss = redSum128(red, t, ls);
  float acc = 0.f;
  for (int basep = beg; basep < end; basep += 128){
    int cnt = min(128, end - basep);
    if (t < cnt){
      int u = colD[basep + t];
      uc[t] = u;
      float w = expf(lrelu02(qd + xdotA[u] + batt) - mm) / ss;
      wmem[t] = w;
      wD[basep + t] = w;
    }
    __syncthreads();
    int i = 0;
    for (; i + 4 <= cnt; i += 4){
      float a0 = x2[(size_t)uc[i]*HH + t];
      float a1 = x2[(size_t)uc[i+1]*HH + t];
      float a2 = x2[(size_t)uc[i+2]*HH + t];
      float a3 = x2[(size_t)uc[i+3]*HH + t];
      acc += wmem[i]*a0 + wmem[i+1]*a1 + wmem[i+2]*a2 + wmem[i+3]*a3;
    }
    for (; i < cnt; ++i) acc += wmem[i] * x2[(size_t)uc[i]*HH + t];
    __syncthreads();
  }
  xnew[(size_t)v*HH + t] = acc;
  float s1 = redSum128(red, t, acc * W1[t]);
  float s2 = redSum128(red, t, acc * W2[t]);
  float s3 = redSum128(red, t, acc * W3[t]);
  if (t == 0){
    qdotA[v] = qd; mA[v] = mm; sA[v] = ss;
    aA[v] = s1 + b1[0]; bA[v] = s2; cA[v] = s3 + b3[0];
  }
}

__global__ void k_fit(const int* __restrict__ rowD, const int* __restrict__ colD,
                      const float* __restrict__ aA, const float* __restrict__ bA, const float* __restrict__ cA,
                      float* __restrict__ fitA){
  __shared__ float red[128];
  int v = blockIdx.x, t = threadIdx.x;
  int beg = rowD[v], end = rowD[v+1];
  float la = 0.f;
  for (int p = beg + t; p < end; p += 128) la += aA[colD[p]];
  float s = redSum128(red, t, la);
  if (t == 0){
    float g = s - (float)(end - beg) * bA[v] + cA[v];
    fitA[v] = 1.f / (1.f + expf(-g));
  }
}

// Exact top-K SET selection via radix-select (1 block, 1024 threads).
__global__ void k_sel(const float* __restrict__ fitA, int* perm, float* fitk, int* kcol){
  __shared__ unsigned keys[NN];
  __shared__ int hist[256];
  __shared__ int sc[1024];
  __shared__ int bc[2];
  int t = threadIdx.x;
  #pragma unroll
  for (int r = 0; r < 4; ++r){
    int i = t + r*1024;
    unsigned b = __float_as_uint(fitA[i]);
    keys[i] = (b & 0x80000000u) ? ~b : (b ^ 0x80000000u);
  }
  __syncthreads();
  unsigned prefix = 0;
  int kneed = KC;
  #pragma unroll
  for (int round = 0; round < 4; ++round){
    int shift = 24 - round*8;
    unsigned pmask = (round == 0) ? 0u : (0xFFFFFFFFu << (shift + 8));
    if (t < 256) hist[t] = 0;
    __syncthreads();
    #pragma unroll
    for (int r = 0; r < 4; ++r){
      unsigned kv = keys[t + r*1024];
      if ((kv & pmask) == prefix)
        atomicAdd(&hist[(kv >> shift) & 0xFF], 1);
    }
    __syncthreads();
    if (t == 0){
      int acc = 0, chosen = 0, rem = kneed;
      for (int bkt = 255; bkt >= 0; --bkt){
        int c = hist[bkt];
        if (acc + c >= kneed){ chosen = bkt; rem = kneed - acc; break; }
        acc += c;
      }
      bc[0] = chosen; bc[1] = rem;
    }
    __syncthreads();
    prefix |= ((unsigned)bc[0]) << shift;
    kneed = bc[1];
    __syncthreads();
  }
  unsigned T = prefix;
  int need_eq = kneed;
  int cnt[4]; int tot = 0;
  #pragma unroll
  for (int r = 0; r < 4; ++r){
    unsigned kv = keys[t*4 + r];
    int g = (kv > T) ? 1 : 0;
    int e = (kv == T) ? 1 : 0;
    cnt[r] = (g << 16) | e;
    tot += cnt[r];
  }
  sc[t] = tot; __syncthreads();
  for (int offs = 1; offs < 1024; offs <<= 1){
    int v = (t >= offs) ? sc[t - offs] : 0;
    __syncthreads();
    sc[t] += v;
    __syncthreads();
  }
  int gtot = sc[1023] >> 16;
  int run = sc[t] - tot;
  #pragma unroll
  for (int r = 0; r < 4; ++r){
    int i = t*4 + r;
    int g = cnt[r] >> 16, e = cnt[r] & 0xFFFF;
    int gpos = run >> 16, epos = run & 0xFFFF;
    int pos = -1;
    if (g) pos = gpos;
    else if (e && epos < need_eq) pos = gtot + epos;
    if (pos >= 0){ perm[pos] = i; fitk[pos] = fitA[i]; kcol[i] = pos; }
    else kcol[i] = -1;
    run += cnt[r];
  }
}

// fused: xp[j,:] = xnew[perm[j],:]*fitk[j]  AND  Xt[h][j] = f16(xp[j][h])
__global__ void k_xpt(const float* __restrict__ xnew, const int* __restrict__ perm,
                      const float* __restrict__ fitk, float* __restrict__ xp,
                      __half* __restrict__ Xt){
  __shared__ float T2[64][129];
  int t = threadIdx.x;
  int j0 = blockIdx.x * 64;
  for (int l = t; l < 64*32; l += 256){
    int jl = l >> 5, hg = (l & 31) * 4;
    int j = j0 + jl;
    float4 v = make_float4(0.f, 0.f, 0.f, 0.f);
    if (j < KC){
      float f = fitk[j];
      const float* src = xnew + (size_t)perm[j]*HH + hg;
      v.x = src[0]*f; v.y = src[1]*f; v.z = src[2]*f; v.w = src[3]*f;
      *(float4*)(xp + (size_t)j*HH + hg) = v;
    }
    T2[jl][hg] = v.x; T2[jl][hg+1] = v.y; T2[jl][hg+2] = v.z; T2[jl][hg+3] = v.w;
  }
  __syncthreads();
  for (int idx = t; idx < 128*64; idx += 256){
    int h = idx >> 6, jl = idx & 63;
    Xt[(size_t)h*A2P + j0 + jl] = __float2half(T2[jl][h]);
  }
}

// src-ordered packed (kcol, w) for k_U; dst-ordered byte-offset + f16 weight for k_A2B
__global__ void k_wS(const int* __restrict__ mapSD, const int* __restrict__ dstS,
                     const int* __restrict__ kcol, const float* __restrict__ wD,
                     const int* __restrict__ colD,
                     int2* __restrict__ kwS, unsigned* __restrict__ offsD,
                     __half* __restrict__ wHD){
  int q = blockIdx.x * blockDim.x + threadIdx.x;
  if (q >= E2) return;
  float w = wD[mapSD[q]];
  int k = kcol[dstS[q]];
  kwS[q] = make_int2(k, __float_as_int(w));
  offsD[q] = (unsigned)colD[q] * (UP*2);
  wHD[q] = __float2half(wD[q]);
}

// U[n,:] = (A @ S)[n,:]  (dense f16 row, stride UP, zero-padded)
__global__ void k_U(const int* __restrict__ rowS, const int* __restrict__ dstS,
                    const int2* __restrict__ kwS, __half* __restrict__ U){
  __shared__ float acc[UP];   // 14 KB
  int t = threadIdx.x, n = blockIdx.x;
  for (int i = t; i < UP; i += 256) acc[i] = 0.f;
  __syncthreads();
  int b = rowS[n], e = rowS[n+1];
  for (int p = b; p < e; ++p){
    int j = dstS[p];
    int b2 = rowS[j], e2 = rowS[j+1];
    for (int q = b2 + t; q < e2; q += 256){
      int2 kw = kwS[q];
      if (kw.x >= 0) atomicAdd(&acc[kw.x], __int_as_float(kw.y));
    }
  }
  __syncthreads();
  __half2* Ur = (__half2*)(U + (size_t)n * UP);
  for (int i = t; i < UP/2; i += 256)
    Ur[i] = __halves2half2(__float2half(acc[2*i]), __float2half(acc[2*i+1]));
}

// A2[k1, cc*448 .. +447] = sum over in-edges of w * U[n, chunk]; wave-per-row.
// Precomputed u32 byte-offsets (saddr form) + f16 pk_fma accumulation, 4 rotating accs.
__global__ void k_A2B(const int* __restrict__ rowD,
                      const unsigned* __restrict__ offsD, const __half* __restrict__ wHDh,
                      const int* __restrict__ perm,
                      const __half* __restrict__ Uh, __half* __restrict__ A2,
                      int* __restrict__ deg){
  int cc = blockIdx.x & 7;
  int rt = blockIdx.x >> 3;
  int t = threadIdx.x;
  int w = t >> 6, lane = t & 63;
  int k1 = rt*4 + w;
  if (k1 >= KC) return;
  bool act = lane < 56;
  unsigned laneoff = (unsigned)(cc*448*2 + lane*16);
  const char* Ub = (const char*)Uh;
  const _Float16* wHD = (const _Float16*)wHDh;

  f16x8 accA = (f16x8)(_Float16)0, accB = (f16x8)(_Float16)0;
  f16x8 accC = (f16x8)(_Float16)0, accD = (f16x8)(_Float16)0;
  int v1 = perm[k1];
  int beg = rowD[v1], end = rowD[v1+1];

  int p = beg;
  int pre = (8 - (p & 7)) & 7;
  if (pre > end - p) pre = end - p;
  for (int z = 0; z < pre; ++z, ++p){
    unsigned off = offsD[p];
    _Float16 w0 = wHD[p];
    if (act){
      f16x8 u = *(const f16x8*)(Ub + (size_t)(off + laneoff));
      accA += u * w0;
    }
  }
  for (; p + 8 <= end; p += 8){
    uint4 oA = *(const uint4*)(offsD + p);
    uint4 oB = *(const uint4*)(offsD + p + 4);
    f16x8 wv = *(const f16x8*)(wHD + p);
    if (act){
      f16x8 u0 = *(const f16x8*)(Ub + (size_t)(oA.x + laneoff));
      f16x8 u1 = *(const f16x8*)(Ub + (size_t)(oA.y + laneoff));
      f16x8 u2 = *(const f16x8*)(Ub + (size_t)(oA.z + laneoff));
      f16x8 u3 = *(const f16x8*)(Ub + (size_t)(oA.w + laneoff));
      f16x8 u4 = *(const f16x8*)(Ub + (size_t)(oB.x + laneoff));
      f16x8 u5 = *(const f16x8*)(Ub + (size_t)(oB.y + laneoff));
      f16x8 u6 = *(const f16x8*)(Ub + (size_t)(oB.z + laneoff));
      f16x8 u7 = *(const f16x8*)(Ub + (size_t)(oB.w + laneoff));
      accA += u0 * wv[0];
      accB += u1 * wv[1];
      accC += u2 * wv[2];
      accD += u3 * wv[3];
      accA += u4 * wv[4];
      accB += u5 * wv[5];
      accC += u6 * wv[6];
      accD += u7 * wv[7];
    }
  }
  for (; p < end; ++p){
    unsigned off = offsD[p];
    _Float16 w0 = wHD[p];
    if (act){
      f16x8 u = *(const f16x8*)(Ub + (size_t)(off + laneoff));
      accB += u * w0;
    }
  }
  f16x8 acc = (accA + accB) + (accC + accD);

  int col0 = cc*448 + lane * 8;
  f16x8 o = (f16x8)(_Float16)0;
  int c = 0;
  if (act){
    #pragma unroll
    for (int e = 0; e < 8; ++e){
      int col = col0 + e;
      _Float16 hv = (col == k1 || col >= KC) ? (_Float16)0 : acc[e];
      o[e] = hv;
      c += (hv != (_Float16)0) ? 1 : 0;
    }
  }
  #pragma unroll
  for (int s = 32; s > 0; s >>= 1) c += __shfl_down(c, s);
  if (lane == 0) atomicAdd(&deg[k1], c);
  if (act && col0 + 8 <= A2P)
    *(f16x8*)(A2 + (size_t)k1 * A2P + col0) = o;
}

// LDS-tiled transpose: A2T[i][j] = A2[j][i]; rows j >= KC read as zero.
__global__ void k_tr(const __half* __restrict__ A2, __half* __restrict__ A2T){
  __shared__ float tile[64][65];
  int t = threadIdx.x;
  int i0 = blockIdx.x * 64, j0 = blockIdx.y * 64;
  int sl = t & 7;
  #pragma unroll
  for (int p = 0; p < 2; ++p){
    int jl = (t >> 3) + p*32;
    int j = j0 + jl;
    f16x8 v;
    if (j < KC) v = *(const f16x8*)(A2 + (size_t)j*A2P + i0 + sl*8);
    else v = (f16x8)(_Float16)0;
    #pragma unroll
    for (int e = 0; e < 8; ++e) tile[jl][sl*8 + e] = (float)v[e];
  }
  __syncthreads();
  #pragma unroll
  for (int p = 0; p < 2; ++p){
    int il = (t >> 3) + p*32;
    int i = i0 + il;
    f16x8 o;
    #pragma unroll
    for (int e = 0; e < 8; ++e) o[e] = (_Float16)tile[sl*8 + e][il];
    *(f16x8*)(A2T + (size_t)i*A2P + j0 + sl*8) = o;
  }
}

// Xt[h][j] = (f16) X[j][h], zero-padded for j >= KC.
__global__ void k_xt(const float* __restrict__ X, __half* __restrict__ Xt){
  __shared__ float T2[64][129];
  int t = threadIdx.x;
  int j0 = blockIdx.x * 64;
  for (int l = t; l < 64*32; l += 256){
    int jl = l >> 5, hg = (l & 31) * 4;
    int j = j0 + jl;
    float4 v = make_float4(0.f, 0.f, 0.f, 0.f);
    if (j < KC) v = *(const float4*)(X + (size_t)j*HH + hg);
    T2[jl][hg] = v.x; T2[jl][hg+1] = v.y; T2[jl][hg+2] = v.z; T2[jl][hg+3] = v.w;
  }
  __syncthreads();
  for (int idx = t; idx < 128*64; idx += 256){
    int h = idx >> 6, jl = idx & 63;
    Xt[(size_t)h*A2P + j0 + jl] = __float2half(T2[jl][h]);
  }
}

// MFMA dagg, K-split 2, atomic-free.
__global__ void k_mm(const __half* __restrict__ A2Th, const __half* __restrict__ Xth,
                     float* __restrict__ part){
  const _Float16* A2T = (const _Float16*)A2Th;
  const _Float16* Xt  = (const _Float16*)Xth;
  int t = threadIdx.x;
  int lane = t & 63, w = t >> 6;
  int i0 = (blockIdx.x >> 1) * 16;
  int half = blockIdx.x & 1;
  int kbeg = half * KHALF;
  float* po = part + (size_t)half * KC * HH;
  int l15 = lane & 15, lk = (lane >> 4) * 8;
  const _Float16* Arow = A2T + (size_t)(i0 + l15) * A2P + lk + kbeg;
  const _Float16* B0 = Xt + (size_t)(w*32 + l15) * A2P + lk + kbeg;
  const _Float16* B1 = B0 + (size_t)16 * A2P;
  f32x4 acc0 = (f32x4)0.f, acc1 = (f32x4)0.f;
  for (int kk = 0; kk < KHALF; kk += 64){
    f16x8 a0 = *(const f16x8*)(Arow + kk);
    f16x8 a1 = *(const f16x8*)(Arow + kk + 32);
    f16x8 b00 = *(const f16x8*)(B0 + kk);
    f16x8 b01 = *(const f16x8*)(B1 + kk);
    f16x8 b10 = *(const f16x8*)(B0 + kk + 32);
    f16x8 b11 = *(const f16x8*)(B1 + kk + 32);
    acc0 = __builtin_amdgcn_mfma_f32_16x16x32_f16(a0, b00, acc0, 0, 0, 0);
    acc1 = __builtin_amdgcn_mfma_f32_16x16x32_f16(a0, b01, acc1, 0, 0, 0);
    acc0 = __builtin_amdgcn_mfma_f32_16x16x32_f16(a1, b10, acc0, 0, 0, 0);
    acc1 = __builtin_amdgcn_mfma_f32_16x16x32_f16(a1, b11, acc1, 0, 0, 0);
  }
  int rbase = (lane >> 4) * 4;
  #pragma unroll
  for (int r = 0; r < 4; ++r){
    int i = i0 + rbase + r;
    if (i < KC){
      po[(size_t)i*HH + w*32 + l15] = acc0[r];
      po[(size_t)i*HH + w*32 + 16 + l15] = acc1[r];
    }
  }
}

} // namespace

extern "C" void kernel_launch(void* const* d_in, const int* in_sizes, int n_in,
                              void* d_out, int out_size, void* d_ws, size_t ws_size,
                              hipStream_t stream){
  (void)in_sizes; (void)n_in; (void)out_size; (void)ws_size;
  const float* x      = (const float*)d_in[0];
  const int*   ei     = (const int*)d_in[1];
  const float* c0Wrel = (const float*)d_in[2];
  const float* c0brel = (const float*)d_in[3];
  const float* c0Wroot= (const float*)d_in[4];
  const float* c1Wrel = (const float*)d_in[5];
  const float* c1brel = (const float*)d_in[6];
  const float* c1Wroot= (const float*)d_in[7];
  const float* c2Wrel = (const float*)d_in[8];
  const float* c2brel = (const float*)d_in[9];
  const float* c2Wroot= (const float*)d_in[10];
  const float* c3Wrel = (const float*)d_in[11];
  const float* c3brel = (const float*)d_in[12];
  const float* c3Wroot= (const float*)d_in[13];
  const float* Wlin   = (const float*)d_in[14];
  const float* blin   = (const float*)d_in[15];
  const float* Watt   = (const float*)d_in[16];
  const float* batt   = (const float*)d_in[17];
  const float* W1     = (const float*)d_in[18];
  const float* b1     = (const float*)d_in[19];
  const float* W2     = (const float*)d_in[20];
  const float* W3     = (const float*)d_in[21];
  const float* b3     = (const float*)d_in[22];
  float* out = (float*)d_out;

  char* base = (char*)d_ws;
  size_t off = 0;
  auto carve = [&](size_t bytes) -> void* {
    void* p = base + off;
    off += (bytes + 255) & ~(size_t)255;
    return p;
  };
  float* x1    = (float*)carve((size_t)NN*HH*4);
  float* x2b   = (float*)carve((size_t)NN*HH*4);
  float* meanb = (float*)carve((size_t)NN*HH*4);
  float* xnew  = (float*)carve((size_t)NN*HH*4);
  float* xp    = (float*)carve((size_t)KC*HH*4);
  float* x3    = (float*)carve((size_t)KC*HH*4);
  float* x4    = (float*)carve((size_t)KC*HH*4);
  float* part  = (float*)carve((size_t)2*KC*HH*4);
  __half* A2   = (__half*)carve((size_t)KC*A2P*2);   // ~22 MB
  __half* U    = (__half*)carve((size_t)NN*UP*2);    // ~29 MB; dead after k_A2B -> reused as A2T
  __half* A2T  = U;
  __half* Xt   = (__half*)carve((size_t)HH*A2P*2);
  float* xdot  = (float*)carve(NN*4);
  float* qdot  = (float*)carve(NN*4);
  float* mmaxA = (float*)carve(NN*4);
  float* ssumA = (float*)carve(NN*4);
  float* aA    = (float*)carve(NN*4);
  float* bA    = (float*)carve(NN*4);
  float* cA    = (float*)carve(NN*4);
  float* fitA  = (float*)carve(NN*4);
  float* fitk  = (float*)carve(KC*4);
  float* wA2   = (float*)carve((HH+1)*4);
  float* wD    = (float*)carve((size_t)E2*4);
  int* rowD = (int*)carve((NN+1)*4);
  int* rowS = (int*)carve((NN+1)*4);
  int* cntD = (int*)carve(NN*4);
  int* cntS = (int*)carve(NN*4);
  int* curD = (int*)carve(NN*4);
  int* curS = (int*)carve(NN*4);
  int* colD = (int*)carve((size_t)E2*4);
  int* dstS = (int*)carve((size_t)E2*4);
  int* mapSD= (int*)carve((size_t)E2*4);
  int2* kwS = (int2*)carve((size_t)E2*8);
  unsigned* offsD = (unsigned*)carve((size_t)E2*4);
  __half* wHD = (__half*)carve((size_t)E2*2);
  int* perm = (int*)carve(KC*4);
  int* kcol = (int*)carve(NN*4);
  int* deg3 = (int*)carve(KC*4);

  k_zero_init<<<NN/256, 256, 0, stream>>>(cntD, cntS, deg3, out);
  k_count<<<(E2+255)/256, 256, 0, stream>>>(ei, cntD, cntS);
  k_scan<<<1, 1024, 0, stream>>>(cntD, cntS, rowD, rowS, curD, curS);
  k_scatter<<<(E2+255)/256, 256, 0, stream>>>(ei, curD, curS, colD, dstS, mapSD);

  // conv0
  k_edge_mean<<<NN, 128, 0, stream>>>(x, rowD, colD, meanb);
  k_lin<<<(NN+15)/16, 256, 0, stream>>>(meanb, x, c0Wrel, c0brel, c0Wroot, x1, NN);
  k_colmean<<<(NN+63)/64, 128, 0, stream>>>(x1, NN, out + 0);

  // conv1
  k_edge_mean<<<NN, 128, 0, stream>>>(x1, rowD, colD, meanb);
  k_lin<<<(NN+15)/16, 256, 0, stream>>>(meanb, x1, c1Wrel, c1brel, c1Wroot, x2b, NN);
  k_colmean<<<(NN+63)/64, 128, 0, stream>>>(x2b, NN, out + 128);

  // ASAP pool
  k_wprep<<<1, 128, 0, stream>>>(Wlin, blin, Watt, wA2);
  k_xdot<<<NN, 128, 0, stream>>>(x2b, Watt, xdot);
  k_pool<<<NN, 128, 0, stream>>>(x2b, rowD, colD, xdot, wA2, batt,
                                 W1, b1, W2, W3, b3,
                                 qdot, mmaxA, ssumA, xnew, wD, aA, bA, cA);
  k_fit<<<NN, 128, 0, stream>>>(rowD, colD, aA, bA, cA, fitA);
  k_sel<<<1, 1024, 0, stream>>>(fitA, perm, fitk, kcol);
  k_wS<<<(E2+255)/256, 256, 0, stream>>>(mapSD, dstS, kcol, wD, colD, kwS, offsD, wHD);
  k_U<<<NN, 256, 0, stream>>>(rowS, dstS, kwS, U);
  k_A2B<<<A2B_RT*8, 256, 0, stream>>>(rowD, offsD, wHD, perm, U, A2, deg3);

  // transpose A2 -> A2T (U is dead now; A2T aliases it)
  k_tr<<<dim3(A2P/64, A2P/64), 256, 0, stream>>>(A2, A2T);

  // conv2 (dense, MFMA K-split 2; partial-sum + deg-mean fused into k_lin2)
  k_xpt<<<A2P/64, 256, 0, stream>>>(xnew, perm, fitk, xp, Xt);
  k_mm<<<(A2P/16)*2, 256, 0, stream>>>(A2T, Xt, part);
  k_lin2<<<(KC+15)/16, 256, 0, stream>>>(part, part + (size_t)KC*HH, deg3, xp,
                                         c2Wrel, c2brel, c2Wroot, x3, KC);
  k_colmean<<<(KC+63)/64, 128, 0, stream>>>(x3, KC, out + 256);

  // conv3 (dense, MFMA)
  k_xt<<<A2P/64, 256, 0, stream>>>(x3, Xt);
  k_mm<<<(A2P/16)*2, 256, 0, stream>>>(A2T, Xt, part);
  k_lin2<<<(KC+15)/16, 256, 0, stream>>>(part, part + (size_t)KC*HH, deg3, x3,
                                         c3Wrel, c3brel, c3Wroot, x4, KC);
  k_colmean<<<(KC+63)/64, 128, 0, stream>>>(x4, KC, out + 384);
}

// Round 10
// 409.243 us; speedup vs baseline: 5.1085x; 1.1626x over previous
//
#include <hip/hip_runtime.h>
#include <hip/hip_fp16.h>
#include <math.h>

namespace {

constexpr int NN = 4096;
constexpr int EE = 131072;
constexpr int E2 = EE + NN;      // 135168 pool edges (orig + self loops)
constexpr int HH = 128;
constexpr int KC = 3277;         // ceil(0.8*4096)
constexpr int UP = 3584;         // U row stride (8*448)
constexpr int A2P = 3328;        // A2 row/col padded dim

typedef _Float16 f16x8 __attribute__((ext_vector_type(8)));
typedef _Float16 f16x4 __attribute__((ext_vector_type(4)));
typedef float f32x4 __attribute__((ext_vector_type(4)));

constexpr int A2B_RT = (KC + 7) / 8;   // 411 row-groups (4 waves x 2 rows)
constexpr int KQ = A2P / 4;             // 832 (=13*64) K-quarter for k_mm

__device__ __forceinline__ float lrelu02(float x){ return x > 0.f ? x : 0.2f * x; }

__device__ __forceinline__ float redSum128(float* red, int t, float v){
  red[t] = v; __syncthreads();
  #pragma unroll
  for (int s = 64; s > 0; s >>= 1){ if (t < s) red[t] += red[t + s]; __syncthreads(); }
  float r = red[0]; __syncthreads();
  return r;
}
__device__ __forceinline__ float redMax128(float* red, int t, float v){
  red[t] = v; __syncthreads();
  #pragma unroll
  for (int s = 64; s > 0; s >>= 1){ if (t < s) red[t] = fmaxf(red[t], red[t + s]); __syncthreads(); }
  float r = red[0]; __syncthreads();
  return r;
}

__global__ void k_zero_init(int* cntD, int* cntS, int* deg, float* out){
  int i = blockIdx.x * blockDim.x + threadIdx.x;
  if (i < NN){ cntD[i] = 0; cntS[i] = 0; }
  if (i < KC) deg[i] = 0;
  if (i < 512) out[i] = 0.f;
}

__global__ void k_count(const int* __restrict__ ei, int* cntD, int* cntS){
  int e = blockIdx.x * blockDim.x + threadIdx.x;
  if (e >= E2) return;
  int u, v;
  if (e < EE){ u = ei[e]; v = ei[EE + e]; } else { u = e - EE; v = u; }
  atomicAdd(&cntD[v], 1);
  atomicAdd(&cntS[u], 1);
}

__global__ void k_scan(const int* cntD, const int* cntS, int* rowD, int* rowS, int* curD, int* curS){
  __shared__ int sc[1024];
  int t = threadIdx.x;
  for (int pass = 0; pass < 2; ++pass){
    const int* cnt = pass ? cntS : cntD;
    int* row = pass ? rowS : rowD;
    int* cur = pass ? curS : curD;
    int c0 = cnt[t*4+0], c1 = cnt[t*4+1], c2 = cnt[t*4+2], c3 = cnt[t*4+3];
    int tot = c0 + c1 + c2 + c3;
    sc[t] = tot; __syncthreads();
    for (int offs = 1; offs < 1024; offs <<= 1){
      int v = (t >= offs) ? sc[t - offs] : 0;
      __syncthreads();
      sc[t] += v;
      __syncthreads();
    }
    int excl = sc[t] - tot;
    int r0 = excl, r1 = r0 + c0, r2 = r1 + c1, r3 = r2 + c2;
    row[t*4+0] = r0; row[t*4+1] = r1; row[t*4+2] = r2; row[t*4+3] = r3;
    cur[t*4+0] = r0; cur[t*4+1] = r1; cur[t*4+2] = r2; cur[t*4+3] = r3;
    if (t == 1023) row[NN] = r3 + c3;
    __syncthreads();
  }
}

__global__ void k_scatter(const int* __restrict__ ei, int* curD, int* curS,
                          int* colD, int* dstS, int* mapSD){
  int e = blockIdx.x * blockDim.x + threadIdx.x;
  if (e >= E2) return;
  int u, v;
  if (e < EE){ u = ei[e]; v = ei[EE + e]; } else { u = e - EE; v = u; }
  int p = atomicAdd(&curD[v], 1); colD[p] = u;
  int q = atomicAdd(&curS[u], 1); dstS[q] = v; mapSD[q] = p;
}

// mean over in-neighbors (original edges only -> skip the self loop entry u==v)
__global__ void k_edge_mean(const float* __restrict__ xin, const int* __restrict__ rowD,
                            const int* __restrict__ colD, float* __restrict__ meanb){
  int v = blockIdx.x, t = threadIdx.x;
  int beg = rowD[v], end = rowD[v+1];
  float acc = 0.f;
  int p = beg;
  for (; p + 8 <= end; p += 8){
    int u0 = colD[p],   u1 = colD[p+1], u2 = colD[p+2], u3 = colD[p+3];
    int u4 = colD[p+4], u5 = colD[p+5], u6 = colD[p+6], u7 = colD[p+7];
    float a0 = xin[(size_t)u0*HH + t];
    float a1 = xin[(size_t)u1*HH + t];
    float a2 = xin[(size_t)u2*HH + t];
    float a3 = xin[(size_t)u3*HH + t];
    float a4 = xin[(size_t)u4*HH + t];
    float a5 = xin[(size_t)u5*HH + t];
    float a6 = xin[(size_t)u6*HH + t];
    float a7 = xin[(size_t)u7*HH + t];
    if (u0 != v) acc += a0;
    if (u1 != v) acc += a1;
    if (u2 != v) acc += a2;
    if (u3 != v) acc += a3;
    if (u4 != v) acc += a4;
    if (u5 != v) acc += a5;
    if (u6 != v) acc += a6;
    if (u7 != v) acc += a7;
  }
  for (; p < end; ++p){ int u = colD[p]; if (u != v) acc += xin[(size_t)u*HH + t]; }
  float dg = (float)(end - beg - 1);
  meanb[v*HH + t] = acc / fmaxf(dg, 1.f);
}

// xout = relu(meanb @ Wrel^T + brel + xin @ Wroot^T); fused column-mean atomic into cmout.
__global__ void k_lin(const float* __restrict__ meanb, const float* __restrict__ xin,
                      const float* __restrict__ Wrel, const float* __restrict__ brel,
                      const float* __restrict__ Wroot, float* __restrict__ xout, int rows,
                      float* __restrict__ cmout){
  __shared__ float ms[16][HH];
  __shared__ float xs[16][HH];
  __shared__ float cmred[256];
  int tid = threadIdx.x;
  int r0 = blockIdx.x * 16;
  for (int l = tid; l < 16*HH; l += 256){
    int r = l >> 7, c = l & 127; int gr = r0 + r;
    float mv = 0.f, xv = 0.f;
    if (gr < rows){ mv = meanb[(size_t)gr*HH + c]; xv = xin[(size_t)gr*HH + c]; }
    ms[r][c] = mv; xs[r][c] = xv;
  }
  __syncthreads();
  int h = tid & 127, hgrp = tid >> 7;
  float acc[8] = {0.f,0.f,0.f,0.f,0.f,0.f,0.f,0.f};
  for (int c = 0; c < HH; ++c){
    float wr = Wrel[h*HH + c], wo = Wroot[h*HH + c];
    #pragma unroll
    for (int r = 0; r < 8; ++r) acc[r] += ms[hgrp*8 + r][c]*wr + xs[hgrp*8 + r][c]*wo;
  }
  float bb = brel[h];
  float csum = 0.f;
  #pragma unroll
  for (int r = 0; r < 8; ++r){
    int gr = r0 + hgrp*8 + r;
    if (gr < rows){
      float val = fmaxf(acc[r] + bb, 0.f);
      xout[(size_t)gr*HH + h] = val;
      csum += val;
    }
  }
  cmred[tid] = csum; __syncthreads();
  if (tid < 128) atomicAdd(&cmout[h], (cmred[tid] + cmred[tid + 128]) / (float)rows);
}

// dense-conv linear: mean from 4 K-quarter partials / deg; optional xout; fused column-mean.
__global__ void k_lin2(const float* __restrict__ part, const int* __restrict__ deg,
                       const float* __restrict__ xin,
                       const float* __restrict__ Wrel, const float* __restrict__ brel,
                       const float* __restrict__ Wroot, float* __restrict__ xout, int rows,
                       float* __restrict__ cmout){
  __shared__ float ms[16][HH];
  __shared__ float xs[16][HH];
  __shared__ float cmred[256];
  const float* p0 = part;
  const float* p1 = part + (size_t)KC*HH;
  const float* p2 = part + (size_t)2*KC*HH;
  const float* p3 = part + (size_t)3*KC*HH;
  int tid = threadIdx.x;
  int r0 = blockIdx.x * 16;
  for (int l = tid; l < 16*HH; l += 256){
    int r = l >> 7, c = l & 127; int gr = r0 + r;
    float mv = 0.f, xv = 0.f;
    if (gr < rows){
      size_t idx = (size_t)gr*HH + c;
      float d = fmaxf((float)deg[gr], 1.f);
      mv = ((p0[idx] + p1[idx]) + (p2[idx] + p3[idx])) / d;
      xv = xin[idx];
    }
    ms[r][c] = mv; xs[r][c] = xv;
  }
  __syncthreads();
  int h = tid & 127, hgrp = tid >> 7;
  float acc[8] = {0.f,0.f,0.f,0.f,0.f,0.f,0.f,0.f};
  for (int c = 0; c < HH; ++c){
    float wr = Wrel[h*HH + c], wo = Wroot[h*HH + c];
    #pragma unroll
    for (int r = 0; r < 8; ++r) acc[r] += ms[hgrp*8 + r][c]*wr + xs[hgrp*8 + r][c]*wo;
  }
  float bb = brel[h];
  float csum = 0.f;
  #pragma unroll
  for (int r = 0; r < 8; ++r){
    int gr = r0 + hgrp*8 + r;
    if (gr < rows){
      float val = fmaxf(acc[r] + bb, 0.f);
      if (xout) xout[(size_t)gr*HH + h] = val;
      csum += val;
    }
  }
  cmred[tid] = csum; __syncthreads();
  if (tid < 128) atomicAdd(&cmout[h], (cmred[tid] + cmred[tid + 128]) / (float)rows);
}

// wA2[c] = sum_h wattA[h]*Wlin[h,c];  wA2[HH] = sum_h blin[h]*wattA[h]
__global__ void k_wprep(const float* __restrict__ Wlin, const float* __restrict__ blin,
                        const float* __restrict__ Watt, float* __restrict__ wA2){
  int c = threadIdx.x;
  float s = 0.f;
  for (int hh = 0; hh < HH; ++hh) s += Watt[hh] * Wlin[hh*HH + c];
  wA2[c] = s;
  if (c == 0){
    float q = 0.f;
    for (int hh = 0; hh < HH; ++hh) q += blin[hh] * Watt[hh];
    wA2[HH] = q;
  }
}

__global__ void k_xdot(const float* __restrict__ x2, const float* __restrict__ Watt, float* __restrict__ xdot){
  __shared__ float red[128];
  int n = blockIdx.x, t = threadIdx.x;
  float v = redSum128(red, t, x2[(size_t)n*HH + t] * Watt[HH + t]);
  if (t == 0) xdot[n] = v;
}

// per dst node v: xq max -> qdot; edge-softmax stats; x_new; wD; fused LEConv partials.
__global__ void k_pool(const float* __restrict__ x2, const int* __restrict__ rowD, const int* __restrict__ colD,
                       const float* __restrict__ xdotA, const float* __restrict__ wA2, const float* __restrict__ battp,
                       const float* __restrict__ W1, const float* __restrict__ b1,
                       const float* __restrict__ W2, const float* __restrict__ W3, const float* __restrict__ b3,
                       float* qdotA, float* mA, float* sA, float* __restrict__ xnew, float* __restrict__ wD,
                       float* aA, float* bA, float* cA){
  __shared__ float red[128];
  __shared__ float wmem[128];
  __shared__ int uc[128];
  int v = blockIdx.x, t = threadIdx.x;
  int beg = rowD[v], end = rowD[v+1];
  float batt = battp[0];
  float mx = -3.402823466e38f;
  int p = beg;
  for (; p + 4 <= end; p += 4){
    float a0 = x2[(size_t)colD[p]*HH + t];
    float a1 = x2[(size_t)colD[p+1]*HH + t];
    float a2 = x2[(size_t)colD[p+2]*HH + t];
    float a3 = x2[(size_t)colD[p+3]*HH + t];
    mx = fmaxf(fmaxf(fmaxf(fmaxf(mx, a0), a1), a2), a3);
  }
  for (; p < end; ++p) mx = fmaxf(mx, x2[(size_t)colD[p]*HH + t]);
  float qd = redSum128(red, t, mx * wA2[t]) + wA2[HH];
  float lm = -3.402823466e38f;
  for (p = beg + t; p < end; p += 128) lm = fmaxf(lm, lrelu02(qd + xdotA[colD[p]] + batt));
  float mm = redMax128(red, t, lm);
  float ls = 0.f;
  for (p = beg + t; p < end; p += 128) ls += expf(lrelu02(qd + xdotA[colD[p]] + batt) - mm);
  float ss = redSum128(red, t, ls);
  float acc = 0.f;
  for (int basep = beg; basep < end; basep += 128){
    int cnt = min(128, end - basep);
    if (t < cnt){
      int u = colD[basep + t];
      uc[t] = u;
      float w = expf(lrelu02(qd + xdotA[u] + batt) - mm) / ss;
      wmem[t] = w;
      wD[basep + t] = w;
    }
    __syncthreads();
    int i = 0;
    for (; i + 4 <= cnt; i += 4){
      float a0 = x2[(size_t)uc[i]*HH + t];
      float a1 = x2[(size_t)uc[i+1]*HH + t];
      float a2 = x2[(size_t)uc[i+2]*HH + t];
      float a3 = x2[(size_t)uc[i+3]*HH + t];
      acc += wmem[i]*a0 + wmem[i+1]*a1 + wmem[i+2]*a2 + wmem[i+3]*a3;
    }
    for (; i < cnt; ++i) acc += wmem[i] * x2[(size_t)uc[i]*HH + t];
    __syncthreads();
  }
  xnew[(size_t)v*HH + t] = acc;
  float s1 = redSum128(red, t, acc * W1[t]);
  float s2 = redSum128(red, t, acc * W2[t]);
  float s3 = redSum128(red, t, acc * W3[t]);
  if (t == 0){
    qdotA[v] = qd; mA[v] = mm; sA[v] = ss;
    aA[v] = s1 + b1[0]; bA[v] = s2; cA[v] = s3 + b3[0];
  }
}

__global__ void k_fit(const int* __restrict__ rowD, const int* __restrict__ colD,
                      const float* __restrict__ aA, const float* __restrict__ bA, const float* __restrict__ cA,
                      float* __restrict__ fitA){
  __shared__ float red[128];
  int v = blockIdx.x, t = threadIdx.x;
  int beg = rowD[v], end = rowD[v+1];
  float la = 0.f;
  for (int p = beg + t; p < end; p += 128) la += aA[colD[p]];
  float s = redSum128(red, t, la);
  if (t == 0){
    float g = s - (float)(end - beg) * bA[v] + cA[v];
    fitA[v] = 1.f / (1.f + expf(-g));
  }
}

// Exact top-K SET selection via radix-select (1 block, 1024 threads).
__global__ void k_sel(const float* __restrict__ fitA, int* perm, float* fitk, int* kcol){
  __shared__ unsigned keys[NN];
  __shared__ int hist[256];
  __shared__ int sc[1024];
  __shared__ int bc[2];
  int t = threadIdx.x;
  #pragma unroll
  for (int r = 0; r < 4; ++r){
    int i = t + r*1024;
    unsigned b = __float_as_uint(fitA[i]);
    keys[i] = (b & 0x80000000u) ? ~b : (b ^ 0x80000000u);
  }
  __syncthreads();
  unsigned prefix = 0;
  int kneed = KC;
  #pragma unroll
  for (int round = 0; round < 4; ++round){
    int shift = 24 - round*8;
    unsigned pmask = (round == 0) ? 0u : (0xFFFFFFFFu << (shift + 8));
    if (t < 256) hist[t] = 0;
    __syncthreads();
    #pragma unroll
    for (int r = 0; r < 4; ++r){
      unsigned kv = keys[t + r*1024];
      if ((kv & pmask) == prefix)
        atomicAdd(&hist[(kv >> shift) & 0xFF], 1);
    }
    __syncthreads();
    if (t == 0){
      int acc = 0, chosen = 0, rem = kneed;
      for (int bkt = 255; bkt >= 0; --bkt){
        int c = hist[bkt];
        if (acc + c >= kneed){ chosen = bkt; rem = kneed - acc; break; }
        acc += c;
      }
      bc[0] = chosen; bc[1] = rem;
    }
    __syncthreads();
    prefix |= ((unsigned)bc[0]) << shift;
    kneed = bc[1];
    __syncthreads();
  }
  unsigned T = prefix;
  int need_eq = kneed;
  int cnt[4]; int tot = 0;
  #pragma unroll
  for (int r = 0; r < 4; ++r){
    unsigned kv = keys[t*4 + r];
    int g = (kv > T) ? 1 : 0;
    int e = (kv == T) ? 1 : 0;
    cnt[r] = (g << 16) | e;
    tot += cnt[r];
  }
  sc[t] = tot; __syncthreads();
  for (int offs = 1; offs < 1024; offs <<= 1){
    int v = (t >= offs) ? sc[t - offs] : 0;
    __syncthreads();
    sc[t] += v;
    __syncthreads();
  }
  int gtot = sc[1023] >> 16;
  int run = sc[t] - tot;
  #pragma unroll
  for (int r = 0; r < 4; ++r){
    int i = t*4 + r;
    int g = cnt[r] >> 16, e = cnt[r] & 0xFFFF;
    int gpos = run >> 16, epos = run & 0xFFFF;
    int pos = -1;
    if (g) pos = gpos;
    else if (e && epos < need_eq) pos = gtot + epos;
    if (pos >= 0){ perm[pos] = i; fitk[pos] = fitA[i]; kcol[i] = pos; }
    else kcol[i] = -1;
    run += cnt[r];
  }
}

// fused: xp[j,:] = xnew[perm[j],:]*fitk[j]  AND  Xt[h][j] = f16(xp[j][h])
__global__ void k_xpt(const float* __restrict__ xnew, const int* __restrict__ perm,
                      const float* __restrict__ fitk, float* __restrict__ xp,
                      __half* __restrict__ Xt){
  __shared__ float T2[64][129];
  int t = threadIdx.x;
  int j0 = blockIdx.x * 64;
  for (int l = t; l < 64*32; l += 256){
    int jl = l >> 5, hg = (l & 31) * 4;
    int j = j0 + jl;
    float4 v = make_float4(0.f, 0.f, 0.f, 0.f);
    if (j < KC){
      float f = fitk[j];
      const float* src = xnew + (size_t)perm[j]*HH + hg;
      v.x = src[0]*f; v.y = src[1]*f; v.z = src[2]*f; v.w = src[3]*f;
      *(float4*)(xp + (size_t)j*HH + hg) = v;
    }
    T2[jl][hg] = v.x; T2[jl][hg+1] = v.y; T2[jl][hg+2] = v.z; T2[jl][hg+3] = v.w;
  }
  __syncthreads();
  for (int idx = t; idx < 128*64; idx += 256){
    int h = idx >> 6, jl = idx & 63;
    Xt[(size_t)h*A2P + j0 + jl] = __float2half(T2[jl][h]);
  }
}

// src-ordered packed (kcol, w) for k_U; dst-ordered byte-offset + f16 weight for k_A2B
__global__ void k_wS(const int* __restrict__ mapSD, const int* __restrict__ dstS,
                     const int* __restrict__ kcol, const float* __restrict__ wD,
                     const int* __restrict__ colD,
                     int2* __restrict__ kwS, unsigned* __restrict__ offsD,
                     __half* __restrict__ wHD){
  int q = blockIdx.x * blockDim.x + threadIdx.x;
  if (q >= E2) return;
  float w = wD[mapSD[q]];
  int k = kcol[dstS[q]];
  kwS[q] = make_int2(k, __float_as_int(w));
  offsD[q] = (unsigned)colD[q] * (UP*2);
  wHD[q] = __float2half(wD[q]);
}

// U[n,:] = (A @ S)[n,:]  (dense f16 row, stride UP, zero-padded)
__global__ void k_U(const int* __restrict__ rowS, const int* __restrict__ dstS,
                    const int2* __restrict__ kwS, __half* __restrict__ U){
  __shared__ float acc[UP];   // 14 KB
  int t = threadIdx.x, n = blockIdx.x;
  for (int i = t; i < UP; i += 256) acc[i] = 0.f;
  __syncthreads();
  int b = rowS[n], e = rowS[n+1];
  for (int p = b; p < e; ++p){
    int j = dstS[p];
    int b2 = rowS[j], e2 = rowS[j+1];
    for (int q = b2 + t; q < e2; q += 256){
      int2 kw = kwS[q];
      if (kw.x >= 0) atomicAdd(&acc[kw.x], __int_as_float(kw.y));
    }
  }
  __syncthreads();
  __half2* Ur = (__half2*)(U + (size_t)n * UP);
  for (int i = t; i < UP/2; i += 256)
    Ur[i] = __halves2half2(__float2half(acc[2*i]), __float2half(acc[2*i+1]));
}

// A2 rows via wave-per-2-rows (interleaved edges -> 8 loads in flight); 8 col-chunks of 448.
__global__ void k_A2B(const int* __restrict__ rowD,
                      const unsigned* __restrict__ offsD, const __half* __restrict__ wHDh,
                      const int* __restrict__ perm,
                      const __half* __restrict__ Uh, __half* __restrict__ A2,
                      int* __restrict__ deg){
  int cc = blockIdx.x & 7;
  int rt = blockIdx.x >> 3;
  int t = threadIdx.x;
  int w = t >> 6, lane = t & 63;
  int k1a = rt*8 + w*2, k1b = k1a + 1;
  if (k1a >= KC) return;
  bool hasB = (k1b < KC);
  bool act = lane < 56;
  unsigned laneoff = (unsigned)(cc*448*2 + lane*16);
  const char* Ub = (const char*)Uh;
  const _Float16* wHD = (const _Float16*)wHDh;

  f16x8 aA0 = (f16x8)(_Float16)0, aA1 = (f16x8)(_Float16)0;
  f16x8 aB0 = (f16x8)(_Float16)0, aB1 = (f16x8)(_Float16)0;

  int va = perm[k1a];
  int pa = rowD[va], enda = rowD[va+1];
  int pb = 0, endb = 0;
  if (hasB){ int vb = perm[k1b]; pb = rowD[vb]; endb = rowD[vb+1]; }

  auto step1 = [&](int p, f16x8& a0){
    unsigned off = offsD[p];
    _Float16 w0 = wHD[p];
    if (act){
      f16x8 u = *(const f16x8*)(Ub + (size_t)(off + laneoff));
      a0 += u * w0;
    }
  };
  auto step4 = [&](int p, f16x8& a0, f16x8& a1){
    uint4 o = *(const uint4*)(offsD + p);
    f16x4 wv = *(const f16x4*)(wHD + p);
    if (act){
      f16x8 u0 = *(const f16x8*)(Ub + (size_t)(o.x + laneoff));
      f16x8 u1 = *(const f16x8*)(Ub + (size_t)(o.y + laneoff));
      f16x8 u2 = *(const f16x8*)(Ub + (size_t)(o.z + laneoff));
      f16x8 u3 = *(const f16x8*)(Ub + (size_t)(o.w + laneoff));
      a0 += u0 * wv[0];
      a1 += u1 * wv[1];
      a0 += u2 * wv[2];
      a1 += u3 * wv[3];
    }
  };

  // align both rows to 4-edge boundary (8B weight alignment, 16B offset alignment)
  int preA = (4 - (pa & 3)) & 3; if (preA > enda - pa) preA = enda - pa;
  for (int z = 0; z < preA; ++z, ++pa) step1(pa, aA0);
  int preB = (4 - (pb & 3)) & 3; if (preB > endb - pb) preB = endb - pb;
  for (int z = 0; z < preB; ++z, ++pb) step1(pb, aB0);

  // joint interleaved loop: 8 independent U loads in flight
  while (pa + 4 <= enda && pb + 4 <= endb){
    step4(pa, aA0, aA1);
    step4(pb, aB0, aB1);
    pa += 4; pb += 4;
  }
  for (; pa + 4 <= enda; pa += 4) step4(pa, aA0, aA1);
  for (; pa < enda; ++pa) step1(pa, aA0);
  for (; pb + 4 <= endb; pb += 4) step4(pb, aB0, aB1);
  for (; pb < endb; ++pb) step1(pb, aB0);

  f16x8 accA = aA0 + aA1;
  f16x8 accB = aB0 + aB1;

  int col0 = cc*448 + lane * 8;
  bool wr = act && (col0 + 8 <= A2P);
  {
    f16x8 o = (f16x8)(_Float16)0;
    int c = 0;
    if (act){
      #pragma unroll
      for (int e = 0; e < 8; ++e){
        int col = col0 + e;
        _Float16 hv = (col == k1a || col >= KC) ? (_Float16)0 : accA[e];
        o[e] = hv;
        c += (hv != (_Float16)0) ? 1 : 0;
      }
    }
    #pragma unroll
    for (int s = 32; s > 0; s >>= 1) c += __shfl_down(c, s);
    if (lane == 0) atomicAdd(&deg[k1a], c);
    if (wr) *(f16x8*)(A2 + (size_t)k1a * A2P + col0) = o;
  }
  if (hasB){
    f16x8 o = (f16x8)(_Float16)0;
    int c = 0;
    if (act){
      #pragma unroll
      for (int e = 0; e < 8; ++e){
        int col = col0 + e;
        _Float16 hv = (col == k1b || col >= KC) ? (_Float16)0 : accB[e];
        o[e] = hv;
        c += (hv != (_Float16)0) ? 1 : 0;
      }
    }
    #pragma unroll
    for (int s = 32; s > 0; s >>= 1) c += __shfl_down(c, s);
    if (lane == 0) atomicAdd(&deg[k1b], c);
    if (wr) *(f16x8*)(A2 + (size_t)k1b * A2P + col0) = o;
  }
}

// LDS-tiled transpose: A2T[i][j] = A2[j][i]; rows j >= KC read as zero.
__global__ void k_tr(const __half* __restrict__ A2, __half* __restrict__ A2T){
  __shared__ float tile[64][65];
  int t = threadIdx.x;
  int i0 = blockIdx.x * 64, j0 = blockIdx.y * 64;
  int sl = t & 7;
  #pragma unroll
  for (int p = 0; p < 2; ++p){
    int jl = (t >> 3) + p*32;
    int j = j0 + jl;
    f16x8 v;
    if (j < KC) v = *(const f16x8*)(A2 + (size_t)j*A2P + i0 + sl*8);
    else v = (f16x8)(_Float16)0;
    #pragma unroll
    for (int e = 0; e < 8; ++e) tile[jl][sl*8 + e] = (float)v[e];
  }
  __syncthreads();
  #pragma unroll
  for (int p = 0; p < 2; ++p){
    int il = (t >> 3) + p*32;
    int i = i0 + il;
    f16x8 o;
    #pragma unroll
    for (int e = 0; e < 8; ++e) o[e] = (_Float16)tile[sl*8 + e][il];
    *(f16x8*)(A2T + (size_t)i*A2P + j0 + sl*8) = o;
  }
}

// Xt[h][j] = (f16) X[j][h], zero-padded for j >= KC.
__global__ void k_xt(const float* __restrict__ X, __half* __restrict__ Xt){
  __shared__ float T2[64][129];
  int t = threadIdx.x;
  int j0 = blockIdx.x * 64;
  for (int l = t; l < 64*32; l += 256){
    int jl = l >> 5, hg = (l & 31) * 4;
    int j = j0 + jl;
    float4 v = make_float4(0.f, 0.f, 0.f, 0.f);
    if (j < KC) v = *(const float4*)(X + (size_t)j*HH + hg);
    T2[jl][hg] = v.x; T2[jl][hg+1] = v.y; T2[jl][hg+2] = v.z; T2[jl][hg+3] = v.w;
  }
  __syncthreads();
  for (int idx = t; idx < 128*64; idx += 256){
    int h = idx >> 6, jl = idx & 63;
    Xt[(size_t)h*A2P + j0 + jl] = __float2half(T2[jl][h]);
  }
}

// MFMA dagg: 32i x 128h per block, K-split 4, atomic-free.
// grid = (A2P/32)*4 = 416; 4 waves, each 32i x 32h; K-unroll 2.
__global__ void k_mm(const __half* __restrict__ A2Th, const __half* __restrict__ Xth,
                     float* __restrict__ part){
  const _Float16* A2T = (const _Float16*)A2Th;
  const _Float16* Xt  = (const _Float16*)Xth;
  int t = threadIdx.x;
  int lane = t & 63, w = t >> 6;
  int i0 = (blockIdx.x >> 2) * 32;
  int kq = blockIdx.x & 3;
  int kbeg = kq * KQ;
  float* po = part + (size_t)kq * KC * HH;
  int l15 = lane & 15, lk = (lane >> 4) * 8;
  const _Float16* Ar0 = A2T + (size_t)(i0 + l15) * A2P + lk + kbeg;
  const _Float16* Ar1 = Ar0 + (size_t)16 * A2P;
  const _Float16* B0 = Xt + (size_t)(w*32 + l15) * A2P + lk + kbeg;
  const _Float16* B1 = B0 + (size_t)16 * A2P;
  f32x4 acc00 = (f32x4)0.f, acc01 = (f32x4)0.f;
  f32x4 acc10 = (f32x4)0.f, acc11 = (f32x4)0.f;
  for (int kk = 0; kk < KQ; kk += 64){
    f16x8 a00 = *(const f16x8*)(Ar0 + kk);
    f16x8 a01 = *(const f16x8*)(Ar0 + kk + 32);
    f16x8 a10 = *(const f16x8*)(Ar1 + kk);
    f16x8 a11 = *(const f16x8*)(Ar1 + kk + 32);
    f16x8 b00 = *(const f16x8*)(B0 + kk);
    f16x8 b01 = *(const f16x8*)(B1 + kk);
    f16x8 b10 = *(const f16x8*)(B0 + kk + 32);
    f16x8 b11 = *(const f16x8*)(B1 + kk + 32);
    acc00 = __builtin_amdgcn_mfma_f32_16x16x32_f16(a00, b00, acc00, 0, 0, 0);
    acc01 = __builtin_amdgcn_mfma_f32_16x16x32_f16(a00, b01, acc01, 0, 0, 0);
    acc10 = __builtin_amdgcn_mfma_f32_16x16x32_f16(a10, b00, acc10, 0, 0, 0);
    acc11 = __builtin_amdgcn_mfma_f32_16x16x32_f16(a10, b01, acc11, 0, 0, 0);
    acc00 = __builtin_amdgcn_mfma_f32_16x16x32_f16(a01, b10, acc00, 0, 0, 0);
    acc01 = __builtin_amdgcn_mfma_f32_16x16x32_f16(a01, b11, acc01, 0, 0, 0);
    acc10 = __builtin_amdgcn_mfma_f32_16x16x32_f16(a11, b10, acc10, 0, 0, 0);
    acc11 = __builtin_amdgcn_mfma_f32_16x16x32_f16(a11, b11, acc11, 0, 0, 0);
  }
  int rbase = (lane >> 4) * 4;
  #pragma unroll
  for (int r = 0; r < 4; ++r){
    int ia = i0 + rbase + r;
    int ib = ia + 16;
    if (ia < KC){
      po[(size_t)ia*HH + w*32 + l15] = acc00[r];
      po[(size_t)ia*HH + w*32 + 16 + l15] = acc01[r];
    }
    if (ib < KC){
      po[(size_t)ib*HH + w*32 + l15] = acc10[r];
      po[(size_t)ib*HH + w*32 + 16 + l15] = acc11[r];
    }
  }
}

} // namespace

extern "C" void kernel_launch(void* const* d_in, const int* in_sizes, int n_in,
                              void* d_out, int out_size, void* d_ws, size_t ws_size,
                              hipStream_t stream){
  (void)in_sizes; (void)n_in; (void)out_size; (void)ws_size;
  const float* x      = (const float*)d_in[0];
  const int*   ei     = (const int*)d_in[1];
  const float* c0Wrel = (const float*)d_in[2];
  const float* c0brel = (const float*)d_in[3];
  const float* c0Wroot= (const float*)d_in[4];
  const float* c1Wrel = (const float*)d_in[5];
  const float* c1brel = (const float*)d_in[6];
  const float* c1Wroot= (const float*)d_in[7];
  const float* c2Wrel = (const float*)d_in[8];
  const float* c2brel = (const float*)d_in[9];
  const float* c2Wroot= (const float*)d_in[10];
  const float* c3Wrel = (const float*)d_in[11];
  const float* c3brel = (const float*)d_in[12];
  const float* c3Wroot= (const float*)d_in[13];
  const float* Wlin   = (const float*)d_in[14];
  const float* blin   = (const float*)d_in[15];
  const float* Watt   = (const float*)d_in[16];
  const float* batt   = (const float*)d_in[17];
  const float* W1     = (const float*)d_in[18];
  const float* b1     = (const float*)d_in[19];
  const float* W2     = (const float*)d_in[20];
  const float* W3     = (const float*)d_in[21];
  const float* b3     = (const float*)d_in[22];
  float* out = (float*)d_out;

  char* base = (char*)d_ws;
  size_t off = 0;
  auto carve = [&](size_t bytes) -> void* {
    void* p = base + off;
    off += (bytes + 255) & ~(size_t)255;
    return p;
  };
  float* x1    = (float*)carve((size_t)NN*HH*4);
  float* x2b   = (float*)carve((size_t)NN*HH*4);
  float* meanb = (float*)carve((size_t)NN*HH*4);
  float* xnew  = (float*)carve((size_t)NN*HH*4);
  float* xp    = (float*)carve((size_t)KC*HH*4);
  float* x3    = (float*)carve((size_t)KC*HH*4);
  float* part  = (float*)carve((size_t)4*KC*HH*4);   // 4 K-quarter partials (~6.7 MB)
  __half* A2   = (__half*)carve((size_t)KC*A2P*2);   // ~22 MB
  __half* U    = (__half*)carve((size_t)NN*UP*2);    // ~29 MB; dead after k_A2B -> reused as A2T
  __half* A2T  = U;
  __half* Xt   = (__half*)carve((size_t)HH*A2P*2);
  float* xdot  = (float*)carve(NN*4);
  float* qdot  = (float*)carve(NN*4);
  float* mmaxA = (float*)carve(NN*4);
  float* ssumA = (float*)carve(NN*4);
  float* aA    = (float*)carve(NN*4);
  float* bA    = (float*)carve(NN*4);
  float* cA    = (float*)carve(NN*4);
  float* fitA  = (float*)carve(NN*4);
  float* fitk  = (float*)carve(KC*4);
  float* wA2   = (float*)carve((HH+1)*4);
  float* wD    = (float*)carve((size_t)E2*4);
  int* rowD = (int*)carve((NN+1)*4);
  int* rowS = (int*)carve((NN+1)*4);
  int* cntD = (int*)carve(NN*4);
  int* cntS = (int*)carve(NN*4);
  int* curD = (int*)carve(NN*4);
  int* curS = (int*)carve(NN*4);
  int* colD = (int*)carve((size_t)E2*4);
  int* dstS = (int*)carve((size_t)E2*4);
  int* mapSD= (int*)carve((size_t)E2*4);
  int2* kwS = (int2*)carve((size_t)E2*8);
  unsigned* offsD = (unsigned*)carve((size_t)E2*4);
  __half* wHD = (__half*)carve((size_t)E2*2);
  int* perm = (int*)carve(KC*4);
  int* kcol = (int*)carve(NN*4);
  int* deg3 = (int*)carve(KC*4);

  k_zero_init<<<NN/256, 256, 0, stream>>>(cntD, cntS, deg3, out);
  k_count<<<(E2+255)/256, 256, 0, stream>>>(ei, cntD, cntS);
  k_scan<<<1, 1024, 0, stream>>>(cntD, cntS, rowD, rowS, curD, curS);
  k_scatter<<<(E2+255)/256, 256, 0, stream>>>(ei, curD, curS, colD, dstS, mapSD);

  // conv0 (colmean fused into k_lin)
  k_edge_mean<<<NN, 128, 0, stream>>>(x, rowD, colD, meanb);
  k_lin<<<(NN+15)/16, 256, 0, stream>>>(meanb, x, c0Wrel, c0brel, c0Wroot, x1, NN, out + 0);

  // conv1
  k_edge_mean<<<NN, 128, 0, stream>>>(x1, rowD, colD, meanb);
  k_lin<<<(NN+15)/16, 256, 0, stream>>>(meanb, x1, c1Wrel, c1brel, c1Wroot, x2b, NN, out + 128);

  // ASAP pool
  k_wprep<<<1, 128, 0, stream>>>(Wlin, blin, Watt, wA2);
  k_xdot<<<NN, 128, 0, stream>>>(x2b, Watt, xdot);
  k_pool<<<NN, 128, 0, stream>>>(x2b, rowD, colD, xdot, wA2, batt,
                                 W1, b1, W2, W3, b3,
                                 qdot, mmaxA, ssumA, xnew, wD, aA, bA, cA);
  k_fit<<<NN, 128, 0, stream>>>(rowD, colD, aA, bA, cA, fitA);
  k_sel<<<1, 1024, 0, stream>>>(fitA, perm, fitk, kcol);
  k_wS<<<(E2+255)/256, 256, 0, stream>>>(mapSD, dstS, kcol, wD, colD, kwS, offsD, wHD);
  k_U<<<NN, 256, 0, stream>>>(rowS, dstS, kwS, U);
  k_A2B<<<A2B_RT*8, 256, 0, stream>>>(rowD, offsD, wHD, perm, U, A2, deg3);

  // transpose A2 -> A2T (U is dead now; A2T aliases it)
  k_tr<<<dim3(A2P/64, A2P/64), 256, 0, stream>>>(A2, A2T);

  // conv2 (MFMA K-split 4; partial-sum + deg-mean + colmean fused into k_lin2)
  k_xpt<<<A2P/64, 256, 0, stream>>>(xnew, perm, fitk, xp, Xt);
  k_mm<<<(A2P/32)*4, 256, 0, stream>>>(A2T, Xt, part);
  k_lin2<<<(KC+15)/16, 256, 0, stream>>>(part, deg3, xp,
                                         c2Wrel, c2brel, c2Wroot, x3, KC, out + 256);

  // conv3 (x4 never materialized; only its column-mean is needed)
  k_xt<<<A2P/64, 256, 0, stream>>>(x3, Xt);
  k_mm<<<(A2P/32)*4, 256, 0, stream>>>(A2T, Xt, part);
  k_lin2<<<(KC+15)/16, 256, 0, stream>>>(part, deg3, x3,
                                         c3Wrel, c3brel, c3Wroot, nullptr, KC, out + 384);
}